// Round 4
// baseline (1910.477 us; speedup 1.0000x reference)
//
#include <hip/hip_runtime.h>
#include <hip/hip_bf16.h>
#include <math.h>

// Problem constants
#define NTOK   8192
#define DMODEL 2048
#define NEXP   8
#define RGATE  8
#define DFF    1024

#define NEG_SENTINEL (-3.0e38f)

using f32x4  = __attribute__((ext_vector_type(4))) float;
using short8 = __attribute__((ext_vector_type(8))) short;

// RNE float->bf16
static __device__ __forceinline__ short f2bf(float f) {
  union { float f; unsigned u; } v; v.f = f;
  unsigned r = v.u + 0x7fffu + ((v.u >> 16) & 1u);
  return (short)(r >> 16);
}
static __device__ __forceinline__ short8 cvt8(const float4 a, const float4 b) {
  short8 o;
  o[0] = f2bf(a.x); o[1] = f2bf(a.y); o[2] = f2bf(a.z); o[3] = f2bf(a.w);
  o[4] = f2bf(b.x); o[5] = f2bf(b.y); o[6] = f2bf(b.z); o[7] = f2bf(b.w);
  return o;
}

#define GLOAD_LDS(gp, lp)                                                  \
  __builtin_amdgcn_global_load_lds(                                        \
      (const __attribute__((address_space(1))) void*)(gp),                 \
      (__attribute__((address_space(3))) void*)(lp), 16, 0, 0)

// ---------------------------------------------------------------------------
// cvt: fp32 -> bf16, 8 elems/thread/iter, grid-stride
// ---------------------------------------------------------------------------
__global__ __launch_bounds__(256) void cvt_kernel(
    const float* __restrict__ in, short* __restrict__ out, int n8) {
  const int stride = gridDim.x * blockDim.x;
  for (int i = blockIdx.x * blockDim.x + threadIdx.x; i < n8; i += stride) {
    const float4 a = ((const float4*)in)[(size_t)i * 2];
    const float4 b = ((const float4*)in)[(size_t)i * 2 + 1];
    ((short8*)out)[i] = cvt8(a, b);
  }
}

// ---------------------------------------------------------------------------
// K1: gate — UNCHANGED (passed R2/R3; fp32 reduce order must stay bit-stable
// for mask correctness near threshold).
// ---------------------------------------------------------------------------
__global__ __launch_bounds__(256) void gate_kernel(
    const float* __restrict__ x, const float* __restrict__ W_A,
    const float* __restrict__ gscale, const float* __restrict__ gbias,
    float* __restrict__ gw, float* __restrict__ score_out) {
  __shared__ float xs[DMODEL];
  __shared__ float gh[NEXP * RGATE];
  const int n = blockIdx.x;
  const float* xr = x + (size_t)n * DMODEL;
  for (int i = threadIdx.x; i < DMODEL / 4; i += 256)
    ((float4*)xs)[i] = ((const float4*)xr)[i];
  __syncthreads();

  const int g = threadIdx.x >> 2;
  const int l = threadIdx.x & 3;
  const float* wa = W_A + (size_t)g * DMODEL;
  float s = 0.f;
#pragma unroll 4
  for (int k = l; k < DMODEL / 4; k += 4) {
    const float4 xv = ((const float4*)xs)[k];
    const float4 wv = ((const float4*)wa)[k];
    s += xv.x * wv.x + xv.y * wv.y + xv.z * wv.z + xv.w * wv.w;
  }
  s += __shfl_xor(s, 1);
  s += __shfl_xor(s, 2);
  if (l == 0) gh[g] = s;
  __syncthreads();

  if (threadIdx.x < NEXP) {
    const int e = threadIdx.x;
    float ss = 0.f;
#pragma unroll
    for (int r = 0; r < RGATE; ++r) { const float v = gh[e * RGATE + r]; ss += v * v; }
    const float score = sqrtf(ss) * gscale[e] - gbias[e];
    const bool m = (score >= 0.0f);
    const float sig = 1.0f / (1.0f + expf(-score));
    gw[(size_t)n * NEXP + e] = m ? sig : 0.0f;
    score_out[(size_t)n * NEXP + e] = m ? score : NEG_SENTINEL;
  }
}

// ---------------------------------------------------------------------------
// m97-style bf16 GEMM: C[M,Ncol] = A[M,K] · B[Ncol,K]^T, 128x128 tile, BK=64,
// 4 waves each owning a 64x64 sub-tile (4x4 frags of 16x16x32).
// Staging: global_load_lds dwordx4, linear LDS (wave-uniform base + lane*16).
// EPI: 0 = write fp32 C (G pass)
//      1 = read Gf, h = silu(g)*u*gw  -> write bf16 Hb (U pass)
//      2 = out RMW fp32 (down pass; e==0 writes, covers poisoned d_out)
// ---------------------------------------------------------------------------
template <int EPI>
__global__ __launch_bounds__(256) void gemm_bt(
    const short* __restrict__ A, const short* __restrict__ B, int K, int ldc,
    float* __restrict__ Cf, short* __restrict__ Cb, float* __restrict__ outp,
    const float* __restrict__ gw, int e) {
  __shared__ __align__(16) short As[128 * 64];
  __shared__ __align__(16) short Bs[128 * 64];

  const int n0 = blockIdx.y * 128;
  const int c0 = blockIdx.x * 128;
  const int t = threadIdx.x;
  const int lane = t & 63;
  const int wid = t >> 6;
  const int wr = wid >> 1;  // row half
  const int wc = wid & 1;   // col half

  const short* Ab = A + (size_t)n0 * K;
  const short* Bb = B + (size_t)c0 * K;

  f32x4 acc[4][4];
#pragma unroll
  for (int i = 0; i < 4; ++i)
#pragma unroll
    for (int j = 0; j < 4; ++j) acc[i][j] = (f32x4){0.f, 0.f, 0.f, 0.f};

  // per-lane within-issue coords: 8 rows x 8 chunks of 16B per wave-issue
  const int lr = lane >> 3;       // row within 8-row stripe
  const int lk = (lane & 7) * 8;  // elem offset of 16B chunk

  for (int k0 = 0; k0 < K; k0 += 64) {
    __syncthreads();  // previous tile's readers done
#pragma unroll
    for (int i = 0; i < 4; ++i) {
      const int row = wid * 32 + i * 8;  // stripe base (wave-uniform)
      GLOAD_LDS(Ab + (size_t)(row + lr) * K + k0 + lk, (char*)As + row * 128);
      GLOAD_LDS(Bb + (size_t)(row + lr) * K + k0 + lk, (char*)Bs + row * 128);
    }
    __syncthreads();  // compiler drains vmcnt before barrier

#pragma unroll
    for (int ks = 0; ks < 2; ++ks) {
      short8 af[4], bf[4];
#pragma unroll
      for (int q = 0; q < 4; ++q) {
        af[q] = *(const short8*)((const char*)As +
                 (wr * 64 + q * 16 + (lane & 15)) * 128 + ks * 64 + (lane >> 4) * 16);
        bf[q] = *(const short8*)((const char*)Bs +
                 (wc * 64 + q * 16 + (lane & 15)) * 128 + ks * 64 + (lane >> 4) * 16);
      }
#pragma unroll
      for (int nf = 0; nf < 4; ++nf)
#pragma unroll
        for (int ff = 0; ff < 4; ++ff)
          acc[nf][ff] = __builtin_amdgcn_mfma_f32_16x16x32_bf16(af[nf], bf[ff], acc[nf][ff], 0, 0, 0);
    }
  }

  // Epilogue. C frag layout [m89]: col = lane&15, row = (lane>>4)*4 + j.
#pragma unroll
  for (int nf = 0; nf < 4; ++nf) {
#pragma unroll
    for (int j = 0; j < 4; ++j) {
      const int n = n0 + wr * 64 + nf * 16 + (lane >> 4) * 4 + j;
      float gwv = 0.f;
      if (EPI == 1) gwv = gw[(size_t)n * NEXP + e];
#pragma unroll
      for (int ff = 0; ff < 4; ++ff) {
        const int c = c0 + wc * 64 + ff * 16 + (lane & 15);
        if (EPI == 0) {
          Cf[(size_t)n * ldc + c] = acc[nf][ff][j];
        } else if (EPI == 1) {
          const float g = Cf[(size_t)n * ldc + c];
          const float u = acc[nf][ff][j];
          const float h = (g / (1.f + expf(-g))) * u * gwv;
          Cb[(size_t)n * ldc + c] = f2bf(h);
        } else {
          float* op = &outp[(size_t)n * ldc + c];
          if (e == 0) *op = acc[nf][ff][j];
          else        *op += acc[nf][ff][j];
        }
      }
    }
  }
}

// ===========================================================================
// FALLBACK PATH (small ws): R3 kernels verbatim — proven correct/passing.
// ===========================================================================
#define BM 128
#define BT 64
#define BK 64
static __device__ __forceinline__ int swoff(int r, int kc) {
  return r * (BK * 2) + ((kc ^ (r & 7)) << 4);
}

__global__ __launch_bounds__(256, 2) void ffn1_mfma(
    const float* __restrict__ x, const float* __restrict__ wgp,
    const float* __restrict__ wup, const float* __restrict__ gw,
    short* __restrict__ Hb, int e) {
  __shared__ __align__(16) short As[BM * BK];
  __shared__ __align__(16) short Bgs[BT * BK];
  __shared__ __align__(16) short Bus[BT * BK];

  const int n0 = blockIdx.y * BM;
  const int f0 = blockIdx.x * BT;
  const int t = threadIdx.x;
  const int lane = t & 63;
  const int wid = t >> 6;
  const int wr = wid >> 1;
  const int wc = wid & 1;

  const float* xa  = x   + (size_t)n0 * DMODEL;
  const float* wge = wgp + ((size_t)e * DFF + f0) * DMODEL;
  const float* wue = wup + ((size_t)e * DFF + f0) * DMODEL;

  int ra4[4], ka4[4], rb2[2], kb2[2];
#pragma unroll
  for (int p = 0; p < 4; ++p) { const int ci = p * 256 + t; ra4[p] = ci >> 3; ka4[p] = ci & 7; }
#pragma unroll
  for (int p = 0; p < 2; ++p) { const int ci = p * 256 + t; rb2[p] = ci >> 3; kb2[p] = ci & 7; }

  f32x4 accg[4][2], accu[4][2];
#pragma unroll
  for (int i = 0; i < 4; ++i)
#pragma unroll
    for (int j = 0; j < 2; ++j) {
      accg[i][j] = (f32x4){0.f, 0.f, 0.f, 0.f};
      accu[i][j] = (f32x4){0.f, 0.f, 0.f, 0.f};
    }

  float4 ar[4][2], bgr[2][2], bur[2][2];
  auto loadg = [&](int k0) {
#pragma unroll
    for (int p = 0; p < 4; ++p) {
      const float* s = &xa[(size_t)ra4[p] * DMODEL + k0 + ka4[p] * 8];
      ar[p][0] = *(const float4*)s; ar[p][1] = *(const float4*)(s + 4);
    }
#pragma unroll
    for (int p = 0; p < 2; ++p) {
      const float* sg = &wge[(size_t)rb2[p] * DMODEL + k0 + kb2[p] * 8];
      bgr[p][0] = *(const float4*)sg; bgr[p][1] = *(const float4*)(sg + 4);
      const float* su = &wue[(size_t)rb2[p] * DMODEL + k0 + kb2[p] * 8];
      bur[p][0] = *(const float4*)su; bur[p][1] = *(const float4*)(su + 4);
    }
  };

  loadg(0);
  for (int k0 = 0; k0 < DMODEL; k0 += BK) {
    __syncthreads();
#pragma unroll
    for (int p = 0; p < 4; ++p)
      *(short8*)((char*)As + swoff(ra4[p], ka4[p])) = cvt8(ar[p][0], ar[p][1]);
#pragma unroll
    for (int p = 0; p < 2; ++p) {
      *(short8*)((char*)Bgs + swoff(rb2[p], kb2[p])) = cvt8(bgr[p][0], bgr[p][1]);
      *(short8*)((char*)Bus + swoff(rb2[p], kb2[p])) = cvt8(bur[p][0], bur[p][1]);
    }
    __syncthreads();
    if (k0 + BK < DMODEL) loadg(k0 + BK);

#pragma unroll
    for (int ks = 0; ks < 2; ++ks) {
      const int kc = ks * 4 + (lane >> 4);
      short8 af[4];
#pragma unroll
      for (int nf = 0; nf < 4; ++nf) {
        const int r = wr * 64 + nf * 16 + (lane & 15);
        af[nf] = *(const short8*)((const char*)As + swoff(r, kc));
      }
#pragma unroll
      for (int ff = 0; ff < 2; ++ff) {
        const int r = wc * 32 + ff * 16 + (lane & 15);
        const short8 bg = *(const short8*)((const char*)Bgs + swoff(r, kc));
        const short8 bu = *(const short8*)((const char*)Bus + swoff(r, kc));
#pragma unroll
        for (int nf = 0; nf < 4; ++nf) {
          accg[nf][ff] = __builtin_amdgcn_mfma_f32_16x16x32_bf16(af[nf], bg, accg[nf][ff], 0, 0, 0);
          accu[nf][ff] = __builtin_amdgcn_mfma_f32_16x16x32_bf16(af[nf], bu, accu[nf][ff], 0, 0, 0);
        }
      }
    }
  }

#pragma unroll
  for (int nf = 0; nf < 4; ++nf) {
#pragma unroll
    for (int j = 0; j < 4; ++j) {
      const int n = n0 + wr * 64 + nf * 16 + (lane >> 4) * 4 + j;
      const float gwv = gw[(size_t)n * NEXP + e];
#pragma unroll
      for (int ff = 0; ff < 2; ++ff) {
        const float g = accg[nf][ff][j];
        const float u = accu[nf][ff][j];
        const float h = (g / (1.f + expf(-g))) * u * gwv;
        const int f = f0 + wc * 32 + ff * 16 + (lane & 15);
        Hb[(size_t)n * DFF + f] = f2bf(h);
      }
    }
  }
}

__global__ __launch_bounds__(256, 2) void ffn2_mfma(
    const short* __restrict__ Hb, const float* __restrict__ wdp,
    float* __restrict__ out, int e) {
  __shared__ __align__(16) short As[BM * BK];
  __shared__ __align__(16) short Bs[BT * BK];

  const int n0 = blockIdx.y * BM;
  const int d0 = blockIdx.x * BT;
  const int t = threadIdx.x;
  const int lane = t & 63;
  const int wid = t >> 6;
  const int wr = wid >> 1;
  const int wc = wid & 1;

  const short* Ha  = Hb  + (size_t)n0 * DFF;
  const float* wde = wdp + ((size_t)e * DMODEL + d0) * DFF;

  int ra4[4], ka4[4], rb2[2], kb2[2];
#pragma unroll
  for (int p = 0; p < 4; ++p) { const int ci = p * 256 + t; ra4[p] = ci >> 3; ka4[p] = ci & 7; }
#pragma unroll
  for (int p = 0; p < 2; ++p) { const int ci = p * 256 + t; rb2[p] = ci >> 3; kb2[p] = ci & 7; }

  f32x4 acc[4][2];
#pragma unroll
  for (int i = 0; i < 4; ++i)
#pragma unroll
    for (int j = 0; j < 2; ++j) acc[i][j] = (f32x4){0.f, 0.f, 0.f, 0.f};

  short8 ar[4];
  float4 br[2][2];
  auto loadg = [&](int k0) {
#pragma unroll
    for (int p = 0; p < 4; ++p)
      ar[p] = *(const short8*)&Ha[(size_t)ra4[p] * DFF + k0 + ka4[p] * 8];
#pragma unroll
    for (int p = 0; p < 2; ++p) {
      const float* s = &wde[(size_t)rb2[p] * DFF + k0 + kb2[p] * 8];
      br[p][0] = *(const float4*)s; br[p][1] = *(const float4*)(s + 4);
    }
  };

  loadg(0);
  for (int k0 = 0; k0 < DFF; k0 += BK) {
    __syncthreads();
#pragma unroll
    for (int p = 0; p < 4; ++p)
      *(short8*)((char*)As + swoff(ra4[p], ka4[p])) = ar[p];
#pragma unroll
    for (int p = 0; p < 2; ++p)
      *(short8*)((char*)Bs + swoff(rb2[p], kb2[p])) = cvt8(br[p][0], br[p][1]);
    __syncthreads();
    if (k0 + BK < DFF) loadg(k0 + BK);

#pragma unroll
    for (int ks = 0; ks < 2; ++ks) {
      const int kc = ks * 4 + (lane >> 4);
      short8 af[4];
#pragma unroll
      for (int nf = 0; nf < 4; ++nf) {
        const int r = wr * 64 + nf * 16 + (lane & 15);
        af[nf] = *(const short8*)((const char*)As + swoff(r, kc));
      }
#pragma unroll
      for (int ff = 0; ff < 2; ++ff) {
        const int r = wc * 32 + ff * 16 + (lane & 15);
        const short8 bb = *(const short8*)((const char*)Bs + swoff(r, kc));
#pragma unroll
        for (int nf = 0; nf < 4; ++nf)
          acc[nf][ff] = __builtin_amdgcn_mfma_f32_16x16x32_bf16(af[nf], bb, acc[nf][ff], 0, 0, 0);
      }
    }
  }

#pragma unroll
  for (int nf = 0; nf < 4; ++nf) {
#pragma unroll
    for (int j = 0; j < 4; ++j) {
      const int n = n0 + wr * 64 + nf * 16 + (lane >> 4) * 4 + j;
#pragma unroll
      for (int ff = 0; ff < 2; ++ff) {
        const int d = d0 + wc * 32 + ff * 16 + (lane & 15);
        float* op = &out[(size_t)n * DMODEL + d];
        if (e == 0) *op = acc[nf][ff][j];
        else        *op += acc[nf][ff][j];
      }
    }
  }
}

// ---------------------------------------------------------------------------
extern "C" void kernel_launch(void* const* d_in, const int* in_sizes, int n_in,
                              void* d_out, int out_size, void* d_ws, size_t ws_size,
                              hipStream_t stream) {
  const float* x      = (const float*)d_in[0];
  const float* W_A    = (const float*)d_in[1];
  const float* gscale = (const float*)d_in[2];
  const float* gbias  = (const float*)d_in[3];
  const float* wg     = (const float*)d_in[4];
  const float* wu     = (const float*)d_in[5];
  const float* wd     = (const float*)d_in[6];

  float* out       = (float*)d_out;                // [N, D]
  float* score_out = out + (size_t)NTOK * DMODEL;  // [N, E]

  const size_t CNT = (size_t)16777216;  // elems of x and of each weight tensor
  const size_t gw_b = (size_t)NTOK * NEXP * 4;
  const size_t need_big = gw_b + 4 * (CNT * 2)            // xb, wgb, wub, wdb
                          + (size_t)NTOK * DFF * 4        // Gf fp32
                          + (size_t)NTOK * DFF * 2;       // Hb bf16

  float* gw = (float*)d_ws;

  if (ws_size >= need_big) {
    char* p = (char*)d_ws + gw_b;
    short* xb  = (short*)p; p += CNT * 2;
    short* wgb = (short*)p; p += CNT * 2;
    short* wub = (short*)p; p += CNT * 2;
    short* wdb = (short*)p; p += CNT * 2;
    float* Gf  = (float*)p; p += (size_t)NTOK * DFF * 4;
    short* Hb  = (short*)p;

    const int n8 = (int)(CNT / 8);
    cvt_kernel<<<2048, 256, 0, stream>>>(x,  xb,  n8);
    cvt_kernel<<<2048, 256, 0, stream>>>(wg, wgb, n8);
    cvt_kernel<<<2048, 256, 0, stream>>>(wu, wub, n8);
    cvt_kernel<<<2048, 256, 0, stream>>>(wd, wdb, n8);

    gate_kernel<<<NTOK, 256, 0, stream>>>(x, W_A, gscale, gbias, gw, score_out);

    for (int e = 0; e < NEXP; ++e) {
      const short* wgbe = wgb + (size_t)e * DFF * DMODEL;
      const short* wube = wub + (size_t)e * DFF * DMODEL;
      const short* wdbe = wdb + (size_t)e * DMODEL * DFF;
      // G = x · wg^T   [8192 x 1024], K = 2048
      gemm_bt<0><<<dim3(DFF / 128, NTOK / 128), 256, 0, stream>>>(
          xb, wgbe, DMODEL, DFF, Gf, nullptr, nullptr, nullptr, e);
      // H = silu(G) * (x · wu^T) * gw   -> bf16
      gemm_bt<1><<<dim3(DFF / 128, NTOK / 128), 256, 0, stream>>>(
          xb, wube, DMODEL, DFF, Gf, Hb, nullptr, gw, e);
      // out (+)= H · wd^T   [8192 x 2048], K = 1024
      gemm_bt<2><<<dim3(DMODEL / 128, NTOK / 128), 256, 0, stream>>>(
          Hb, wdbe, DFF, DMODEL, nullptr, nullptr, out, nullptr, e);
    }
  } else {
    // Fallback: R3 structure (proven). ws: gw | Hb bf16 [N,F]
    short* Hb = (short*)((char*)d_ws + gw_b);
    gate_kernel<<<NTOK, 256, 0, stream>>>(x, W_A, gscale, gbias, gw, score_out);
    for (int e = 0; e < NEXP; ++e) {
      ffn1_mfma<<<dim3(DFF / BT, NTOK / BM), 256, 0, stream>>>(x, wg, wu, gw, Hb, e);
      ffn2_mfma<<<dim3(DMODEL / BT, NTOK / BM), 256, 0, stream>>>(Hb, wd, out, e);
    }
  }
}

// Round 5
// 1286.718 us; speedup vs baseline: 1.4848x; 1.4848x over previous
//
#include <hip/hip_runtime.h>
#include <hip/hip_bf16.h>
#include <math.h>

// Problem constants
#define NTOK   8192
#define DMODEL 2048
#define NEXP   8
#define RGATE  8
#define DFF    1024

#define NEG_SENTINEL (-3.0e38f)

using f32x4  = __attribute__((ext_vector_type(4))) float;
using short8 = __attribute__((ext_vector_type(8))) short;

// RNE float->bf16
static __device__ __forceinline__ short f2bf(float f) {
  union { float f; unsigned u; } v; v.f = f;
  unsigned r = v.u + 0x7fffu + ((v.u >> 16) & 1u);
  return (short)(r >> 16);
}
static __device__ __forceinline__ short8 cvt8(const float4 a, const float4 b) {
  short8 o;
  o[0] = f2bf(a.x); o[1] = f2bf(a.y); o[2] = f2bf(a.z); o[3] = f2bf(a.w);
  o[4] = f2bf(b.x); o[5] = f2bf(b.y); o[6] = f2bf(b.z); o[7] = f2bf(b.w);
  return o;
}

#define GLOAD_LDS(gp, lp)                                                  \
  __builtin_amdgcn_global_load_lds(                                        \
      (const __attribute__((address_space(1))) void*)(gp),                 \
      (__attribute__((address_space(3))) void*)(lp), 16, 0, 0)

// ---------------------------------------------------------------------------
// prep_zero: zero out[N,D] (poison-safe accumulate base) + idx lists + cnts.
// ---------------------------------------------------------------------------
__global__ __launch_bounds__(256) void prep_zero(
    float4* __restrict__ out4, int4* __restrict__ ic4) {
  const int stride = gridDim.x * blockDim.x;
  const float4 z4 = make_float4(0.f, 0.f, 0.f, 0.f);
  for (int i = blockIdx.x * blockDim.x + threadIdx.x;
       i < NTOK * DMODEL / 4; i += stride) {
    out4[i] = z4;
    if (i < (NEXP * NTOK + 16) / 4) ic4[i] = make_int4(0, 0, 0, 0);
  }
}

// ---------------------------------------------------------------------------
// cvt: fp32 -> bf16 plain
// ---------------------------------------------------------------------------
__global__ __launch_bounds__(256) void cvt_kernel(
    const float* __restrict__ in, short* __restrict__ out, int n8) {
  const int stride = gridDim.x * blockDim.x;
  for (int i = blockIdx.x * blockDim.x + threadIdx.x; i < n8; i += stride) {
    const float4 a = ((const float4*)in)[(size_t)i * 2];
    const float4 b = ((const float4*)in)[(size_t)i * 2 + 1];
    ((short8*)out)[i] = cvt8(a, b);
  }
}

// ---------------------------------------------------------------------------
// pack_gu: build wgu[e][r][d] bf16 with wg/wu rows interleaved in 16-groups:
// r -> pair p=r>>5, sel=(r>>4)&1, f=p*16+(r&15); row = (sel?wu:wg)[e,f,:].
// Then a 128-col GEMM tile holds g in even 16-col frags, u in odd ones.
// ---------------------------------------------------------------------------
__global__ __launch_bounds__(256) void pack_gu(
    const float* __restrict__ wg, const float* __restrict__ wu,
    short* __restrict__ wgu) {
  const int stride = gridDim.x * blockDim.x;
  const int total = NEXP * 2048 * (DMODEL / 8);  // 8-elem chunks
  for (int i = blockIdx.x * blockDim.x + threadIdx.x; i < total; i += stride) {
    const int c = i & 255;            // chunk within row (DMODEL/8 = 256)
    const int r = (i >> 8) & 2047;    // packed row
    const int e = i >> 19;
    const int sel = (r >> 4) & 1;
    const int f = ((r >> 5) << 4) + (r & 15);
    const float* src = (sel ? wu : wg) + ((size_t)(e * DFF + f)) * DMODEL + c * 8;
    const float4 a = *(const float4*)src;
    const float4 b = *(const float4*)(src + 4);
    ((short8*)wgu)[i] = cvt8(a, b);   // layout index == i by construction
  }
}

// ---------------------------------------------------------------------------
// gate8: 8 tokens per block. Bit-identical per-token math to the R2 gate
// (same k sequence per lane, same shfl tree, same r-order) — mask stability.
// Adds per-expert active-token list append (order nondeterministic; all
// downstream per-token results are order-independent).
// ---------------------------------------------------------------------------
__global__ __launch_bounds__(256) void gate8_kernel(
    const float* __restrict__ x, const float* __restrict__ W_A,
    const float* __restrict__ gscale, const float* __restrict__ gbias,
    float* __restrict__ gw, float* __restrict__ score_out,
    int* __restrict__ idx, int* __restrict__ cnt) {
  __shared__ float xs[8][1024];
  __shared__ float gh[8][64];
  const int tok0 = blockIdx.x * 8;
  const int tid = threadIdx.x;
  const int g = tid >> 2, l = tid & 3;
  const float* wa = W_A + (size_t)g * DMODEL;
  float s[8] = {0.f, 0.f, 0.f, 0.f, 0.f, 0.f, 0.f, 0.f};

  for (int half = 0; half < 2; ++half) {
    __syncthreads();  // prev half's readers done
    for (int i = tid; i < 8 * 256; i += 256) {
      const int row = i >> 8, c4 = i & 255;
      ((float4*)xs[row])[c4] =
          ((const float4*)(x + (size_t)(tok0 + row) * DMODEL + half * 1024))[c4];
    }
    __syncthreads();
    for (int k = l; k < 256; k += 4) {
      const float4 wv = ((const float4*)wa)[half * 256 + k];
#pragma unroll
      for (int tk = 0; tk < 8; ++tk) {
        const float4 xv = ((const float4*)xs[tk])[k];
        s[tk] += xv.x * wv.x + xv.y * wv.y + xv.z * wv.z + xv.w * wv.w;
      }
    }
  }
#pragma unroll
  for (int tk = 0; tk < 8; ++tk) {
    s[tk] += __shfl_xor(s[tk], 1);
    s[tk] += __shfl_xor(s[tk], 2);
  }
  if (l == 0) {
#pragma unroll
    for (int tk = 0; tk < 8; ++tk) gh[tk][g] = s[tk];
  }
  __syncthreads();

  if (tid < 64) {
    const int tk = tid >> 3, e = tid & 7;
    const int n = tok0 + tk;
    float ss = 0.f;
#pragma unroll
    for (int r = 0; r < RGATE; ++r) { const float v = gh[tk][e * 8 + r]; ss += v * v; }
    const float score = sqrtf(ss) * gscale[e] - gbias[e];
    const bool m = (score >= 0.0f);
    const float sig = 1.0f / (1.0f + expf(-score));
    gw[(size_t)n * NEXP + e] = m ? sig : 0.0f;
    score_out[(size_t)n * NEXP + e] = m ? score : NEG_SENTINEL;
    if (m) {
      const int slot = atomicAdd(&cnt[e], 1);
      idx[(size_t)e * NTOK + slot] = n;
    }
  }
}

// ---------------------------------------------------------------------------
// ffn1_gemm: compact-row fused G+U GEMM + SwiGLU epilogue.
// C tile 128(compact n) x 128(packed col), BK=64, 4 waves of 64x64.
// A rows gathered via idx (per-lane global src for global_load_lds).
// acc[nf][2q] = g, acc[nf][2q+1] = u for the same f (packed weights).
// ---------------------------------------------------------------------------
__global__ __launch_bounds__(256) void ffn1_gemm(
    const short* __restrict__ xb, const short* __restrict__ wgu,
    const int* __restrict__ idx, const int* __restrict__ cnt,
    const float* __restrict__ gw, short* __restrict__ Hb, int e) {
  const int cnte = cnt[e];
  const int n0 = blockIdx.y * 128;
  if (n0 >= cnte) return;
  __shared__ __align__(16) short As[128 * 64];
  __shared__ __align__(16) short Bs[128 * 64];

  const int c0 = blockIdx.x * 128;
  const int t = threadIdx.x, lane = t & 63, wid = t >> 6;
  const int wr = wid >> 1, wc = wid & 1;
  const int* idxe = idx + (size_t)e * NTOK;
  const short* Bb = wgu + (size_t)e * 2048 * DMODEL + (size_t)c0 * DMODEL;
  const int lr = lane >> 3, lk = (lane & 7) * 8;

  int tokA[4];
#pragma unroll
  for (int i = 0; i < 4; ++i) tokA[i] = idxe[n0 + wid * 32 + i * 8 + lr];

  f32x4 acc[4][4];
#pragma unroll
  for (int i = 0; i < 4; ++i)
#pragma unroll
    for (int j = 0; j < 4; ++j) acc[i][j] = (f32x4){0.f, 0.f, 0.f, 0.f};

  for (int k0 = 0; k0 < DMODEL; k0 += 64) {
    __syncthreads();
#pragma unroll
    for (int i = 0; i < 4; ++i) {
      const int row = wid * 32 + i * 8;
      GLOAD_LDS(xb + (size_t)tokA[i] * DMODEL + k0 + lk, (char*)As + row * 128);
      GLOAD_LDS(Bb + (size_t)(row + lr) * DMODEL + k0 + lk, (char*)Bs + row * 128);
    }
    __syncthreads();

#pragma unroll
    for (int ks = 0; ks < 2; ++ks) {
      short8 af[4], bf[4];
#pragma unroll
      for (int q = 0; q < 4; ++q) {
        af[q] = *(const short8*)((const char*)As +
                 (wr * 64 + q * 16 + (lane & 15)) * 128 + ks * 64 + (lane >> 4) * 16);
        bf[q] = *(const short8*)((const char*)Bs +
                 (wc * 64 + q * 16 + (lane & 15)) * 128 + ks * 64 + (lane >> 4) * 16);
      }
#pragma unroll
      for (int nf = 0; nf < 4; ++nf)
#pragma unroll
        for (int ff = 0; ff < 4; ++ff)
          acc[nf][ff] = __builtin_amdgcn_mfma_f32_16x16x32_bf16(af[nf], bf[ff], acc[nf][ff], 0, 0, 0);
    }
  }

  // Epilogue: h = silu(g)*u*gw -> Hb (compact rows), pads write exact 0.
  const int fbase = (c0 >> 1) + wc * 32;
#pragma unroll
  for (int nf = 0; nf < 4; ++nf) {
#pragma unroll
    for (int j = 0; j < 4; ++j) {
      const int n = n0 + wr * 64 + nf * 16 + (lane >> 4) * 4 + j;
      const bool valid = n < cnte;
      const int tok = valid ? idxe[n] : 0;
      const float gwv = gw[(size_t)tok * NEXP + e];
#pragma unroll
      for (int q = 0; q < 2; ++q) {
        const float gv = acc[nf][2 * q][j];
        const float uv = acc[nf][2 * q + 1][j];
        const float h = (gv / (1.f + expf(-gv))) * uv * gwv;
        Hb[(size_t)n * DFF + fbase + q * 16 + (lane & 15)] = valid ? f2bf(h) : (short)0;
      }
    }
  }
}

// ---------------------------------------------------------------------------
// ffn2_gemm: compact-row down GEMM, scatter-accumulate into out via idx.
// Pad rows (exact-zero H) scatter to dummy (benign races on garbage).
// ---------------------------------------------------------------------------
__global__ __launch_bounds__(256) void ffn2_gemm(
    const short* __restrict__ Hb, const short* __restrict__ wdb,
    const int* __restrict__ idx, const int* __restrict__ cnt,
    float* __restrict__ out, float* __restrict__ dummy, int e) {
  const int cnte = cnt[e];
  const int n0 = blockIdx.y * 128;
  if (n0 >= cnte) return;
  __shared__ __align__(16) short As[128 * 64];
  __shared__ __align__(16) short Bs[128 * 64];

  const int c0 = blockIdx.x * 128;
  const int t = threadIdx.x, lane = t & 63, wid = t >> 6;
  const int wr = wid >> 1, wc = wid & 1;
  const int* idxe = idx + (size_t)e * NTOK;
  const short* Ab = Hb + (size_t)n0 * DFF;
  const short* Bb = wdb + (size_t)e * DMODEL * DFF + (size_t)c0 * DFF;
  const int lr = lane >> 3, lk = (lane & 7) * 8;

  f32x4 acc[4][4];
#pragma unroll
  for (int i = 0; i < 4; ++i)
#pragma unroll
    for (int j = 0; j < 4; ++j) acc[i][j] = (f32x4){0.f, 0.f, 0.f, 0.f};

  for (int k0 = 0; k0 < DFF; k0 += 64) {
    __syncthreads();
#pragma unroll
    for (int i = 0; i < 4; ++i) {
      const int row = wid * 32 + i * 8;
      GLOAD_LDS(Ab + (size_t)(row + lr) * DFF + k0 + lk, (char*)As + row * 128);
      GLOAD_LDS(Bb + (size_t)(row + lr) * DFF + k0 + lk, (char*)Bs + row * 128);
    }
    __syncthreads();

#pragma unroll
    for (int ks = 0; ks < 2; ++ks) {
      short8 af[4], bf[4];
#pragma unroll
      for (int q = 0; q < 4; ++q) {
        af[q] = *(const short8*)((const char*)As +
                 (wr * 64 + q * 16 + (lane & 15)) * 128 + ks * 64 + (lane >> 4) * 16);
        bf[q] = *(const short8*)((const char*)Bs +
                 (wc * 64 + q * 16 + (lane & 15)) * 128 + ks * 64 + (lane >> 4) * 16);
      }
#pragma unroll
      for (int nf = 0; nf < 4; ++nf)
#pragma unroll
        for (int ff = 0; ff < 4; ++ff)
          acc[nf][ff] = __builtin_amdgcn_mfma_f32_16x16x32_bf16(af[nf], bf[ff], acc[nf][ff], 0, 0, 0);
    }
  }

#pragma unroll
  for (int nf = 0; nf < 4; ++nf) {
#pragma unroll
    for (int j = 0; j < 4; ++j) {
      const int n = n0 + wr * 64 + nf * 16 + (lane >> 4) * 4 + j;
      const bool valid = n < cnte;
      const int tok = valid ? idxe[n] : 0;
      float* bp = valid ? (out + (size_t)tok * DMODEL) : dummy;
#pragma unroll
      for (int ff = 0; ff < 4; ++ff) {
        const int d = c0 + wc * 64 + ff * 16 + (lane & 15);
        bp[valid ? d : (d & 2047)] += acc[nf][ff][j];
      }
    }
  }
}

// ===========================================================================
// FALLBACK PATH (small ws): R3 kernels verbatim — proven passing.
// ===========================================================================
#define BM 128
#define BT 64
#define BK 64
static __device__ __forceinline__ int swoff(int r, int kc) {
  return r * (BK * 2) + ((kc ^ (r & 7)) << 4);
}

__global__ __launch_bounds__(256) void gate_kernel(
    const float* __restrict__ x, const float* __restrict__ W_A,
    const float* __restrict__ gscale, const float* __restrict__ gbias,
    float* __restrict__ gw, float* __restrict__ score_out) {
  __shared__ float xs[DMODEL];
  __shared__ float gh[NEXP * RGATE];
  const int n = blockIdx.x;
  const float* xr = x + (size_t)n * DMODEL;
  for (int i = threadIdx.x; i < DMODEL / 4; i += 256)
    ((float4*)xs)[i] = ((const float4*)xr)[i];
  __syncthreads();
  const int g = threadIdx.x >> 2;
  const int l = threadIdx.x & 3;
  const float* wa = W_A + (size_t)g * DMODEL;
  float s = 0.f;
#pragma unroll 4
  for (int k = l; k < DMODEL / 4; k += 4) {
    const float4 xv = ((const float4*)xs)[k];
    const float4 wv = ((const float4*)wa)[k];
    s += xv.x * wv.x + xv.y * wv.y + xv.z * wv.z + xv.w * wv.w;
  }
  s += __shfl_xor(s, 1);
  s += __shfl_xor(s, 2);
  if (l == 0) gh[g] = s;
  __syncthreads();
  if (threadIdx.x < NEXP) {
    const int e = threadIdx.x;
    float ss = 0.f;
#pragma unroll
    for (int r = 0; r < RGATE; ++r) { const float v = gh[e * RGATE + r]; ss += v * v; }
    const float score = sqrtf(ss) * gscale[e] - gbias[e];
    const bool m = (score >= 0.0f);
    const float sig = 1.0f / (1.0f + expf(-score));
    gw[(size_t)n * NEXP + e] = m ? sig : 0.0f;
    score_out[(size_t)n * NEXP + e] = m ? score : NEG_SENTINEL;
  }
}

__global__ __launch_bounds__(256, 2) void ffn1_mfma(
    const float* __restrict__ x, const float* __restrict__ wgp,
    const float* __restrict__ wup, const float* __restrict__ gw,
    short* __restrict__ Hb, int e) {
  __shared__ __align__(16) short As[BM * BK];
  __shared__ __align__(16) short Bgs[BT * BK];
  __shared__ __align__(16) short Bus[BT * BK];
  const int n0 = blockIdx.y * BM;
  const int f0 = blockIdx.x * BT;
  const int t = threadIdx.x;
  const int lane = t & 63;
  const int wid = t >> 6;
  const int wr = wid >> 1;
  const int wc = wid & 1;
  const float* xa  = x   + (size_t)n0 * DMODEL;
  const float* wge = wgp + ((size_t)e * DFF + f0) * DMODEL;
  const float* wue = wup + ((size_t)e * DFF + f0) * DMODEL;
  int ra4[4], ka4[4], rb2[2], kb2[2];
#pragma unroll
  for (int p = 0; p < 4; ++p) { const int ci = p * 256 + t; ra4[p] = ci >> 3; ka4[p] = ci & 7; }
#pragma unroll
  for (int p = 0; p < 2; ++p) { const int ci = p * 256 + t; rb2[p] = ci >> 3; kb2[p] = ci & 7; }
  f32x4 accg[4][2], accu[4][2];
#pragma unroll
  for (int i = 0; i < 4; ++i)
#pragma unroll
    for (int j = 0; j < 2; ++j) {
      accg[i][j] = (f32x4){0.f, 0.f, 0.f, 0.f};
      accu[i][j] = (f32x4){0.f, 0.f, 0.f, 0.f};
    }
  float4 ar[4][2], bgr[2][2], bur[2][2];
  auto loadg = [&](int k0) {
#pragma unroll
    for (int p = 0; p < 4; ++p) {
      const float* s = &xa[(size_t)ra4[p] * DMODEL + k0 + ka4[p] * 8];
      ar[p][0] = *(const float4*)s; ar[p][1] = *(const float4*)(s + 4);
    }
#pragma unroll
    for (int p = 0; p < 2; ++p) {
      const float* sg = &wge[(size_t)rb2[p] * DMODEL + k0 + kb2[p] * 8];
      bgr[p][0] = *(const float4*)sg; bgr[p][1] = *(const float4*)(sg + 4);
      const float* su = &wue[(size_t)rb2[p] * DMODEL + k0 + kb2[p] * 8];
      bur[p][0] = *(const float4*)su; bur[p][1] = *(const float4*)(su + 4);
    }
  };
  loadg(0);
  for (int k0 = 0; k0 < DMODEL; k0 += BK) {
    __syncthreads();
#pragma unroll
    for (int p = 0; p < 4; ++p)
      *(short8*)((char*)As + swoff(ra4[p], ka4[p])) = cvt8(ar[p][0], ar[p][1]);
#pragma unroll
    for (int p = 0; p < 2; ++p) {
      *(short8*)((char*)Bgs + swoff(rb2[p], kb2[p])) = cvt8(bgr[p][0], bgr[p][1]);
      *(short8*)((char*)Bus + swoff(rb2[p], kb2[p])) = cvt8(bur[p][0], bur[p][1]);
    }
    __syncthreads();
    if (k0 + BK < DMODEL) loadg(k0 + BK);
#pragma unroll
    for (int ks = 0; ks < 2; ++ks) {
      const int kc = ks * 4 + (lane >> 4);
      short8 af[4];
#pragma unroll
      for (int nf = 0; nf < 4; ++nf) {
        const int r = wr * 64 + nf * 16 + (lane & 15);
        af[nf] = *(const short8*)((const char*)As + swoff(r, kc));
      }
#pragma unroll
      for (int ff = 0; ff < 2; ++ff) {
        const int r = wc * 32 + ff * 16 + (lane & 15);
        const short8 bg = *(const short8*)((const char*)Bgs + swoff(r, kc));
        const short8 bu = *(const short8*)((const char*)Bus + swoff(r, kc));
#pragma unroll
        for (int nf = 0; nf < 4; ++nf) {
          accg[nf][ff] = __builtin_amdgcn_mfma_f32_16x16x32_bf16(af[nf], bg, accg[nf][ff], 0, 0, 0);
          accu[nf][ff] = __builtin_amdgcn_mfma_f32_16x16x32_bf16(af[nf], bu, accu[nf][ff], 0, 0, 0);
        }
      }
    }
  }
#pragma unroll
  for (int nf = 0; nf < 4; ++nf) {
#pragma unroll
    for (int j = 0; j < 4; ++j) {
      const int n = n0 + wr * 64 + nf * 16 + (lane >> 4) * 4 + j;
      const float gwv = gw[(size_t)n * NEXP + e];
#pragma unroll
      for (int ff = 0; ff < 2; ++ff) {
        const float g = accg[nf][ff][j];
        const float u = accu[nf][ff][j];
        const float h = (g / (1.f + expf(-g))) * u * gwv;
        const int f = f0 + wc * 32 + ff * 16 + (lane & 15);
        Hb[(size_t)n * DFF + f] = f2bf(h);
      }
    }
  }
}

__global__ __launch_bounds__(256, 2) void ffn2_mfma(
    const short* __restrict__ Hb, const float* __restrict__ wdp,
    float* __restrict__ out, int e) {
  __shared__ __align__(16) short As[BM * BK];
  __shared__ __align__(16) short Bs[BT * BK];
  const int n0 = blockIdx.y * BM;
  const int d0 = blockIdx.x * BT;
  const int t = threadIdx.x;
  const int lane = t & 63;
  const int wid = t >> 6;
  const int wr = wid >> 1;
  const int wc = wid & 1;
  const short* Ha  = Hb  + (size_t)n0 * DFF;
  const float* wde = wdp + ((size_t)e * DMODEL + d0) * DFF;
  int ra4[4], ka4[4], rb2[2], kb2[2];
#pragma unroll
  for (int p = 0; p < 4; ++p) { const int ci = p * 256 + t; ra4[p] = ci >> 3; ka4[p] = ci & 7; }
#pragma unroll
  for (int p = 0; p < 2; ++p) { const int ci = p * 256 + t; rb2[p] = ci >> 3; kb2[p] = ci & 7; }
  f32x4 acc[4][2];
#pragma unroll
  for (int i = 0; i < 4; ++i)
#pragma unroll
    for (int j = 0; j < 2; ++j) acc[i][j] = (f32x4){0.f, 0.f, 0.f, 0.f};
  short8 ar[4];
  float4 br[2][2];
  auto loadg = [&](int k0) {
#pragma unroll
    for (int p = 0; p < 4; ++p)
      ar[p] = *(const short8*)&Ha[(size_t)ra4[p] * DFF + k0 + ka4[p] * 8];
#pragma unroll
    for (int p = 0; p < 2; ++p) {
      const float* s = &wde[(size_t)rb2[p] * DFF + k0 + kb2[p] * 8];
      br[p][0] = *(const float4*)s; br[p][1] = *(const float4*)(s + 4);
    }
  };
  loadg(0);
  for (int k0 = 0; k0 < DFF; k0 += BK) {
    __syncthreads();
#pragma unroll
    for (int p = 0; p < 4; ++p)
      *(short8*)((char*)As + swoff(ra4[p], ka4[p])) = ar[p];
#pragma unroll
    for (int p = 0; p < 2; ++p)
      *(short8*)((char*)Bs + swoff(rb2[p], kb2[p])) = cvt8(br[p][0], br[p][1]);
    __syncthreads();
    if (k0 + BK < DFF) loadg(k0 + BK);
#pragma unroll
    for (int ks = 0; ks < 2; ++ks) {
      const int kc = ks * 4 + (lane >> 4);
      short8 af[4];
#pragma unroll
      for (int nf = 0; nf < 4; ++nf) {
        const int r = wr * 64 + nf * 16 + (lane & 15);
        af[nf] = *(const short8*)((const char*)As + swoff(r, kc));
      }
#pragma unroll
      for (int ff = 0; ff < 2; ++ff) {
        const int r = wc * 32 + ff * 16 + (lane & 15);
        const short8 bb = *(const short8*)((const char*)Bs + swoff(r, kc));
#pragma unroll
        for (int nf = 0; nf < 4; ++nf)
          acc[nf][ff] = __builtin_amdgcn_mfma_f32_16x16x32_bf16(af[nf], bb, acc[nf][ff], 0, 0, 0);
      }
    }
  }
#pragma unroll
  for (int nf = 0; nf < 4; ++nf) {
#pragma unroll
    for (int j = 0; j < 4; ++j) {
      const int n = n0 + wr * 64 + nf * 16 + (lane >> 4) * 4 + j;
#pragma unroll
      for (int ff = 0; ff < 2; ++ff) {
        const int d = d0 + wc * 32 + ff * 16 + (lane & 15);
        float* op = &out[(size_t)n * DMODEL + d];
        if (e == 0) *op = acc[nf][ff][j];
        else        *op += acc[nf][ff][j];
      }
    }
  }
}

// ---------------------------------------------------------------------------
extern "C" void kernel_launch(void* const* d_in, const int* in_sizes, int n_in,
                              void* d_out, int out_size, void* d_ws, size_t ws_size,
                              hipStream_t stream) {
  const float* x      = (const float*)d_in[0];
  const float* W_A    = (const float*)d_in[1];
  const float* gscale = (const float*)d_in[2];
  const float* gbias  = (const float*)d_in[3];
  const float* wg     = (const float*)d_in[4];
  const float* wu     = (const float*)d_in[5];
  const float* wd     = (const float*)d_in[6];

  float* out       = (float*)d_out;                // [N, D]
  float* score_out = out + (size_t)NTOK * DMODEL;  // [N, E]

  // ws layout (big path):
  // gw f32[N*E] | idx i32[E*N] | cnt i32[16] | dummy f32[D] |
  // xb bf16[N*D] | wgu bf16[E*2048*D] | wdb bf16[E*D*F] | Hb bf16[N*F]
  const size_t CNT = (size_t)16777216;
  size_t off = 0;
  float* gw    = (float*)((char*)d_ws + off); off += (size_t)NTOK * NEXP * 4;
  int*   idx   = (int*)((char*)d_ws + off);   off += (size_t)NEXP * NTOK * 4;
  int*   cnt   = (int*)((char*)d_ws + off);   off += 16 * 4;
  float* dummy = (float*)((char*)d_ws + off); off += (size_t)DMODEL * 4;
  short* xb    = (short*)((char*)d_ws + off); off += CNT * 2;
  short* wgu   = (short*)((char*)d_ws + off); off += CNT * 4;  // 2048 rows/expert
  short* wdb   = (short*)((char*)d_ws + off); off += CNT * 2;
  short* Hb    = (short*)((char*)d_ws + off); off += (size_t)NTOK * DFF * 2;
  const size_t need_big = off;

  if (ws_size >= need_big) {
    prep_zero<<<2048, 256, 0, stream>>>((float4*)out, (int4*)idx);
    cvt_kernel<<<2048, 256, 0, stream>>>(x,  xb,  (int)(CNT / 8));
    cvt_kernel<<<2048, 256, 0, stream>>>(wd, wdb, (int)(CNT / 8));
    pack_gu<<<2048, 256, 0, stream>>>(wg, wu, wgu);
    gate8_kernel<<<NTOK / 8, 256, 0, stream>>>(x, W_A, gscale, gbias, gw,
                                               score_out, idx, cnt);
    for (int e = 0; e < NEXP; ++e) {
      ffn1_gemm<<<dim3(2048 / 128, NTOK / 128), 256, 0, stream>>>(
          xb, wgu, idx, cnt, gw, Hb, e);
      ffn2_gemm<<<dim3(DMODEL / 128, NTOK / 128), 256, 0, stream>>>(
          Hb, wdb, idx, cnt, out, dummy, e);
    }
  } else {
    // Fallback: R3 structure (proven). ws: gw | Hb bf16 [N,F]
    const size_t gw_b = (size_t)NTOK * NEXP * 4;
    short* Hbf = (short*)((char*)d_ws + gw_b);
    gate_kernel<<<NTOK, 256, 0, stream>>>(x, W_A, gscale, gbias, gw, score_out);
    for (int e = 0; e < NEXP; ++e) {
      ffn1_mfma<<<dim3(DFF / BT, NTOK / BM), 256, 0, stream>>>(x, wg, wu, gw, Hbf, e);
      ffn2_mfma<<<dim3(DMODEL / BT, NTOK / BM), 256, 0, stream>>>(Hbf, wd, out, e);
    }
  }
}

// Round 6
// 1235.440 us; speedup vs baseline: 1.5464x; 1.0415x over previous
//
#include <hip/hip_runtime.h>
#include <hip/hip_bf16.h>
#include <math.h>

// Problem constants
#define NTOK   8192
#define DMODEL 2048
#define NEXP   8
#define RGATE  8
#define DFF    1024

#define NEG_SENTINEL (-3.0e38f)

using f32x4  = __attribute__((ext_vector_type(4))) float;
using short8 = __attribute__((ext_vector_type(8))) short;

// RNE float->bf16
static __device__ __forceinline__ short f2bf(float f) {
  union { float f; unsigned u; } v; v.f = f;
  unsigned r = v.u + 0x7fffu + ((v.u >> 16) & 1u);
  return (short)(r >> 16);
}
static __device__ __forceinline__ short8 cvt8(const float4 a, const float4 b) {
  short8 o;
  o[0] = f2bf(a.x); o[1] = f2bf(a.y); o[2] = f2bf(a.z); o[3] = f2bf(a.w);
  o[4] = f2bf(b.x); o[5] = f2bf(b.y); o[6] = f2bf(b.z); o[7] = f2bf(b.w);
  return o;
}

#define GLOAD_LDS(gp, lp)                                                  \
  __builtin_amdgcn_global_load_lds(                                        \
      (const __attribute__((address_space(1))) void*)(gp),                 \
      (__attribute__((address_space(3))) void*)(lp), 16, 0, 0)

// ---------------------------------------------------------------------------
// prep_zero: zero out[N,D] (accumulate base over poison) + idx lists + cnt.
// ---------------------------------------------------------------------------
__global__ __launch_bounds__(256) void prep_zero(
    float4* __restrict__ out4, int4* __restrict__ ic4) {
  const int stride = gridDim.x * blockDim.x;
  const float4 z4 = make_float4(0.f, 0.f, 0.f, 0.f);
  for (int i = blockIdx.x * blockDim.x + threadIdx.x;
       i < NTOK * DMODEL / 4; i += stride) {
    out4[i] = z4;
    if (i < (NEXP * NTOK + 16) / 4) ic4[i] = make_int4(0, 0, 0, 0);
  }
}

// ---------------------------------------------------------------------------
// cvt: fp32 -> bf16
// ---------------------------------------------------------------------------
__global__ __launch_bounds__(256) void cvt_kernel(
    const float* __restrict__ in, short* __restrict__ out, int n8) {
  const int stride = gridDim.x * blockDim.x;
  for (int i = blockIdx.x * blockDim.x + threadIdx.x; i < n8; i += stride) {
    const float4 a = ((const float4*)in)[(size_t)i * 2];
    const float4 b = ((const float4*)in)[(size_t)i * 2 + 1];
    ((short8*)out)[i] = cvt8(a, b);
  }
}

// ---------------------------------------------------------------------------
// pack_gu: interleave wg/wu rows in 16-row groups (g in even 16-col frags of
// a 128-col GEMM tile, u in odd).
// ---------------------------------------------------------------------------
__global__ __launch_bounds__(256) void pack_gu(
    const float* __restrict__ wg, const float* __restrict__ wu,
    short* __restrict__ wgu) {
  const int stride = gridDim.x * blockDim.x;
  const int total = NEXP * 2048 * (DMODEL / 8);
  for (int i = blockIdx.x * blockDim.x + threadIdx.x; i < total; i += stride) {
    const int c = i & 255;
    const int r = (i >> 8) & 2047;
    const int e = i >> 19;
    const int sel = (r >> 4) & 1;
    const int f = ((r >> 5) << 4) + (r & 15);
    const float* src = (sel ? wu : wg) + ((size_t)(e * DFF + f)) * DMODEL + c * 8;
    const float4 a = *(const float4*)src;
    const float4 b = *(const float4*)(src + 4);
    ((short8*)wgu)[i] = cvt8(a, b);
  }
}

// ---------------------------------------------------------------------------
// gate_v3: register outer-product gate. 32 tokens/block, 256 blocks (1/CU).
// 256 thr = 64 positions (8 tok-grp x 8 row-grp) x 4 k-slices.
// Thread tile: 4 tokens x 8 rows, fp32 acc; x and W_A read straight from
// global (L1/L2-hot), double-buffered. No LDS in the main loop.
// k-slice ks covers k in {ks*4+16j}; shfl-xor(1,2) combines slices.
// ---------------------------------------------------------------------------
__global__ __launch_bounds__(256) void gate_v3(
    const float* __restrict__ x, const float* __restrict__ W_A,
    const float* __restrict__ gscale, const float* __restrict__ gbias,
    float* __restrict__ gw, float* __restrict__ score_out,
    int* __restrict__ idx, int* __restrict__ cnt) {
  __shared__ float ghs[32][65];
  const int tok0 = blockIdx.x * 32;
  const int t = threadIdx.x;
  const int ks = t & 3;
  const int pos = t >> 2;   // 0..63
  const int tg = pos & 7;   // token group (4 tokens)
  const int rg = pos >> 3;  // row group (8 rows)
  const float* xp = x + (size_t)(tok0 + tg * 4) * DMODEL;
  const float* wp = W_A + (size_t)(rg * 8) * DMODEL;

  float acc[4][8];
#pragma unroll
  for (int i = 0; i < 4; ++i)
#pragma unroll
    for (int r = 0; r < 8; ++r) acc[i][r] = 0.f;

  float4 xa_[4], wa_[8], xb_[4], wb_[8];
  auto loadj = [&](int j, float4* xv, float4* wv) {
    const int k = ks * 4 + j * 16;
#pragma unroll
    for (int i = 0; i < 4; ++i) xv[i] = *(const float4*)(xp + (size_t)i * DMODEL + k);
#pragma unroll
    for (int r = 0; r < 8; ++r) wv[r] = *(const float4*)(wp + (size_t)r * DMODEL + k);
  };
  auto fmaj = [&](const float4* xv, const float4* wv) {
#pragma unroll
    for (int i = 0; i < 4; ++i)
#pragma unroll
      for (int r = 0; r < 8; ++r) {
        acc[i][r] = fmaf(xv[i].x, wv[r].x, acc[i][r]);
        acc[i][r] = fmaf(xv[i].y, wv[r].y, acc[i][r]);
        acc[i][r] = fmaf(xv[i].z, wv[r].z, acc[i][r]);
        acc[i][r] = fmaf(xv[i].w, wv[r].w, acc[i][r]);
      }
  };

  loadj(0, xa_, wa_);
#pragma unroll 1
  for (int j = 0; j < 128; j += 2) {
    loadj(j + 1, xb_, wb_);
    fmaj(xa_, wa_);
    if (j + 2 < 128) loadj(j + 2, xa_, wa_);
    fmaj(xb_, wb_);
  }

  // combine k-slices (lanes ks=0..3 adjacent)
#pragma unroll
  for (int i = 0; i < 4; ++i)
#pragma unroll
    for (int r = 0; r < 8; ++r) {
      float v = acc[i][r];
      v += __shfl_xor(v, 1);
      v += __shfl_xor(v, 2);
      acc[i][r] = v;
    }
  if (ks == 0) {
#pragma unroll
    for (int i = 0; i < 4; ++i)
#pragma unroll
      for (int r = 0; r < 8; ++r) ghs[tg * 4 + i][rg * 8 + r] = acc[i][r];
  }
  __syncthreads();

  // 32 tok x 8 experts = 256 pairs, one per thread
  {
    const int tk = t >> 3, e = t & 7;
    const int n = tok0 + tk;
    float ss = 0.f;
#pragma unroll
    for (int r = 0; r < RGATE; ++r) { const float v = ghs[tk][e * 8 + r]; ss += v * v; }
    const float score = sqrtf(ss) * gscale[e] - gbias[e];
    const bool m = (score >= 0.0f);
    const float sig = 1.0f / (1.0f + expf(-score));
    gw[(size_t)n * NEXP + e] = m ? sig : 0.0f;
    score_out[(size_t)n * NEXP + e] = m ? score : NEG_SENTINEL;
    if (m) {
      const int slot = atomicAdd(&cnt[e], 1);
      idx[(size_t)e * NTOK + slot] = n;
    }
  }
}

// ---------------------------------------------------------------------------
// ffn1_gemm: compact-row fused G+U GEMM + SwiGLU epilogue. e_arg < 0 =>
// expert = blockIdx.z, per-expert Hb region (fused single dispatch).
// ---------------------------------------------------------------------------
__global__ __launch_bounds__(256) void ffn1_gemm(
    const short* __restrict__ xb, const short* __restrict__ wgu,
    const int* __restrict__ idx, const int* __restrict__ cnt,
    const float* __restrict__ gw, short* __restrict__ Hb, int e_arg) {
  const int e = (e_arg < 0) ? (int)blockIdx.z : e_arg;
  short* __restrict__ Hbe = Hb + ((e_arg < 0) ? (size_t)e * NTOK * DFF : (size_t)0);
  const int cnte = cnt[e];
  const int n0 = blockIdx.y * 128;
  if (n0 >= cnte) return;
  __shared__ __align__(16) short As[128 * 64];
  __shared__ __align__(16) short Bs[128 * 64];

  const int c0 = blockIdx.x * 128;
  const int t = threadIdx.x, lane = t & 63, wid = t >> 6;
  const int wr = wid >> 1, wc = wid & 1;
  const int* idxe = idx + (size_t)e * NTOK;
  const short* Bb = wgu + (size_t)e * 2048 * DMODEL + (size_t)c0 * DMODEL;
  const int lr = lane >> 3, lk = (lane & 7) * 8;

  int tokA[4];
#pragma unroll
  for (int i = 0; i < 4; ++i) tokA[i] = idxe[n0 + wid * 32 + i * 8 + lr];

  f32x4 acc[4][4];
#pragma unroll
  for (int i = 0; i < 4; ++i)
#pragma unroll
    for (int j = 0; j < 4; ++j) acc[i][j] = (f32x4){0.f, 0.f, 0.f, 0.f};

  for (int k0 = 0; k0 < DMODEL; k0 += 64) {
    __syncthreads();
#pragma unroll
    for (int i = 0; i < 4; ++i) {
      const int row = wid * 32 + i * 8;
      GLOAD_LDS(xb + (size_t)tokA[i] * DMODEL + k0 + lk, (char*)As + row * 128);
      GLOAD_LDS(Bb + (size_t)(row + lr) * DMODEL + k0 + lk, (char*)Bs + row * 128);
    }
    __syncthreads();

#pragma unroll
    for (int ks = 0; ks < 2; ++ks) {
      short8 af[4], bf[4];
#pragma unroll
      for (int q = 0; q < 4; ++q) {
        af[q] = *(const short8*)((const char*)As +
                 (wr * 64 + q * 16 + (lane & 15)) * 128 + ks * 64 + (lane >> 4) * 16);
        bf[q] = *(const short8*)((const char*)Bs +
                 (wc * 64 + q * 16 + (lane & 15)) * 128 + ks * 64 + (lane >> 4) * 16);
      }
#pragma unroll
      for (int nf = 0; nf < 4; ++nf)
#pragma unroll
        for (int ff = 0; ff < 4; ++ff)
          acc[nf][ff] = __builtin_amdgcn_mfma_f32_16x16x32_bf16(af[nf], bf[ff], acc[nf][ff], 0, 0, 0);
    }
  }

  const int fbase = (c0 >> 1) + wc * 32;
#pragma unroll
  for (int nf = 0; nf < 4; ++nf) {
#pragma unroll
    for (int j = 0; j < 4; ++j) {
      const int n = n0 + wr * 64 + nf * 16 + (lane >> 4) * 4 + j;
      const bool valid = n < cnte;
      const int tok = valid ? idxe[n] : 0;
      const float gwv = gw[(size_t)tok * NEXP + e];
#pragma unroll
      for (int q = 0; q < 2; ++q) {
        const float gv = acc[nf][2 * q][j];
        const float uv = acc[nf][2 * q + 1][j];
        const float h = (gv / (1.f + expf(-gv))) * uv * gwv;
        Hbe[(size_t)n * DFF + fbase + q * 16 + (lane & 15)] = valid ? f2bf(h) : (short)0;
      }
    }
  }
}

// ---------------------------------------------------------------------------
// ffn2_gemm: compact-row down GEMM, scatter-accumulate into out via idx.
// Sequential per expert (RMW race-free, deterministic e-order).
// ---------------------------------------------------------------------------
__global__ __launch_bounds__(256) void ffn2_gemm(
    const short* __restrict__ Hbe, const short* __restrict__ wdb,
    const int* __restrict__ idx, const int* __restrict__ cnt,
    float* __restrict__ out, float* __restrict__ dummy, int e) {
  const int cnte = cnt[e];
  const int n0 = blockIdx.y * 128;
  if (n0 >= cnte) return;
  __shared__ __align__(16) short As[128 * 64];
  __shared__ __align__(16) short Bs[128 * 64];

  const int c0 = blockIdx.x * 128;
  const int t = threadIdx.x, lane = t & 63, wid = t >> 6;
  const int wr = wid >> 1, wc = wid & 1;
  const int* idxe = idx + (size_t)e * NTOK;
  const short* Ab = Hbe + (size_t)n0 * DFF;
  const short* Bb = wdb + (size_t)e * DMODEL * DFF + (size_t)c0 * DFF;
  const int lr = lane >> 3, lk = (lane & 7) * 8;

  f32x4 acc[4][4];
#pragma unroll
  for (int i = 0; i < 4; ++i)
#pragma unroll
    for (int j = 0; j < 4; ++j) acc[i][j] = (f32x4){0.f, 0.f, 0.f, 0.f};

  for (int k0 = 0; k0 < DFF; k0 += 64) {
    __syncthreads();
#pragma unroll
    for (int i = 0; i < 4; ++i) {
      const int row = wid * 32 + i * 8;
      GLOAD_LDS(Ab + (size_t)(row + lr) * DFF + k0 + lk, (char*)As + row * 128);
      GLOAD_LDS(Bb + (size_t)(row + lr) * DFF + k0 + lk, (char*)Bs + row * 128);
    }
    __syncthreads();

#pragma unroll
    for (int ks = 0; ks < 2; ++ks) {
      short8 af[4], bf[4];
#pragma unroll
      for (int q = 0; q < 4; ++q) {
        af[q] = *(const short8*)((const char*)As +
                 (wr * 64 + q * 16 + (lane & 15)) * 128 + ks * 64 + (lane >> 4) * 16);
        bf[q] = *(const short8*)((const char*)Bs +
                 (wc * 64 + q * 16 + (lane & 15)) * 128 + ks * 64 + (lane >> 4) * 16);
      }
#pragma unroll
      for (int nf = 0; nf < 4; ++nf)
#pragma unroll
        for (int ff = 0; ff < 4; ++ff)
          acc[nf][ff] = __builtin_amdgcn_mfma_f32_16x16x32_bf16(af[nf], bf[ff], acc[nf][ff], 0, 0, 0);
    }
  }

#pragma unroll
  for (int nf = 0; nf < 4; ++nf) {
#pragma unroll
    for (int j = 0; j < 4; ++j) {
      const int n = n0 + wr * 64 + nf * 16 + (lane >> 4) * 4 + j;
      const bool valid = n < cnte;
      const int tok = valid ? idxe[n] : 0;
      float* bp = valid ? (out + (size_t)tok * DMODEL) : dummy;
#pragma unroll
      for (int ff = 0; ff < 4; ++ff) {
        const int d = c0 + wc * 64 + ff * 16 + (lane & 15);
        bp[valid ? d : (d & 2047)] += acc[nf][ff][j];
      }
    }
  }
}

// ---------------------------------------------------------------------------
extern "C" void kernel_launch(void* const* d_in, const int* in_sizes, int n_in,
                              void* d_out, int out_size, void* d_ws, size_t ws_size,
                              hipStream_t stream) {
  const float* x      = (const float*)d_in[0];
  const float* W_A    = (const float*)d_in[1];
  const float* gscale = (const float*)d_in[2];
  const float* gbias  = (const float*)d_in[3];
  const float* wg     = (const float*)d_in[4];
  const float* wu     = (const float*)d_in[5];
  const float* wd     = (const float*)d_in[6];

  float* out       = (float*)d_out;                // [N, D]
  float* score_out = out + (size_t)NTOK * DMODEL;  // [N, E]

  // ws layout: gw f32[N*E] | idx i32[E*N] | cnt i32[16] | dummy f32[D] |
  //            xb bf16[N*D] | wgu bf16[E*2048*D] | wdb bf16[E*D*F] | Hb bf16
  const size_t CNT = (size_t)16777216;
  size_t off = 0;
  float* gw    = (float*)((char*)d_ws + off); off += (size_t)NTOK * NEXP * 4;
  int*   idx   = (int*)((char*)d_ws + off);   off += (size_t)NEXP * NTOK * 4;
  int*   cnt   = (int*)((char*)d_ws + off);   off += 16 * 4;
  float* dummy = (float*)((char*)d_ws + off); off += (size_t)DMODEL * 4;
  short* xb    = (short*)((char*)d_ws + off); off += CNT * 2;
  short* wgu   = (short*)((char*)d_ws + off); off += CNT * 4;
  short* wdb   = (short*)((char*)d_ws + off); off += CNT * 2;
  short* Hb    = (short*)((char*)d_ws + off);
  const size_t needA = off + (size_t)NEXP * NTOK * DFF * 2;  // per-expert Hb
  // Tier B need = off + NTOK*DFF*2 (= ~145 MB) — guaranteed by R4 (ws>=176MB)

  prep_zero<<<2048, 256, 0, stream>>>((float4*)out, (int4*)idx);
  cvt_kernel<<<2048, 256, 0, stream>>>(x,  xb,  (int)(CNT / 8));
  cvt_kernel<<<2048, 256, 0, stream>>>(wd, wdb, (int)(CNT / 8));
  pack_gu<<<2048, 256, 0, stream>>>(wg, wu, wgu);
  gate_v3<<<NTOK / 32, 256, 0, stream>>>(x, W_A, gscale, gbias, gw,
                                         score_out, idx, cnt);

  if (ws_size >= needA) {
    // Tier A: all experts' ffn1 in ONE dispatch (tails overlap); per-expert
    // Hb regions (no write collisions). ffn2 sequential (RMW determinism).
    ffn1_gemm<<<dim3(2048 / 128, NTOK / 128, NEXP), 256, 0, stream>>>(
        xb, wgu, idx, cnt, gw, Hb, -1);
    for (int e = 0; e < NEXP; ++e)
      ffn2_gemm<<<dim3(DMODEL / 128, NTOK / 128), 256, 0, stream>>>(
          Hb + (size_t)e * NTOK * DFF, wdb, idx, cnt, out, dummy, e);
  } else {
    // Tier B: shared Hb, sequential per expert (R5-proven shape).
    for (int e = 0; e < NEXP; ++e) {
      ffn1_gemm<<<dim3(2048 / 128, NTOK / 128), 256, 0, stream>>>(
          xb, wgu, idx, cnt, gw, Hb, e);
      ffn2_gemm<<<dim3(DMODEL / 128, NTOK / 128), 256, 0, stream>>>(
          Hb, wdb, idx, cnt, out, dummy, e);
    }
  }
}

// Round 7
// 1182.961 us; speedup vs baseline: 1.6150x; 1.0444x over previous
//
#include <hip/hip_runtime.h>
#include <hip/hip_bf16.h>
#include <math.h>

// Problem constants
#define NTOK   8192
#define DMODEL 2048
#define NEXP   8
#define RGATE  8
#define DFF    1024

#define NEG_SENTINEL (-3.0e38f)

using f32x4  = __attribute__((ext_vector_type(4))) float;
using short8 = __attribute__((ext_vector_type(8))) short;

// RNE float->bf16
static __device__ __forceinline__ short f2bf(float f) {
  union { float f; unsigned u; } v; v.f = f;
  unsigned r = v.u + 0x7fffu + ((v.u >> 16) & 1u);
  return (short)(r >> 16);
}
static __device__ __forceinline__ short8 cvt8(const float4 a, const float4 b) {
  short8 o;
  o[0] = f2bf(a.x); o[1] = f2bf(a.y); o[2] = f2bf(a.z); o[3] = f2bf(a.w);
  o[4] = f2bf(b.x); o[5] = f2bf(b.y); o[6] = f2bf(b.z); o[7] = f2bf(b.w);
  return o;
}

#define GLOAD_LDS(gp, lp)                                                  \
  __builtin_amdgcn_global_load_lds(                                        \
      (const __attribute__((address_space(1))) void*)(gp),                 \
      (__attribute__((address_space(3))) void*)(lp), 16, 0, 0)

// ---------------------------------------------------------------------------
// prep_zero: zero out[N,D] (accumulate base over poison) + idx lists + cnt.
// ---------------------------------------------------------------------------
__global__ __launch_bounds__(256) void prep_zero(
    float4* __restrict__ out4, int4* __restrict__ ic4) {
  const int stride = gridDim.x * blockDim.x;
  const float4 z4 = make_float4(0.f, 0.f, 0.f, 0.f);
  for (int i = blockIdx.x * blockDim.x + threadIdx.x;
       i < NTOK * DMODEL / 4; i += stride) {
    out4[i] = z4;
    if (i < (NEXP * NTOK + 16) / 4) ic4[i] = make_int4(0, 0, 0, 0);
  }
}

// ---------------------------------------------------------------------------
// cvt: fp32 -> bf16
// ---------------------------------------------------------------------------
__global__ __launch_bounds__(256) void cvt_kernel(
    const float* __restrict__ in, short* __restrict__ out, int n8) {
  const int stride = gridDim.x * blockDim.x;
  for (int i = blockIdx.x * blockDim.x + threadIdx.x; i < n8; i += stride) {
    const float4 a = ((const float4*)in)[(size_t)i * 2];
    const float4 b = ((const float4*)in)[(size_t)i * 2 + 1];
    ((short8*)out)[i] = cvt8(a, b);
  }
}

// ---------------------------------------------------------------------------
// pack_gu: interleave wg/wu rows in 16-row groups (g in even 16-col frags of
// a 128-col GEMM tile, u in odd).
// ---------------------------------------------------------------------------
__global__ __launch_bounds__(256) void pack_gu(
    const float* __restrict__ wg, const float* __restrict__ wu,
    short* __restrict__ wgu) {
  const int stride = gridDim.x * blockDim.x;
  const int total = NEXP * 2048 * (DMODEL / 8);
  for (int i = blockIdx.x * blockDim.x + threadIdx.x; i < total; i += stride) {
    const int c = i & 255;
    const int r = (i >> 8) & 2047;
    const int e = i >> 19;
    const int sel = (r >> 4) & 1;
    const int f = ((r >> 5) << 4) + (r & 15);
    const float* src = (sel ? wu : wg) + ((size_t)(e * DFF + f)) * DMODEL + c * 8;
    const float4 a = *(const float4*)src;
    const float4 b = *(const float4*)(src + 4);
    ((short8*)wgu)[i] = cvt8(a, b);
  }
}

// ---------------------------------------------------------------------------
// gate_v3: register outer-product gate (unchanged from R6 — passed).
// ---------------------------------------------------------------------------
__global__ __launch_bounds__(256) void gate_v3(
    const float* __restrict__ x, const float* __restrict__ W_A,
    const float* __restrict__ gscale, const float* __restrict__ gbias,
    float* __restrict__ gw, float* __restrict__ score_out,
    int* __restrict__ idx, int* __restrict__ cnt) {
  __shared__ float ghs[32][65];
  const int tok0 = blockIdx.x * 32;
  const int t = threadIdx.x;
  const int ks = t & 3;
  const int pos = t >> 2;
  const int tg = pos & 7;
  const int rg = pos >> 3;
  const float* xp = x + (size_t)(tok0 + tg * 4) * DMODEL;
  const float* wp = W_A + (size_t)(rg * 8) * DMODEL;

  float acc[4][8];
#pragma unroll
  for (int i = 0; i < 4; ++i)
#pragma unroll
    for (int r = 0; r < 8; ++r) acc[i][r] = 0.f;

  float4 xa_[4], wa_[8], xb_[4], wb_[8];
  auto loadj = [&](int j, float4* xv, float4* wv) {
    const int k = ks * 4 + j * 16;
#pragma unroll
    for (int i = 0; i < 4; ++i) xv[i] = *(const float4*)(xp + (size_t)i * DMODEL + k);
#pragma unroll
    for (int r = 0; r < 8; ++r) wv[r] = *(const float4*)(wp + (size_t)r * DMODEL + k);
  };
  auto fmaj = [&](const float4* xv, const float4* wv) {
#pragma unroll
    for (int i = 0; i < 4; ++i)
#pragma unroll
      for (int r = 0; r < 8; ++r) {
        acc[i][r] = fmaf(xv[i].x, wv[r].x, acc[i][r]);
        acc[i][r] = fmaf(xv[i].y, wv[r].y, acc[i][r]);
        acc[i][r] = fmaf(xv[i].z, wv[r].z, acc[i][r]);
        acc[i][r] = fmaf(xv[i].w, wv[r].w, acc[i][r]);
      }
  };

  loadj(0, xa_, wa_);
#pragma unroll 1
  for (int j = 0; j < 128; j += 2) {
    loadj(j + 1, xb_, wb_);
    fmaj(xa_, wa_);
    if (j + 2 < 128) loadj(j + 2, xa_, wa_);
    fmaj(xb_, wb_);
  }

#pragma unroll
  for (int i = 0; i < 4; ++i)
#pragma unroll
    for (int r = 0; r < 8; ++r) {
      float v = acc[i][r];
      v += __shfl_xor(v, 1);
      v += __shfl_xor(v, 2);
      acc[i][r] = v;
    }
  if (ks == 0) {
#pragma unroll
    for (int i = 0; i < 4; ++i)
#pragma unroll
      for (int r = 0; r < 8; ++r) ghs[tg * 4 + i][rg * 8 + r] = acc[i][r];
  }
  __syncthreads();

  {
    const int tk = t >> 3, e = t & 7;
    const int n = tok0 + tk;
    float ss = 0.f;
#pragma unroll
    for (int r = 0; r < RGATE; ++r) { const float v = ghs[tk][e * 8 + r]; ss += v * v; }
    const float score = sqrtf(ss) * gscale[e] - gbias[e];
    const bool m = (score >= 0.0f);
    const float sig = 1.0f / (1.0f + expf(-score));
    gw[(size_t)n * NEXP + e] = m ? sig : 0.0f;
    score_out[(size_t)n * NEXP + e] = m ? score : NEG_SENTINEL;
    if (m) {
      const int slot = atomicAdd(&cnt[e], 1);
      idx[(size_t)e * NTOK + slot] = n;
    }
  }
}

// ===========================================================================
// GEMM LDS swizzle (rule #21: both-sides-or-neither with global_load_lds):
//   - LDS destination stays LINEAR (hardware: wave base + lane*16).
//   - Per-lane GLOBAL source chunk pre-swizzled: srcChunk = (lane&7)^(lane>>3)
//     (stripes are 8-row aligned, so row&7 == lane>>3; the permutation stays
//     inside one 128B segment -> coalescing preserved).
//   - Read side applies the same XOR: chunk ^= (row&7) == (lane&7).
// Result: lanes 0-7 of each 16-lane group cover all 8 chunks = all 32 banks;
// residual 2-way aliasing is free (m136). Kills the 16-way conflict
// (8.8e7 conflict-cycles/dispatch in R6).
// ===========================================================================

// ---------------------------------------------------------------------------
// ffn1_gemm: compact-row fused G+U GEMM + SwiGLU epilogue. e_arg < 0 =>
// expert = blockIdx.z, per-expert Hb region (fused single dispatch).
// ---------------------------------------------------------------------------
__global__ __launch_bounds__(256) void ffn1_gemm(
    const short* __restrict__ xb, const short* __restrict__ wgu,
    const int* __restrict__ idx, const int* __restrict__ cnt,
    const float* __restrict__ gw, short* __restrict__ Hb, int e_arg) {
  const int e = (e_arg < 0) ? (int)blockIdx.z : e_arg;
  short* __restrict__ Hbe = Hb + ((e_arg < 0) ? (size_t)e * NTOK * DFF : (size_t)0);
  const int cnte = cnt[e];
  const int n0 = blockIdx.y * 128;
  if (n0 >= cnte) return;
  __shared__ __align__(16) short As[128 * 64];
  __shared__ __align__(16) short Bs[128 * 64];

  const int c0 = blockIdx.x * 128;
  const int t = threadIdx.x, lane = t & 63, wid = t >> 6;
  const int wr = wid >> 1, wc = wid & 1;
  const int* idxe = idx + (size_t)e * NTOK;
  const short* Bb = wgu + (size_t)e * 2048 * DMODEL + (size_t)c0 * DMODEL;
  const int lr = lane >> 3;                       // row within 8-row stripe
  const int lk = ((lane & 7) ^ lr) * 8;           // pre-swizzled source chunk

  int tokA[4];
#pragma unroll
  for (int i = 0; i < 4; ++i) tokA[i] = idxe[n0 + wid * 32 + i * 8 + lr];

  f32x4 acc[4][4];
#pragma unroll
  for (int i = 0; i < 4; ++i)
#pragma unroll
    for (int j = 0; j < 4; ++j) acc[i][j] = (f32x4){0.f, 0.f, 0.f, 0.f};

  for (int k0 = 0; k0 < DMODEL; k0 += 64) {
    __syncthreads();
#pragma unroll
    for (int i = 0; i < 4; ++i) {
      const int row = wid * 32 + i * 8;
      GLOAD_LDS(xb + (size_t)tokA[i] * DMODEL + k0 + lk, (char*)As + row * 128);
      GLOAD_LDS(Bb + (size_t)(row + lr) * DMODEL + k0 + lk, (char*)Bs + row * 128);
    }
    __syncthreads();

#pragma unroll
    for (int ks = 0; ks < 2; ++ks) {
      // swizzled read: logical chunk = ks*4 + (lane>>4), XOR with row&7==lane&7
      const int cswz = ((ks * 4 + (lane >> 4)) ^ (lane & 7)) << 4;
      short8 af[4], bf[4];
#pragma unroll
      for (int q = 0; q < 4; ++q) {
        af[q] = *(const short8*)((const char*)As +
                 (wr * 64 + q * 16 + (lane & 15)) * 128 + cswz);
        bf[q] = *(const short8*)((const char*)Bs +
                 (wc * 64 + q * 16 + (lane & 15)) * 128 + cswz);
      }
#pragma unroll
      for (int nf = 0; nf < 4; ++nf)
#pragma unroll
        for (int ff = 0; ff < 4; ++ff)
          acc[nf][ff] = __builtin_amdgcn_mfma_f32_16x16x32_bf16(af[nf], bf[ff], acc[nf][ff], 0, 0, 0);
    }
  }

  const int fbase = (c0 >> 1) + wc * 32;
#pragma unroll
  for (int nf = 0; nf < 4; ++nf) {
#pragma unroll
    for (int j = 0; j < 4; ++j) {
      const int n = n0 + wr * 64 + nf * 16 + (lane >> 4) * 4 + j;
      const bool valid = n < cnte;
      const int tok = valid ? idxe[n] : 0;
      const float gwv = gw[(size_t)tok * NEXP + e];
#pragma unroll
      for (int q = 0; q < 2; ++q) {
        const float gv = acc[nf][2 * q][j];
        const float uv = acc[nf][2 * q + 1][j];
        const float h = (gv / (1.f + expf(-gv))) * uv * gwv;
        Hbe[(size_t)n * DFF + fbase + q * 16 + (lane & 15)] = valid ? f2bf(h) : (short)0;
      }
    }
  }
}

// ---------------------------------------------------------------------------
// ffn2_gemm: compact-row down GEMM, scatter-accumulate into out via idx.
// Sequential per expert (RMW race-free, deterministic e-order).
// ---------------------------------------------------------------------------
__global__ __launch_bounds__(256) void ffn2_gemm(
    const short* __restrict__ Hbe, const short* __restrict__ wdb,
    const int* __restrict__ idx, const int* __restrict__ cnt,
    float* __restrict__ out, float* __restrict__ dummy, int e) {
  const int cnte = cnt[e];
  const int n0 = blockIdx.y * 128;
  if (n0 >= cnte) return;
  __shared__ __align__(16) short As[128 * 64];
  __shared__ __align__(16) short Bs[128 * 64];

  const int c0 = blockIdx.x * 128;
  const int t = threadIdx.x, lane = t & 63, wid = t >> 6;
  const int wr = wid >> 1, wc = wid & 1;
  const int* idxe = idx + (size_t)e * NTOK;
  const short* Ab = Hbe + (size_t)n0 * DFF;
  const short* Bb = wdb + (size_t)e * DMODEL * DFF + (size_t)c0 * DFF;
  const int lr = lane >> 3;
  const int lk = ((lane & 7) ^ lr) * 8;           // pre-swizzled source chunk

  f32x4 acc[4][4];
#pragma unroll
  for (int i = 0; i < 4; ++i)
#pragma unroll
    for (int j = 0; j < 4; ++j) acc[i][j] = (f32x4){0.f, 0.f, 0.f, 0.f};

  for (int k0 = 0; k0 < DFF; k0 += 64) {
    __syncthreads();
#pragma unroll
    for (int i = 0; i < 4; ++i) {
      const int row = wid * 32 + i * 8;
      GLOAD_LDS(Ab + (size_t)(row + lr) * DFF + k0 + lk, (char*)As + row * 128);
      GLOAD_LDS(Bb + (size_t)(row + lr) * DFF + k0 + lk, (char*)Bs + row * 128);
    }
    __syncthreads();

#pragma unroll
    for (int ks = 0; ks < 2; ++ks) {
      const int cswz = ((ks * 4 + (lane >> 4)) ^ (lane & 7)) << 4;
      short8 af[4], bf[4];
#pragma unroll
      for (int q = 0; q < 4; ++q) {
        af[q] = *(const short8*)((const char*)As +
                 (wr * 64 + q * 16 + (lane & 15)) * 128 + cswz);
        bf[q] = *(const short8*)((const char*)Bs +
                 (wc * 64 + q * 16 + (lane & 15)) * 128 + cswz);
      }
#pragma unroll
      for (int nf = 0; nf < 4; ++nf)
#pragma unroll
        for (int ff = 0; ff < 4; ++ff)
          acc[nf][ff] = __builtin_amdgcn_mfma_f32_16x16x32_bf16(af[nf], bf[ff], acc[nf][ff], 0, 0, 0);
    }
  }

#pragma unroll
  for (int nf = 0; nf < 4; ++nf) {
#pragma unroll
    for (int j = 0; j < 4; ++j) {
      const int n = n0 + wr * 64 + nf * 16 + (lane >> 4) * 4 + j;
      const bool valid = n < cnte;
      const int tok = valid ? idxe[n] : 0;
      float* bp = valid ? (out + (size_t)tok * DMODEL) : dummy;
#pragma unroll
      for (int ff = 0; ff < 4; ++ff) {
        const int d = c0 + wc * 64 + ff * 16 + (lane & 15);
        bp[valid ? d : (d & 2047)] += acc[nf][ff][j];
      }
    }
  }
}

// ---------------------------------------------------------------------------
extern "C" void kernel_launch(void* const* d_in, const int* in_sizes, int n_in,
                              void* d_out, int out_size, void* d_ws, size_t ws_size,
                              hipStream_t stream) {
  const float* x      = (const float*)d_in[0];
  const float* W_A    = (const float*)d_in[1];
  const float* gscale = (const float*)d_in[2];
  const float* gbias  = (const float*)d_in[3];
  const float* wg     = (const float*)d_in[4];
  const float* wu     = (const float*)d_in[5];
  const float* wd     = (const float*)d_in[6];

  float* out       = (float*)d_out;                // [N, D]
  float* score_out = out + (size_t)NTOK * DMODEL;  // [N, E]

  // ws layout: gw f32[N*E] | idx i32[E*N] | cnt i32[16] | dummy f32[D] |
  //            xb bf16[N*D] | wgu bf16[E*2048*D] | wdb bf16[E*D*F] | Hb bf16
  const size_t CNT = (size_t)16777216;
  size_t off = 0;
  float* gw    = (float*)((char*)d_ws + off); off += (size_t)NTOK * NEXP * 4;
  int*   idx   = (int*)((char*)d_ws + off);   off += (size_t)NEXP * NTOK * 4;
  int*   cnt   = (int*)((char*)d_ws + off);   off += 16 * 4;
  float* dummy = (float*)((char*)d_ws + off); off += (size_t)DMODEL * 4;
  short* xb    = (short*)((char*)d_ws + off); off += CNT * 2;
  short* wgu   = (short*)((char*)d_ws + off); off += CNT * 4;
  short* wdb   = (short*)((char*)d_ws + off); off += CNT * 2;
  short* Hb    = (short*)((char*)d_ws + off);
  const size_t needA = off + (size_t)NEXP * NTOK * DFF * 2;  // per-expert Hb

  prep_zero<<<2048, 256, 0, stream>>>((float4*)out, (int4*)idx);
  cvt_kernel<<<2048, 256, 0, stream>>>(x,  xb,  (int)(CNT / 8));
  cvt_kernel<<<2048, 256, 0, stream>>>(wd, wdb, (int)(CNT / 8));
  pack_gu<<<2048, 256, 0, stream>>>(wg, wu, wgu);
  gate_v3<<<NTOK / 32, 256, 0, stream>>>(x, W_A, gscale, gbias, gw,
                                         score_out, idx, cnt);

  if (ws_size >= needA) {
    // Tier A: all experts' ffn1 in ONE dispatch; per-expert Hb regions.
    ffn1_gemm<<<dim3(2048 / 128, NTOK / 128, NEXP), 256, 0, stream>>>(
        xb, wgu, idx, cnt, gw, Hb, -1);
    for (int e = 0; e < NEXP; ++e)
      ffn2_gemm<<<dim3(DMODEL / 128, NTOK / 128), 256, 0, stream>>>(
          Hb + (size_t)e * NTOK * DFF, wdb, idx, cnt, out, dummy, e);
  } else {
    // Tier B: shared Hb, sequential per expert (R5-proven shape).
    for (int e = 0; e < NEXP; ++e) {
      ffn1_gemm<<<dim3(2048 / 128, NTOK / 128), 256, 0, stream>>>(
          xb, wgu, idx, cnt, gw, Hb, e);
      ffn2_gemm<<<dim3(DMODEL / 128, NTOK / 128), 256, 0, stream>>>(
          Hb, wdb, idx, cnt, out, dummy, e);
    }
  }
}

// Round 8
// 1089.030 us; speedup vs baseline: 1.7543x; 1.0863x over previous
//
#include <hip/hip_runtime.h>
#include <hip/hip_bf16.h>
#include <math.h>

// Problem constants
#define NTOK   8192
#define DMODEL 2048
#define NEXP   8
#define RGATE  8
#define DFF    1024

#define NEG_SENTINEL (-3.0e38f)

using f32x4  = __attribute__((ext_vector_type(4))) float;
using short8 = __attribute__((ext_vector_type(8))) short;

// RNE float->bf16
static __device__ __forceinline__ short f2bf(float f) {
  union { float f; unsigned u; } v; v.f = f;
  unsigned r = v.u + 0x7fffu + ((v.u >> 16) & 1u);
  return (short)(r >> 16);
}
static __device__ __forceinline__ short8 cvt8(const float4 a, const float4 b) {
  short8 o;
  o[0] = f2bf(a.x); o[1] = f2bf(a.y); o[2] = f2bf(a.z); o[3] = f2bf(a.w);
  o[4] = f2bf(b.x); o[5] = f2bf(b.y); o[6] = f2bf(b.z); o[7] = f2bf(b.w);
  return o;
}

#define GLOAD_LDS(gp, lp)                                                  \
  __builtin_amdgcn_global_load_lds(                                        \
      (const __attribute__((address_space(1))) void*)(gp),                 \
      (__attribute__((address_space(3))) void*)(lp), 16, 0, 0)

// ---------------------------------------------------------------------------
// prep_zero: zero out[N,D] (accumulate base over poison) + idx lists + cnt.
// ---------------------------------------------------------------------------
__global__ __launch_bounds__(256) void prep_zero(
    float4* __restrict__ out4, int4* __restrict__ ic4) {
  const int stride = gridDim.x * blockDim.x;
  const float4 z4 = make_float4(0.f, 0.f, 0.f, 0.f);
  for (int i = blockIdx.x * blockDim.x + threadIdx.x;
       i < NTOK * DMODEL / 4; i += stride) {
    out4[i] = z4;
    if (i < (NEXP * NTOK + 16) / 4) ic4[i] = make_int4(0, 0, 0, 0);
  }
}

// ---------------------------------------------------------------------------
// cvt: fp32 -> bf16
// ---------------------------------------------------------------------------
__global__ __launch_bounds__(256) void cvt_kernel(
    const float* __restrict__ in, short* __restrict__ out, int n8) {
  const int stride = gridDim.x * blockDim.x;
  for (int i = blockIdx.x * blockDim.x + threadIdx.x; i < n8; i += stride) {
    const float4 a = ((const float4*)in)[(size_t)i * 2];
    const float4 b = ((const float4*)in)[(size_t)i * 2 + 1];
    ((short8*)out)[i] = cvt8(a, b);
  }
}

// ---------------------------------------------------------------------------
// pack_gu: interleave wg/wu rows in 16-row groups (g in even 16-col frags of
// a GEMM tile, u in odd).
// ---------------------------------------------------------------------------
__global__ __launch_bounds__(256) void pack_gu(
    const float* __restrict__ wg, const float* __restrict__ wu,
    short* __restrict__ wgu) {
  const int stride = gridDim.x * blockDim.x;
  const int total = NEXP * 2048 * (DMODEL / 8);
  for (int i = blockIdx.x * blockDim.x + threadIdx.x; i < total; i += stride) {
    const int c = i & 255;
    const int r = (i >> 8) & 2047;
    const int e = i >> 19;
    const int sel = (r >> 4) & 1;
    const int f = ((r >> 5) << 4) + (r & 15);
    const float* src = (sel ? wu : wg) + ((size_t)(e * DFF + f)) * DMODEL + c * 8;
    const float4 a = *(const float4*)src;
    const float4 b = *(const float4*)(src + 4);
    ((short8*)wgu)[i] = cvt8(a, b);
  }
}

// ---------------------------------------------------------------------------
// gate_v3: register outer-product gate (unchanged — R6/R7-proven).
// ---------------------------------------------------------------------------
__global__ __launch_bounds__(256) void gate_v3(
    const float* __restrict__ x, const float* __restrict__ W_A,
    const float* __restrict__ gscale, const float* __restrict__ gbias,
    float* __restrict__ gw, float* __restrict__ score_out,
    int* __restrict__ idx, int* __restrict__ cnt) {
  __shared__ float ghs[32][65];
  const int tok0 = blockIdx.x * 32;
  const int t = threadIdx.x;
  const int ks = t & 3;
  const int pos = t >> 2;
  const int tg = pos & 7;
  const int rg = pos >> 3;
  const float* xp = x + (size_t)(tok0 + tg * 4) * DMODEL;
  const float* wp = W_A + (size_t)(rg * 8) * DMODEL;

  float acc[4][8];
#pragma unroll
  for (int i = 0; i < 4; ++i)
#pragma unroll
    for (int r = 0; r < 8; ++r) acc[i][r] = 0.f;

  float4 xa_[4], wa_[8], xb_[4], wb_[8];
  auto loadj = [&](int j, float4* xv, float4* wv) {
    const int k = ks * 4 + j * 16;
#pragma unroll
    for (int i = 0; i < 4; ++i) xv[i] = *(const float4*)(xp + (size_t)i * DMODEL + k);
#pragma unroll
    for (int r = 0; r < 8; ++r) wv[r] = *(const float4*)(wp + (size_t)r * DMODEL + k);
  };
  auto fmaj = [&](const float4* xv, const float4* wv) {
#pragma unroll
    for (int i = 0; i < 4; ++i)
#pragma unroll
      for (int r = 0; r < 8; ++r) {
        acc[i][r] = fmaf(xv[i].x, wv[r].x, acc[i][r]);
        acc[i][r] = fmaf(xv[i].y, wv[r].y, acc[i][r]);
        acc[i][r] = fmaf(xv[i].z, wv[r].z, acc[i][r]);
        acc[i][r] = fmaf(xv[i].w, wv[r].w, acc[i][r]);
      }
  };

  loadj(0, xa_, wa_);
#pragma unroll 1
  for (int j = 0; j < 128; j += 2) {
    loadj(j + 1, xb_, wb_);
    fmaj(xa_, wa_);
    if (j + 2 < 128) loadj(j + 2, xa_, wa_);
    fmaj(xb_, wb_);
  }

#pragma unroll
  for (int i = 0; i < 4; ++i)
#pragma unroll
    for (int r = 0; r < 8; ++r) {
      float v = acc[i][r];
      v += __shfl_xor(v, 1);
      v += __shfl_xor(v, 2);
      acc[i][r] = v;
    }
  if (ks == 0) {
#pragma unroll
    for (int i = 0; i < 4; ++i)
#pragma unroll
      for (int r = 0; r < 8; ++r) ghs[tg * 4 + i][rg * 8 + r] = acc[i][r];
  }
  __syncthreads();

  {
    const int tk = t >> 3, e = t & 7;
    const int n = tok0 + tk;
    float ss = 0.f;
#pragma unroll
    for (int r = 0; r < RGATE; ++r) { const float v = ghs[tk][e * 8 + r]; ss += v * v; }
    const float score = sqrtf(ss) * gscale[e] - gbias[e];
    const bool m = (score >= 0.0f);
    const float sig = 1.0f / (1.0f + expf(-score));
    gw[(size_t)n * NEXP + e] = m ? sig : 0.0f;
    score_out[(size_t)n * NEXP + e] = m ? score : NEG_SENTINEL;
    if (m) {
      const int slot = atomicAdd(&cnt[e], 1);
      idx[(size_t)e * NTOK + slot] = n;
    }
  }
}

// ===========================================================================
// ffn1_gemm256: 256x256 tile, 512 thr / 8 waves (2M x 4N, wave tile 128x64),
// BK=64, DOUBLE-BUFFERED LDS (4 distinct __shared__ arrays, statically
// unrolled x2 body so alias analysis keeps next-tile global_load_lds in
// flight across the current tile's MFMAs; compiler's vmcnt(0) lands at the
// single end-of-iter barrier). T2 swizzle retained (R7: conflicts = 0).
// ===========================================================================
#define FFN1_STAGE(AS, BS, k0)                                                 \
  _Pragma("unroll") for (int i_ = 0; i_ < 4; ++i_) {                           \
    const int row_ = wid * 32 + i_ * 8;                                        \
    GLOAD_LDS(xb + (size_t)tokA[i_] * DMODEL + (k0) + lk,                      \
              (char*)(AS) + row_ * 128);                                       \
    GLOAD_LDS(Bb + (size_t)(row_ + lr) * DMODEL + (k0) + lk,                   \
              (char*)(BS) + row_ * 128);                                       \
  }

#define FFN1_COMPUTE(AS, BS)                                                   \
  _Pragma("unroll") for (int ks_ = 0; ks_ < 2; ++ks_) {                        \
    const int cswz_ = ((ks_ * 4 + (lane >> 4)) ^ (lane & 7)) << 4;             \
    short8 af_[8], bf_[4];                                                     \
    _Pragma("unroll") for (int q_ = 0; q_ < 8; ++q_)                           \
      af_[q_] = *(const short8*)((const char*)(AS) +                           \
                (arow + q_ * 16 + (lane & 15)) * 128 + cswz_);                 \
    _Pragma("unroll") for (int q_ = 0; q_ < 4; ++q_)                           \
      bf_[q_] = *(const short8*)((const char*)(BS) +                           \
                (brow + q_ * 16 + (lane & 15)) * 128 + cswz_);                 \
    _Pragma("unroll") for (int nf_ = 0; nf_ < 8; ++nf_)                        \
      _Pragma("unroll") for (int ff_ = 0; ff_ < 4; ++ff_)                      \
        acc[nf_][ff_] = __builtin_amdgcn_mfma_f32_16x16x32_bf16(               \
            af_[nf_], bf_[ff_], acc[nf_][ff_], 0, 0, 0);                       \
  }

__global__ __launch_bounds__(512, 2) void ffn1_gemm256(
    const short* __restrict__ xb, const short* __restrict__ wgu,
    const int* __restrict__ idx, const int* __restrict__ cnt,
    const float* __restrict__ gw, short* __restrict__ Hb, int e_arg) {
  const int e = (e_arg < 0) ? (int)blockIdx.z : e_arg;
  short* __restrict__ Hbe = Hb + ((e_arg < 0) ? (size_t)e * NTOK * DFF : (size_t)0);
  const int cnte = cnt[e];
  const int n0 = blockIdx.y * 256;
  if (n0 >= cnte) return;

  __shared__ __align__(16) short As0[256 * 64];
  __shared__ __align__(16) short Bs0[256 * 64];
  __shared__ __align__(16) short As1[256 * 64];
  __shared__ __align__(16) short Bs1[256 * 64];

  const int c0 = blockIdx.x * 256;
  const int t = threadIdx.x, lane = t & 63, wid = t >> 6;
  const int arow = (wid >> 2) * 128;  // wave row-half base
  const int brow = (wid & 3) * 64;    // wave col-quarter base
  const int* idxe = idx + (size_t)e * NTOK;
  const short* Bb = wgu + (size_t)e * 2048 * DMODEL + (size_t)c0 * DMODEL;
  const int lr = lane >> 3;                 // row within 8-row stripe
  const int lk = ((lane & 7) ^ lr) * 8;     // pre-swizzled source chunk

  int tokA[4];
#pragma unroll
  for (int i = 0; i < 4; ++i) tokA[i] = idxe[n0 + wid * 32 + i * 8 + lr];

  f32x4 acc[8][4];
#pragma unroll
  for (int i = 0; i < 8; ++i)
#pragma unroll
    for (int j = 0; j < 4; ++j) acc[i][j] = (f32x4){0.f, 0.f, 0.f, 0.f};

  FFN1_STAGE(As0, Bs0, 0);
  __syncthreads();
#pragma unroll 1
  for (int kt = 0; kt < 32; kt += 2) {
    FFN1_STAGE(As1, Bs1, (kt + 1) * 64);   // prefetch odd tile
    FFN1_COMPUTE(As0, Bs0);                // compute even tile
    __syncthreads();                       // drains vmcnt for odd tile
    if (kt + 2 < 32) FFN1_STAGE(As0, Bs0, (kt + 2) * 64);
    FFN1_COMPUTE(As1, Bs1);
    __syncthreads();
  }

  // Epilogue: h = silu(g)*u*gw -> Hb compact rows; pads write exact 0.
  const int fhalf = c0 >> 1;
#pragma unroll
  for (int nf = 0; nf < 8; ++nf) {
#pragma unroll
    for (int j = 0; j < 4; ++j) {
      const int n = n0 + arow + nf * 16 + (lane >> 4) * 4 + j;
      const bool valid = n < cnte;
      const int tok = valid ? idxe[n] : 0;
      const float gwv = gw[(size_t)tok * NEXP + e];
#pragma unroll
      for (int p = 0; p < 2; ++p) {
        const float gv = acc[nf][2 * p][j];
        const float uv = acc[nf][2 * p + 1][j];
        const float h = (gv / (1.f + expf(-gv))) * uv * gwv;
        const int f = fhalf + ((wid & 3) * 2 + p) * 16 + (lane & 15);
        Hbe[(size_t)n * DFF + f] = valid ? f2bf(h) : (short)0;
      }
    }
  }
}

// ---------------------------------------------------------------------------
// ffn2_gemm: UNCHANGED from R7 (proven; swizzled, conflicts = 0).
// ---------------------------------------------------------------------------
__global__ __launch_bounds__(256) void ffn2_gemm(
    const short* __restrict__ Hbe, const short* __restrict__ wdb,
    const int* __restrict__ idx, const int* __restrict__ cnt,
    float* __restrict__ out, float* __restrict__ dummy, int e) {
  const int cnte = cnt[e];
  const int n0 = blockIdx.y * 128;
  if (n0 >= cnte) return;
  __shared__ __align__(16) short As[128 * 64];
  __shared__ __align__(16) short Bs[128 * 64];

  const int c0 = blockIdx.x * 128;
  const int t = threadIdx.x, lane = t & 63, wid = t >> 6;
  const int wr = wid >> 1, wc = wid & 1;
  const int* idxe = idx + (size_t)e * NTOK;
  const short* Ab = Hbe + (size_t)n0 * DFF;
  const short* Bb = wdb + (size_t)e * DMODEL * DFF + (size_t)c0 * DFF;
  const int lr = lane >> 3;
  const int lk = ((lane & 7) ^ lr) * 8;

  f32x4 acc[4][4];
#pragma unroll
  for (int i = 0; i < 4; ++i)
#pragma unroll
    for (int j = 0; j < 4; ++j) acc[i][j] = (f32x4){0.f, 0.f, 0.f, 0.f};

  for (int k0 = 0; k0 < DFF; k0 += 64) {
    __syncthreads();
#pragma unroll
    for (int i = 0; i < 4; ++i) {
      const int row = wid * 32 + i * 8;
      GLOAD_LDS(Ab + (size_t)(row + lr) * DFF + k0 + lk, (char*)As + row * 128);
      GLOAD_LDS(Bb + (size_t)(row + lr) * DFF + k0 + lk, (char*)Bs + row * 128);
    }
    __syncthreads();

#pragma unroll
    for (int ks = 0; ks < 2; ++ks) {
      const int cswz = ((ks * 4 + (lane >> 4)) ^ (lane & 7)) << 4;
      short8 af[4], bf[4];
#pragma unroll
      for (int q = 0; q < 4; ++q) {
        af[q] = *(const short8*)((const char*)As +
                 (wr * 64 + q * 16 + (lane & 15)) * 128 + cswz);
        bf[q] = *(const short8*)((const char*)Bs +
                 (wc * 64 + q * 16 + (lane & 15)) * 128 + cswz);
      }
#pragma unroll
      for (int nf = 0; nf < 4; ++nf)
#pragma unroll
        for (int ff = 0; ff < 4; ++ff)
          acc[nf][ff] = __builtin_amdgcn_mfma_f32_16x16x32_bf16(af[nf], bf[ff], acc[nf][ff], 0, 0, 0);
    }
  }

#pragma unroll
  for (int nf = 0; nf < 4; ++nf) {
#pragma unroll
    for (int j = 0; j < 4; ++j) {
      const int n = n0 + wr * 64 + nf * 16 + (lane >> 4) * 4 + j;
      const bool valid = n < cnte;
      const int tok = valid ? idxe[n] : 0;
      float* bp = valid ? (out + (size_t)tok * DMODEL) : dummy;
#pragma unroll
      for (int ff = 0; ff < 4; ++ff) {
        const int d = c0 + wc * 64 + ff * 16 + (lane & 15);
        bp[valid ? d : (d & 2047)] += acc[nf][ff][j];
      }
    }
  }
}

// ---------------------------------------------------------------------------
extern "C" void kernel_launch(void* const* d_in, const int* in_sizes, int n_in,
                              void* d_out, int out_size, void* d_ws, size_t ws_size,
                              hipStream_t stream) {
  const float* x      = (const float*)d_in[0];
  const float* W_A    = (const float*)d_in[1];
  const float* gscale = (const float*)d_in[2];
  const float* gbias  = (const float*)d_in[3];
  const float* wg     = (const float*)d_in[4];
  const float* wu     = (const float*)d_in[5];
  const float* wd     = (const float*)d_in[6];

  float* out       = (float*)d_out;                // [N, D]
  float* score_out = out + (size_t)NTOK * DMODEL;  // [N, E]

  // ws layout: gw f32[N*E] | idx i32[E*N] | cnt i32[16] | dummy f32[D] |
  //            xb bf16[N*D] | wgu bf16[E*2048*D] | wdb bf16[E*D*F] | Hb bf16
  const size_t CNT = (size_t)16777216;
  size_t off = 0;
  float* gw    = (float*)((char*)d_ws + off); off += (size_t)NTOK * NEXP * 4;
  int*   idx   = (int*)((char*)d_ws + off);   off += (size_t)NEXP * NTOK * 4;
  int*   cnt   = (int*)((char*)d_ws + off);   off += 16 * 4;
  float* dummy = (float*)((char*)d_ws + off); off += (size_t)DMODEL * 4;
  short* xb    = (short*)((char*)d_ws + off); off += CNT * 2;
  short* wgu   = (short*)((char*)d_ws + off); off += CNT * 4;
  short* wdb   = (short*)((char*)d_ws + off); off += CNT * 2;
  short* Hb    = (short*)((char*)d_ws + off);
  const size_t needA = off + (size_t)NEXP * NTOK * DFF * 2;  // per-expert Hb

  prep_zero<<<2048, 256, 0, stream>>>((float4*)out, (int4*)idx);
  cvt_kernel<<<2048, 256, 0, stream>>>(x,  xb,  (int)(CNT / 8));
  cvt_kernel<<<2048, 256, 0, stream>>>(wd, wdb, (int)(CNT / 8));
  pack_gu<<<2048, 256, 0, stream>>>(wg, wu, wgu);
  gate_v3<<<NTOK / 32, 256, 0, stream>>>(x, W_A, gscale, gbias, gw,
                                         score_out, idx, cnt);

  if (ws_size >= needA) {
    // Tier A: all experts' ffn1 in ONE dispatch; per-expert Hb regions.
    ffn1_gemm256<<<dim3(2048 / 256, NTOK / 256, NEXP), 512, 0, stream>>>(
        xb, wgu, idx, cnt, gw, Hb, -1);
    for (int e = 0; e < NEXP; ++e)
      ffn2_gemm<<<dim3(DMODEL / 128, NTOK / 128), 256, 0, stream>>>(
          Hb + (size_t)e * NTOK * DFF, wdb, idx, cnt, out, dummy, e);
  } else {
    // Tier B: shared Hb, sequential per expert.
    for (int e = 0; e < NEXP; ++e) {
      ffn1_gemm256<<<dim3(2048 / 256, NTOK / 256), 512, 0, stream>>>(
          xb, wgu, idx, cnt, gw, Hb, e);
      ffn2_gemm<<<dim3(DMODEL / 128, NTOK / 128), 256, 0, stream>>>(
          Hb, wdb, idx, cnt, out, dummy, e);
    }
  }
}

// Round 9
// 1039.105 us; speedup vs baseline: 1.8386x; 1.0480x over previous
//
#include <hip/hip_runtime.h>
#include <hip/hip_bf16.h>
#include <math.h>

// Problem constants
#define NTOK   8192
#define DMODEL 2048
#define NEXP   8
#define RGATE  8
#define DFF    1024

#define NEG_SENTINEL (-3.0e38f)

using f32x4  = __attribute__((ext_vector_type(4))) float;
using short8 = __attribute__((ext_vector_type(8))) short;

// RNE float->bf16
static __device__ __forceinline__ short f2bf(float f) {
  union { float f; unsigned u; } v; v.f = f;
  unsigned r = v.u + 0x7fffu + ((v.u >> 16) & 1u);
  return (short)(r >> 16);
}
static __device__ __forceinline__ short8 cvt8(const float4 a, const float4 b) {
  short8 o;
  o[0] = f2bf(a.x); o[1] = f2bf(a.y); o[2] = f2bf(a.z); o[3] = f2bf(a.w);
  o[4] = f2bf(b.x); o[5] = f2bf(b.y); o[6] = f2bf(b.z); o[7] = f2bf(b.w);
  return o;
}

#define GLOAD_LDS(gp, lp)                                                  \
  __builtin_amdgcn_global_load_lds(                                        \
      (const __attribute__((address_space(1))) void*)(gp),                 \
      (__attribute__((address_space(3))) void*)(lp), 16, 0, 0)

// ---------------------------------------------------------------------------
// prep_zero: zero out[N,D] (accumulate base over poison) + idx lists + cnt.
// ---------------------------------------------------------------------------
__global__ __launch_bounds__(256) void prep_zero(
    float4* __restrict__ out4, int4* __restrict__ ic4) {
  const int stride = gridDim.x * blockDim.x;
  const float4 z4 = make_float4(0.f, 0.f, 0.f, 0.f);
  for (int i = blockIdx.x * blockDim.x + threadIdx.x;
       i < NTOK * DMODEL / 4; i += stride) {
    out4[i] = z4;
    if (i < (NEXP * NTOK + 16) / 4) ic4[i] = make_int4(0, 0, 0, 0);
  }
}

// ---------------------------------------------------------------------------
// cvt: fp32 -> bf16
// ---------------------------------------------------------------------------
__global__ __launch_bounds__(256) void cvt_kernel(
    const float* __restrict__ in, short* __restrict__ out, int n8) {
  const int stride = gridDim.x * blockDim.x;
  for (int i = blockIdx.x * blockDim.x + threadIdx.x; i < n8; i += stride) {
    const float4 a = ((const float4*)in)[(size_t)i * 2];
    const float4 b = ((const float4*)in)[(size_t)i * 2 + 1];
    ((short8*)out)[i] = cvt8(a, b);
  }
}

// ---------------------------------------------------------------------------
// pack_gu: interleave wg/wu rows in 16-row groups (g in even 16-col frags of
// a GEMM tile, u in odd).
// ---------------------------------------------------------------------------
__global__ __launch_bounds__(256) void pack_gu(
    const float* __restrict__ wg, const float* __restrict__ wu,
    short* __restrict__ wgu) {
  const int stride = gridDim.x * blockDim.x;
  const int total = NEXP * 2048 * (DMODEL / 8);
  for (int i = blockIdx.x * blockDim.x + threadIdx.x; i < total; i += stride) {
    const int c = i & 255;
    const int r = (i >> 8) & 2047;
    const int e = i >> 19;
    const int sel = (r >> 4) & 1;
    const int f = ((r >> 5) << 4) + (r & 15);
    const float* src = (sel ? wu : wg) + ((size_t)(e * DFF + f)) * DMODEL + c * 8;
    const float4 a = *(const float4*)src;
    const float4 b = *(const float4*)(src + 4);
    ((short8*)wgu)[i] = cvt8(a, b);
  }
}

// ---------------------------------------------------------------------------
// gate_v3: register outer-product gate (unchanged — R6/R7/R8-proven).
// ---------------------------------------------------------------------------
__global__ __launch_bounds__(256) void gate_v3(
    const float* __restrict__ x, const float* __restrict__ W_A,
    const float* __restrict__ gscale, const float* __restrict__ gbias,
    float* __restrict__ gw, float* __restrict__ score_out,
    int* __restrict__ idx, int* __restrict__ cnt) {
  __shared__ float ghs[32][65];
  const int tok0 = blockIdx.x * 32;
  const int t = threadIdx.x;
  const int ks = t & 3;
  const int pos = t >> 2;
  const int tg = pos & 7;
  const int rg = pos >> 3;
  const float* xp = x + (size_t)(tok0 + tg * 4) * DMODEL;
  const float* wp = W_A + (size_t)(rg * 8) * DMODEL;

  float acc[4][8];
#pragma unroll
  for (int i = 0; i < 4; ++i)
#pragma unroll
    for (int r = 0; r < 8; ++r) acc[i][r] = 0.f;

  float4 xa_[4], wa_[8], xb_[4], wb_[8];
  auto loadj = [&](int j, float4* xv, float4* wv) {
    const int k = ks * 4 + j * 16;
#pragma unroll
    for (int i = 0; i < 4; ++i) xv[i] = *(const float4*)(xp + (size_t)i * DMODEL + k);
#pragma unroll
    for (int r = 0; r < 8; ++r) wv[r] = *(const float4*)(wp + (size_t)r * DMODEL + k);
  };
  auto fmaj = [&](const float4* xv, const float4* wv) {
#pragma unroll
    for (int i = 0; i < 4; ++i)
#pragma unroll
      for (int r = 0; r < 8; ++r) {
        acc[i][r] = fmaf(xv[i].x, wv[r].x, acc[i][r]);
        acc[i][r] = fmaf(xv[i].y, wv[r].y, acc[i][r]);
        acc[i][r] = fmaf(xv[i].z, wv[r].z, acc[i][r]);
        acc[i][r] = fmaf(xv[i].w, wv[r].w, acc[i][r]);
      }
  };

  loadj(0, xa_, wa_);
#pragma unroll 1
  for (int j = 0; j < 128; j += 2) {
    loadj(j + 1, xb_, wb_);
    fmaj(xa_, wa_);
    if (j + 2 < 128) loadj(j + 2, xa_, wa_);
    fmaj(xb_, wb_);
  }

#pragma unroll
  for (int i = 0; i < 4; ++i)
#pragma unroll
    for (int r = 0; r < 8; ++r) {
      float v = acc[i][r];
      v += __shfl_xor(v, 1);
      v += __shfl_xor(v, 2);
      acc[i][r] = v;
    }
  if (ks == 0) {
#pragma unroll
    for (int i = 0; i < 4; ++i)
#pragma unroll
      for (int r = 0; r < 8; ++r) ghs[tg * 4 + i][rg * 8 + r] = acc[i][r];
  }
  __syncthreads();

  {
    const int tk = t >> 3, e = t & 7;
    const int n = tok0 + tk;
    float ss = 0.f;
#pragma unroll
    for (int r = 0; r < RGATE; ++r) { const float v = ghs[tk][e * 8 + r]; ss += v * v; }
    const float score = sqrtf(ss) * gscale[e] - gbias[e];
    const bool m = (score >= 0.0f);
    const float sig = 1.0f / (1.0f + expf(-score));
    gw[(size_t)n * NEXP + e] = m ? sig : 0.0f;
    score_out[(size_t)n * NEXP + e] = m ? score : NEG_SENTINEL;
    if (m) {
      const int slot = atomicAdd(&cnt[e], 1);
      idx[(size_t)e * NTOK + slot] = n;
    }
  }
}

// ===========================================================================
// ffn1_gemm256: UNCHANGED from R8 (proven: 364 µs, conflicts 0, MfmaUtil 29%).
// ===========================================================================
#define FFN1_STAGE(AS, BS, k0)                                                 \
  _Pragma("unroll") for (int i_ = 0; i_ < 4; ++i_) {                           \
    const int row_ = wid * 32 + i_ * 8;                                        \
    GLOAD_LDS(xb + (size_t)tokA[i_] * DMODEL + (k0) + lk,                      \
              (char*)(AS) + row_ * 128);                                       \
    GLOAD_LDS(Bb + (size_t)(row_ + lr) * DMODEL + (k0) + lk,                   \
              (char*)(BS) + row_ * 128);                                       \
  }

#define FFN1_COMPUTE(AS, BS)                                                   \
  _Pragma("unroll") for (int ks_ = 0; ks_ < 2; ++ks_) {                        \
    const int cswz_ = ((ks_ * 4 + (lane >> 4)) ^ (lane & 7)) << 4;             \
    short8 af_[8], bf_[4];                                                     \
    _Pragma("unroll") for (int q_ = 0; q_ < 8; ++q_)                           \
      af_[q_] = *(const short8*)((const char*)(AS) +                           \
                (arow + q_ * 16 + (lane & 15)) * 128 + cswz_);                 \
    _Pragma("unroll") for (int q_ = 0; q_ < 4; ++q_)                           \
      bf_[q_] = *(const short8*)((const char*)(BS) +                           \
                (brow + q_ * 16 + (lane & 15)) * 128 + cswz_);                 \
    _Pragma("unroll") for (int nf_ = 0; nf_ < 8; ++nf_)                        \
      _Pragma("unroll") for (int ff_ = 0; ff_ < 4; ++ff_)                      \
        acc[nf_][ff_] = __builtin_amdgcn_mfma_f32_16x16x32_bf16(               \
            af_[nf_], bf_[ff_], acc[nf_][ff_], 0, 0, 0);                       \
  }

__global__ __launch_bounds__(512, 2) void ffn1_gemm256(
    const short* __restrict__ xb, const short* __restrict__ wgu,
    const int* __restrict__ idx, const int* __restrict__ cnt,
    const float* __restrict__ gw, short* __restrict__ Hb, int e_arg) {
  const int e = (e_arg < 0) ? (int)blockIdx.z : e_arg;
  short* __restrict__ Hbe = Hb + ((e_arg < 0) ? (size_t)e * NTOK * DFF : (size_t)0);
  const int cnte = cnt[e];
  const int n0 = blockIdx.y * 256;
  if (n0 >= cnte) return;

  __shared__ __align__(16) short As0[256 * 64];
  __shared__ __align__(16) short Bs0[256 * 64];
  __shared__ __align__(16) short As1[256 * 64];
  __shared__ __align__(16) short Bs1[256 * 64];

  const int c0 = blockIdx.x * 256;
  const int t = threadIdx.x, lane = t & 63, wid = t >> 6;
  const int arow = (wid >> 2) * 128;  // wave row-half base
  const int brow = (wid & 3) * 64;    // wave col-quarter base
  const int* idxe = idx + (size_t)e * NTOK;
  const short* Bb = wgu + (size_t)e * 2048 * DMODEL + (size_t)c0 * DMODEL;
  const int lr = lane >> 3;                 // row within 8-row stripe
  const int lk = ((lane & 7) ^ lr) * 8;     // pre-swizzled source chunk

  int tokA[4];
#pragma unroll
  for (int i = 0; i < 4; ++i) tokA[i] = idxe[n0 + wid * 32 + i * 8 + lr];

  f32x4 acc[8][4];
#pragma unroll
  for (int i = 0; i < 8; ++i)
#pragma unroll
    for (int j = 0; j < 4; ++j) acc[i][j] = (f32x4){0.f, 0.f, 0.f, 0.f};

  FFN1_STAGE(As0, Bs0, 0);
  __syncthreads();
#pragma unroll 1
  for (int kt = 0; kt < 32; kt += 2) {
    FFN1_STAGE(As1, Bs1, (kt + 1) * 64);   // prefetch odd tile
    FFN1_COMPUTE(As0, Bs0);                // compute even tile
    __syncthreads();                       // drains vmcnt for odd tile
    if (kt + 2 < 32) FFN1_STAGE(As0, Bs0, (kt + 2) * 64);
    FFN1_COMPUTE(As1, Bs1);
    __syncthreads();
  }

  // Epilogue: h = silu(g)*u*gw -> Hb compact rows; pads write exact 0.
  const int fhalf = c0 >> 1;
#pragma unroll
  for (int nf = 0; nf < 8; ++nf) {
#pragma unroll
    for (int j = 0; j < 4; ++j) {
      const int n = n0 + arow + nf * 16 + (lane >> 4) * 4 + j;
      const bool valid = n < cnte;
      const int tok = valid ? idxe[n] : 0;
      const float gwv = gw[(size_t)tok * NEXP + e];
#pragma unroll
      for (int p = 0; p < 2; ++p) {
        const float gv = acc[nf][2 * p][j];
        const float uv = acc[nf][2 * p + 1][j];
        const float h = (gv / (1.f + expf(-gv))) * uv * gwv;
        const int f = fhalf + ((wid & 3) * 2 + p) * 16 + (lane & 15);
        Hbe[(size_t)n * DFF + f] = valid ? f2bf(h) : (short)0;
      }
    }
  }
}

// ===========================================================================
// ffn2_gemm_db: R9 change — 128x128 tile + DOUBLE-BUFFERED LDS (the R8-proven
// stage-ahead pattern). 64 KB LDS -> 2 blocks/CU keeps occupancy. Swizzle
// retained (conflicts 0). Sequential per expert (out RMW determinism).
// ===========================================================================
#define FFN2_STAGE(AS, BS, k0)                                                 \
  _Pragma("unroll") for (int i_ = 0; i_ < 4; ++i_) {                           \
    const int row_ = wid * 32 + i_ * 8;                                        \
    GLOAD_LDS(Ab + (size_t)(row_ + lr) * DFF + (k0) + lk,                      \
              (char*)(AS) + row_ * 128);                                       \
    GLOAD_LDS(Bb + (size_t)(row_ + lr) * DFF + (k0) + lk,                      \
              (char*)(BS) + row_ * 128);                                       \
  }

#define FFN2_COMPUTE(AS, BS)                                                   \
  _Pragma("unroll") for (int ks_ = 0; ks_ < 2; ++ks_) {                        \
    const int cswz_ = ((ks_ * 4 + (lane >> 4)) ^ (lane & 7)) << 4;             \
    short8 af_[4], bf_[4];                                                     \
    _Pragma("unroll") for (int q_ = 0; q_ < 4; ++q_) {                         \
      af_[q_] = *(const short8*)((const char*)(AS) +                           \
                (wr * 64 + q_ * 16 + (lane & 15)) * 128 + cswz_);              \
      bf_[q_] = *(const short8*)((const char*)(BS) +                           \
                (wc * 64 + q_ * 16 + (lane & 15)) * 128 + cswz_);              \
    }                                                                          \
    _Pragma("unroll") for (int nf_ = 0; nf_ < 4; ++nf_)                        \
      _Pragma("unroll") for (int ff_ = 0; ff_ < 4; ++ff_)                      \
        acc[nf_][ff_] = __builtin_amdgcn_mfma_f32_16x16x32_bf16(               \
            af_[nf_], bf_[ff_], acc[nf_][ff_], 0, 0, 0);                       \
  }

__global__ __launch_bounds__(256, 2) void ffn2_gemm_db(
    const short* __restrict__ Hbe, const short* __restrict__ wdb,
    const int* __restrict__ idx, const int* __restrict__ cnt,
    float* __restrict__ out, float* __restrict__ dummy, int e) {
  const int cnte = cnt[e];
  const int n0 = blockIdx.y * 128;
  if (n0 >= cnte) return;
  __shared__ __align__(16) short As0[128 * 64];
  __shared__ __align__(16) short Bs0[128 * 64];
  __shared__ __align__(16) short As1[128 * 64];
  __shared__ __align__(16) short Bs1[128 * 64];

  const int c0 = blockIdx.x * 128;
  const int t = threadIdx.x, lane = t & 63, wid = t >> 6;
  const int wr = wid >> 1, wc = wid & 1;
  const int* idxe = idx + (size_t)e * NTOK;
  const short* Ab = Hbe + (size_t)n0 * DFF;
  const short* Bb = wdb + (size_t)e * DMODEL * DFF + (size_t)c0 * DFF;
  const int lr = lane >> 3;
  const int lk = ((lane & 7) ^ lr) * 8;

  f32x4 acc[4][4];
#pragma unroll
  for (int i = 0; i < 4; ++i)
#pragma unroll
    for (int j = 0; j < 4; ++j) acc[i][j] = (f32x4){0.f, 0.f, 0.f, 0.f};

  FFN2_STAGE(As0, Bs0, 0);
  __syncthreads();
#pragma unroll 1
  for (int kt = 0; kt < 16; kt += 2) {
    FFN2_STAGE(As1, Bs1, (kt + 1) * 64);   // prefetch odd tile
    FFN2_COMPUTE(As0, Bs0);                // compute even tile
    __syncthreads();
    if (kt + 2 < 16) FFN2_STAGE(As0, Bs0, (kt + 2) * 64);
    FFN2_COMPUTE(As1, Bs1);
    __syncthreads();
  }

#pragma unroll
  for (int nf = 0; nf < 4; ++nf) {
#pragma unroll
    for (int j = 0; j < 4; ++j) {
      const int n = n0 + wr * 64 + nf * 16 + (lane >> 4) * 4 + j;
      const bool valid = n < cnte;
      const int tok = valid ? idxe[n] : 0;
      float* bp = valid ? (out + (size_t)tok * DMODEL) : dummy;
#pragma unroll
      for (int ff = 0; ff < 4; ++ff) {
        const int d = c0 + wc * 64 + ff * 16 + (lane & 15);
        bp[valid ? d : (d & 2047)] += acc[nf][ff][j];
      }
    }
  }
}

// ---------------------------------------------------------------------------
extern "C" void kernel_launch(void* const* d_in, const int* in_sizes, int n_in,
                              void* d_out, int out_size, void* d_ws, size_t ws_size,
                              hipStream_t stream) {
  const float* x      = (const float*)d_in[0];
  const float* W_A    = (const float*)d_in[1];
  const float* gscale = (const float*)d_in[2];
  const float* gbias  = (const float*)d_in[3];
  const float* wg     = (const float*)d_in[4];
  const float* wu     = (const float*)d_in[5];
  const float* wd     = (const float*)d_in[6];

  float* out       = (float*)d_out;                // [N, D]
  float* score_out = out + (size_t)NTOK * DMODEL;  // [N, E]

  // ws layout: gw f32[N*E] | idx i32[E*N] | cnt i32[16] | dummy f32[D] |
  //            xb bf16[N*D] | wgu bf16[E*2048*D] | wdb bf16[E*D*F] | Hb bf16
  const size_t CNT = (size_t)16777216;
  size_t off = 0;
  float* gw    = (float*)((char*)d_ws + off); off += (size_t)NTOK * NEXP * 4;
  int*   idx   = (int*)((char*)d_ws + off);   off += (size_t)NEXP * NTOK * 4;
  int*   cnt   = (int*)((char*)d_ws + off);   off += 16 * 4;
  float* dummy = (float*)((char*)d_ws + off); off += (size_t)DMODEL * 4;
  short* xb    = (short*)((char*)d_ws + off); off += CNT * 2;
  short* wgu   = (short*)((char*)d_ws + off); off += CNT * 4;
  short* wdb   = (short*)((char*)d_ws + off); off += CNT * 2;
  short* Hb    = (short*)((char*)d_ws + off);
  const size_t needA = off + (size_t)NEXP * NTOK * DFF * 2;  // per-expert Hb

  prep_zero<<<2048, 256, 0, stream>>>((float4*)out, (int4*)idx);
  cvt_kernel<<<2048, 256, 0, stream>>>(x,  xb,  (int)(CNT / 8));
  cvt_kernel<<<2048, 256, 0, stream>>>(wd, wdb, (int)(CNT / 8));
  pack_gu<<<2048, 256, 0, stream>>>(wg, wu, wgu);
  gate_v3<<<NTOK / 32, 256, 0, stream>>>(x, W_A, gscale, gbias, gw,
                                         score_out, idx, cnt);

  if (ws_size >= needA) {
    // Tier A: all experts' ffn1 in ONE dispatch; per-expert Hb regions.
    ffn1_gemm256<<<dim3(2048 / 256, NTOK / 256, NEXP), 512, 0, stream>>>(
        xb, wgu, idx, cnt, gw, Hb, -1);
    for (int e = 0; e < NEXP; ++e)
      ffn2_gemm_db<<<dim3(DMODEL / 128, NTOK / 128), 256, 0, stream>>>(
          Hb + (size_t)e * NTOK * DFF, wdb, idx, cnt, out, dummy, e);
  } else {
    // Tier B: shared Hb, sequential per expert.
    for (int e = 0; e < NEXP; ++e) {
      ffn1_gemm256<<<dim3(2048 / 256, NTOK / 256), 512, 0, stream>>>(
          xb, wgu, idx, cnt, gw, Hb, e);
      ffn2_gemm_db<<<dim3(DMODEL / 128, NTOK / 128), 256, 0, stream>>>(
          Hb, wdb, idx, cnt, out, dummy, e);
    }
  }
}

// Round 10
// 1037.833 us; speedup vs baseline: 1.8408x; 1.0012x over previous
//
#include <hip/hip_runtime.h>
#include <hip/hip_bf16.h>
#include <math.h>

// Problem constants
#define NTOK   8192
#define DMODEL 2048
#define NEXP   8
#define RGATE  8
#define DFF    1024

#define NEG_SENTINEL (-3.0e38f)

using f32x4  = __attribute__((ext_vector_type(4))) float;
using short8 = __attribute__((ext_vector_type(8))) short;

// RNE float->bf16
static __device__ __forceinline__ short f2bf(float f) {
  union { float f; unsigned u; } v; v.f = f;
  unsigned r = v.u + 0x7fffu + ((v.u >> 16) & 1u);
  return (short)(r >> 16);
}
static __device__ __forceinline__ float bf2f(short s) {
  union { unsigned u; float f; } v; v.u = ((unsigned)(unsigned short)s) << 16;
  return v.f;
}
static __device__ __forceinline__ short8 cvt8(const float4 a, const float4 b) {
  short8 o;
  o[0] = f2bf(a.x); o[1] = f2bf(a.y); o[2] = f2bf(a.z); o[3] = f2bf(a.w);
  o[4] = f2bf(b.x); o[5] = f2bf(b.y); o[6] = f2bf(b.z); o[7] = f2bf(b.w);
  return o;
}

#define GLOAD_LDS(gp, lp)                                                  \
  __builtin_amdgcn_global_load_lds(                                        \
      (const __attribute__((address_space(1))) void*)(gp),                 \
      (__attribute__((address_space(3))) void*)(lp), 16, 0, 0)

// ---------------------------------------------------------------------------
// prep_zero: always zero idx+pos+cnt block; zero out[N,D] only when the
// RMW fallback tier runs (Tier C's reduce_out fully overwrites out).
// ---------------------------------------------------------------------------
__global__ __launch_bounds__(256) void prep_zero(
    float4* __restrict__ out4, int4* __restrict__ ic4, int nIc4, int zero_out) {
  const int stride = gridDim.x * blockDim.x;
  const float4 z4 = make_float4(0.f, 0.f, 0.f, 0.f);
  for (int i = blockIdx.x * blockDim.x + threadIdx.x;
       i < NTOK * DMODEL / 4; i += stride) {
    if (zero_out) out4[i] = z4;
    if (i < nIc4) ic4[i] = make_int4(0, 0, 0, 0);
    if (!zero_out && i >= nIc4) break;
  }
}

// ---------------------------------------------------------------------------
// cvt: fp32 -> bf16
// ---------------------------------------------------------------------------
__global__ __launch_bounds__(256) void cvt_kernel(
    const float* __restrict__ in, short* __restrict__ out, int n8) {
  const int stride = gridDim.x * blockDim.x;
  for (int i = blockIdx.x * blockDim.x + threadIdx.x; i < n8; i += stride) {
    const float4 a = ((const float4*)in)[(size_t)i * 2];
    const float4 b = ((const float4*)in)[(size_t)i * 2 + 1];
    ((short8*)out)[i] = cvt8(a, b);
  }
}

// ---------------------------------------------------------------------------
// pack_gu: interleave wg/wu rows in 16-row groups.
// ---------------------------------------------------------------------------
__global__ __launch_bounds__(256) void pack_gu(
    const float* __restrict__ wg, const float* __restrict__ wu,
    short* __restrict__ wgu) {
  const int stride = gridDim.x * blockDim.x;
  const int total = NEXP * 2048 * (DMODEL / 8);
  for (int i = blockIdx.x * blockDim.x + threadIdx.x; i < total; i += stride) {
    const int c = i & 255;
    const int r = (i >> 8) & 2047;
    const int e = i >> 19;
    const int sel = (r >> 4) & 1;
    const int f = ((r >> 5) << 4) + (r & 15);
    const float* src = (sel ? wu : wg) + ((size_t)(e * DFF + f)) * DMODEL + c * 8;
    const float4 a = *(const float4*)src;
    const float4 b = *(const float4*)(src + 4);
    ((short8*)wgu)[i] = cvt8(a, b);
  }
}

// ---------------------------------------------------------------------------
// gate_v3: register outer-product gate (R6-proven) + pos[e][n] inverse map.
// ---------------------------------------------------------------------------
__global__ __launch_bounds__(256) void gate_v3(
    const float* __restrict__ x, const float* __restrict__ W_A,
    const float* __restrict__ gscale, const float* __restrict__ gbias,
    float* __restrict__ gw, float* __restrict__ score_out,
    int* __restrict__ idx, int* __restrict__ pos, int* __restrict__ cnt) {
  __shared__ float ghs[32][65];
  const int tok0 = blockIdx.x * 32;
  const int t = threadIdx.x;
  const int ks = t & 3;
  const int posn = t >> 2;
  const int tg = posn & 7;
  const int rg = posn >> 3;
  const float* xp = x + (size_t)(tok0 + tg * 4) * DMODEL;
  const float* wp = W_A + (size_t)(rg * 8) * DMODEL;

  float acc[4][8];
#pragma unroll
  for (int i = 0; i < 4; ++i)
#pragma unroll
    for (int r = 0; r < 8; ++r) acc[i][r] = 0.f;

  float4 xa_[4], wa_[8], xb_[4], wb_[8];
  auto loadj = [&](int j, float4* xv, float4* wv) {
    const int k = ks * 4 + j * 16;
#pragma unroll
    for (int i = 0; i < 4; ++i) xv[i] = *(const float4*)(xp + (size_t)i * DMODEL + k);
#pragma unroll
    for (int r = 0; r < 8; ++r) wv[r] = *(const float4*)(wp + (size_t)r * DMODEL + k);
  };
  auto fmaj = [&](const float4* xv, const float4* wv) {
#pragma unroll
    for (int i = 0; i < 4; ++i)
#pragma unroll
      for (int r = 0; r < 8; ++r) {
        acc[i][r] = fmaf(xv[i].x, wv[r].x, acc[i][r]);
        acc[i][r] = fmaf(xv[i].y, wv[r].y, acc[i][r]);
        acc[i][r] = fmaf(xv[i].z, wv[r].z, acc[i][r]);
        acc[i][r] = fmaf(xv[i].w, wv[r].w, acc[i][r]);
      }
  };

  loadj(0, xa_, wa_);
#pragma unroll 1
  for (int j = 0; j < 128; j += 2) {
    loadj(j + 1, xb_, wb_);
    fmaj(xa_, wa_);
    if (j + 2 < 128) loadj(j + 2, xa_, wa_);
    fmaj(xb_, wb_);
  }

#pragma unroll
  for (int i = 0; i < 4; ++i)
#pragma unroll
    for (int r = 0; r < 8; ++r) {
      float v = acc[i][r];
      v += __shfl_xor(v, 1);
      v += __shfl_xor(v, 2);
      acc[i][r] = v;
    }
  if (ks == 0) {
#pragma unroll
    for (int i = 0; i < 4; ++i)
#pragma unroll
      for (int r = 0; r < 8; ++r) ghs[tg * 4 + i][rg * 8 + r] = acc[i][r];
  }
  __syncthreads();

  {
    const int tk = t >> 3, e = t & 7;
    const int n = tok0 + tk;
    float ss = 0.f;
#pragma unroll
    for (int r = 0; r < RGATE; ++r) { const float v = ghs[tk][e * 8 + r]; ss += v * v; }
    const float score = sqrtf(ss) * gscale[e] - gbias[e];
    const bool m = (score >= 0.0f);
    const float sig = 1.0f / (1.0f + expf(-score));
    gw[(size_t)n * NEXP + e] = m ? sig : 0.0f;
    score_out[(size_t)n * NEXP + e] = m ? score : NEG_SENTINEL;
    int slot = -1;
    if (m) {
      slot = atomicAdd(&cnt[e], 1);
      idx[(size_t)e * NTOK + slot] = n;
    }
    pos[(size_t)e * NTOK + n] = slot;
  }
}

// ===========================================================================
// ffn1_gemm256: UNCHANGED from R8/R9 (proven: ~366 µs, conflicts 0).
// ===========================================================================
#define FFN1_STAGE(AS, BS, k0)                                                 \
  _Pragma("unroll") for (int i_ = 0; i_ < 4; ++i_) {                           \
    const int row_ = wid * 32 + i_ * 8;                                        \
    GLOAD_LDS(xb + (size_t)tokA[i_] * DMODEL + (k0) + lk,                      \
              (char*)(AS) + row_ * 128);                                       \
    GLOAD_LDS(Bb + (size_t)(row_ + lr) * DMODEL + (k0) + lk,                   \
              (char*)(BS) + row_ * 128);                                       \
  }

#define FFN1_COMPUTE(AS, BS)                                                   \
  _Pragma("unroll") for (int ks_ = 0; ks_ < 2; ++ks_) {                        \
    const int cswz_ = ((ks_ * 4 + (lane >> 4)) ^ (lane & 7)) << 4;             \
    short8 af_[8], bf_[4];                                                     \
    _Pragma("unroll") for (int q_ = 0; q_ < 8; ++q_)                           \
      af_[q_] = *(const short8*)((const char*)(AS) +                           \
                (arow + q_ * 16 + (lane & 15)) * 128 + cswz_);                 \
    _Pragma("unroll") for (int q_ = 0; q_ < 4; ++q_)                           \
      bf_[q_] = *(const short8*)((const char*)(BS) +                           \
                (brow + q_ * 16 + (lane & 15)) * 128 + cswz_);                 \
    _Pragma("unroll") for (int nf_ = 0; nf_ < 8; ++nf_)                        \
      _Pragma("unroll") for (int ff_ = 0; ff_ < 4; ++ff_)                      \
        acc[nf_][ff_] = __builtin_amdgcn_mfma_f32_16x16x32_bf16(               \
            af_[nf_], bf_[ff_], acc[nf_][ff_], 0, 0, 0);                       \
  }

__global__ __launch_bounds__(512, 2) void ffn1_gemm256(
    const short* __restrict__ xb, const short* __restrict__ wgu,
    const int* __restrict__ idx, const int* __restrict__ cnt,
    const float* __restrict__ gw, short* __restrict__ Hb, int e_arg) {
  const int e = (e_arg < 0) ? (int)blockIdx.z : e_arg;
  short* __restrict__ Hbe = Hb + ((e_arg < 0) ? (size_t)e * NTOK * DFF : (size_t)0);
  const int cnte = cnt[e];
  const int n0 = blockIdx.y * 256;
  if (n0 >= cnte) return;

  __shared__ __align__(16) short As0[256 * 64];
  __shared__ __align__(16) short Bs0[256 * 64];
  __shared__ __align__(16) short As1[256 * 64];
  __shared__ __align__(16) short Bs1[256 * 64];

  const int c0 = blockIdx.x * 256;
  const int t = threadIdx.x, lane = t & 63, wid = t >> 6;
  const int arow = (wid >> 2) * 128;
  const int brow = (wid & 3) * 64;
  const int* idxe = idx + (size_t)e * NTOK;
  const short* Bb = wgu + (size_t)e * 2048 * DMODEL + (size_t)c0 * DMODEL;
  const int lr = lane >> 3;
  const int lk = ((lane & 7) ^ lr) * 8;

  int tokA[4];
#pragma unroll
  for (int i = 0; i < 4; ++i) tokA[i] = idxe[n0 + wid * 32 + i * 8 + lr];

  f32x4 acc[8][4];
#pragma unroll
  for (int i = 0; i < 8; ++i)
#pragma unroll
    for (int j = 0; j < 4; ++j) acc[i][j] = (f32x4){0.f, 0.f, 0.f, 0.f};

  FFN1_STAGE(As0, Bs0, 0);
  __syncthreads();
#pragma unroll 1
  for (int kt = 0; kt < 32; kt += 2) {
    FFN1_STAGE(As1, Bs1, (kt + 1) * 64);
    FFN1_COMPUTE(As0, Bs0);
    __syncthreads();
    if (kt + 2 < 32) FFN1_STAGE(As0, Bs0, (kt + 2) * 64);
    FFN1_COMPUTE(As1, Bs1);
    __syncthreads();
  }

  const int fhalf = c0 >> 1;
#pragma unroll
  for (int nf = 0; nf < 8; ++nf) {
#pragma unroll
    for (int j = 0; j < 4; ++j) {
      const int n = n0 + arow + nf * 16 + (lane >> 4) * 4 + j;
      const bool valid = n < cnte;
      const int tok = valid ? idxe[n] : 0;
      const float gwv = gw[(size_t)tok * NEXP + e];
#pragma unroll
      for (int p = 0; p < 2; ++p) {
        const float gv = acc[nf][2 * p][j];
        const float uv = acc[nf][2 * p + 1][j];
        const float h = (gv / (1.f + expf(-gv))) * uv * gwv;
        const int f = fhalf + ((wid & 3) * 2 + p) * 16 + (lane & 15);
        Hbe[(size_t)n * DFF + f] = valid ? f2bf(h) : (short)0;
      }
    }
  }
}

// ===========================================================================
// ffn2 staging/compute macros (shared by Tier C z-fused and fallback kernels)
// ===========================================================================
#define FFN2_STAGE(AS, BS, k0)                                                 \
  _Pragma("unroll") for (int i_ = 0; i_ < 4; ++i_) {                           \
    const int row_ = wid * 32 + i_ * 8;                                        \
    GLOAD_LDS(Ab + (size_t)(row_ + lr) * DFF + (k0) + lk,                      \
              (char*)(AS) + row_ * 128);                                       \
    GLOAD_LDS(Bb + (size_t)(row_ + lr) * DFF + (k0) + lk,                      \
              (char*)(BS) + row_ * 128);                                       \
  }

#define FFN2_COMPUTE(AS, BS)                                                   \
  _Pragma("unroll") for (int ks_ = 0; ks_ < 2; ++ks_) {                        \
    const int cswz_ = ((ks_ * 4 + (lane >> 4)) ^ (lane & 7)) << 4;             \
    short8 af_[4], bf_[4];                                                     \
    _Pragma("unroll") for (int q_ = 0; q_ < 4; ++q_) {                         \
      af_[q_] = *(const short8*)((const char*)(AS) +                           \
                (wr * 64 + q_ * 16 + (lane & 15)) * 128 + cswz_);              \
      bf_[q_] = *(const short8*)((const char*)(BS) +                           \
                (wc * 64 + q_ * 16 + (lane & 15)) * 128 + cswz_);              \
    }                                                                          \
    _Pragma("unroll") for (int nf_ = 0; nf_ < 4; ++nf_)                        \
      _Pragma("unroll") for (int ff_ = 0; ff_ < 4; ++ff_)                      \
        acc[nf_][ff_] = __builtin_amdgcn_mfma_f32_16x16x32_bf16(               \
            af_[nf_], bf_[ff_], acc[nf_][ff_], 0, 0, 0);                       \
  }

// ---------------------------------------------------------------------------
// ffn2z_gemm (Tier C): one dispatch, blockIdx.z = expert. Writes bf16 compact
// partial rows into Cp[e] — NO out RMW, no inter-expert ordering.
// ---------------------------------------------------------------------------
__global__ __launch_bounds__(256, 2) void ffn2z_gemm(
    const short* __restrict__ Hb, const short* __restrict__ wdb,
    const int* __restrict__ cnt, short* __restrict__ Cp) {
  const int e = blockIdx.z;
  const int cnte = cnt[e];
  const int n0 = blockIdx.y * 128;
  if (n0 >= cnte) return;
  __shared__ __align__(16) short As0[128 * 64];
  __shared__ __align__(16) short Bs0[128 * 64];
  __shared__ __align__(16) short As1[128 * 64];
  __shared__ __align__(16) short Bs1[128 * 64];

  const int c0 = blockIdx.x * 128;
  const int t = threadIdx.x, lane = t & 63, wid = t >> 6;
  const int wr = wid >> 1, wc = wid & 1;
  const short* Ab = Hb + (size_t)e * NTOK * DFF + (size_t)n0 * DFF;
  const short* Bb = wdb + (size_t)e * DMODEL * DFF + (size_t)c0 * DFF;
  short* Cpe = Cp + (size_t)e * NTOK * DMODEL;
  const int lr = lane >> 3;
  const int lk = ((lane & 7) ^ lr) * 8;

  f32x4 acc[4][4];
#pragma unroll
  for (int i = 0; i < 4; ++i)
#pragma unroll
    for (int j = 0; j < 4; ++j) acc[i][j] = (f32x4){0.f, 0.f, 0.f, 0.f};

  FFN2_STAGE(As0, Bs0, 0);
  __syncthreads();
#pragma unroll 1
  for (int kt = 0; kt < 16; kt += 2) {
    FFN2_STAGE(As1, Bs1, (kt + 1) * 64);
    FFN2_COMPUTE(As0, Bs0);
    __syncthreads();
    if (kt + 2 < 16) FFN2_STAGE(As0, Bs0, (kt + 2) * 64);
    FFN2_COMPUTE(As1, Bs1);
    __syncthreads();
  }

#pragma unroll
  for (int nf = 0; nf < 4; ++nf) {
#pragma unroll
    for (int j = 0; j < 4; ++j) {
      const int n = n0 + wr * 64 + nf * 16 + (lane >> 4) * 4 + j;
      if (n < cnte) {
#pragma unroll
        for (int ff = 0; ff < 4; ++ff) {
          const int d = c0 + wc * 64 + ff * 16 + (lane & 15);
          Cpe[(size_t)n * DMODEL + d] = f2bf(acc[nf][ff][j]);
        }
      }
    }
  }
}

// ---------------------------------------------------------------------------
// reduce_out (Tier C): out[n,:] = sum_e Cp[e][pos[e][n],:]. One block/token,
// coalesced 4KB row gathers; fixed e-order (deterministic); fully overwrites
// poisoned out.
// ---------------------------------------------------------------------------
__global__ __launch_bounds__(256) void reduce_out(
    const short* __restrict__ Cp, const int* __restrict__ pos,
    float* __restrict__ out) {
  const int n = blockIdx.x;
  const int t = threadIdx.x;
  float acc[8] = {0.f, 0.f, 0.f, 0.f, 0.f, 0.f, 0.f, 0.f};
#pragma unroll
  for (int e = 0; e < NEXP; ++e) {
    const int p = pos[(size_t)e * NTOK + n];
    if (p >= 0) {  // block-uniform branch
      const short8 v = *(const short8*)(Cp + (size_t)e * NTOK * DMODEL +
                                        (size_t)p * DMODEL + t * 8);
#pragma unroll
      for (int j = 0; j < 8; ++j) acc[j] += bf2f(v[j]);
    }
  }
  float* op = out + (size_t)n * DMODEL + t * 8;
  *(float4*)op = make_float4(acc[0], acc[1], acc[2], acc[3]);
  *(float4*)(op + 4) = make_float4(acc[4], acc[5], acc[6], acc[7]);
}

// ---------------------------------------------------------------------------
// ffn2_gemm_db (fallback Tier A/B): R9-proven out-RMW version.
// ---------------------------------------------------------------------------
__global__ __launch_bounds__(256, 2) void ffn2_gemm_db(
    const short* __restrict__ Hbe, const short* __restrict__ wdb,
    const int* __restrict__ idx, const int* __restrict__ cnt,
    float* __restrict__ out, float* __restrict__ dummy, int e) {
  const int cnte = cnt[e];
  const int n0 = blockIdx.y * 128;
  if (n0 >= cnte) return;
  __shared__ __align__(16) short As0[128 * 64];
  __shared__ __align__(16) short Bs0[128 * 64];
  __shared__ __align__(16) short As1[128 * 64];
  __shared__ __align__(16) short Bs1[128 * 64];

  const int c0 = blockIdx.x * 128;
  const int t = threadIdx.x, lane = t & 63, wid = t >> 6;
  const int wr = wid >> 1, wc = wid & 1;
  const int* idxe = idx + (size_t)e * NTOK;
  const short* Ab = Hbe + (size_t)n0 * DFF;
  const short* Bb = wdb + (size_t)e * DMODEL * DFF + (size_t)c0 * DFF;
  const int lr = lane >> 3;
  const int lk = ((lane & 7) ^ lr) * 8;

  f32x4 acc[4][4];
#pragma unroll
  for (int i = 0; i < 4; ++i)
#pragma unroll
    for (int j = 0; j < 4; ++j) acc[i][j] = (f32x4){0.f, 0.f, 0.f, 0.f};

  FFN2_STAGE(As0, Bs0, 0);
  __syncthreads();
#pragma unroll 1
  for (int kt = 0; kt < 16; kt += 2) {
    FFN2_STAGE(As1, Bs1, (kt + 1) * 64);
    FFN2_COMPUTE(As0, Bs0);
    __syncthreads();
    if (kt + 2 < 16) FFN2_STAGE(As0, Bs0, (kt + 2) * 64);
    FFN2_COMPUTE(As1, Bs1);
    __syncthreads();
  }

#pragma unroll
  for (int nf = 0; nf < 4; ++nf) {
#pragma unroll
    for (int j = 0; j < 4; ++j) {
      const int n = n0 + wr * 64 + nf * 16 + (lane >> 4) * 4 + j;
      const bool valid = n < cnte;
      const int tok = valid ? idxe[n] : 0;
      float* bp = valid ? (out + (size_t)tok * DMODEL) : dummy;
#pragma unroll
      for (int ff = 0; ff < 4; ++ff) {
        const int d = c0 + wc * 64 + ff * 16 + (lane & 15);
        bp[valid ? d : (d & 2047)] += acc[nf][ff][j];
      }
    }
  }
}

// ---------------------------------------------------------------------------
extern "C" void kernel_launch(void* const* d_in, const int* in_sizes, int n_in,
                              void* d_out, int out_size, void* d_ws, size_t ws_size,
                              hipStream_t stream) {
  const float* x      = (const float*)d_in[0];
  const float* W_A    = (const float*)d_in[1];
  const float* gscale = (const float*)d_in[2];
  const float* gbias  = (const float*)d_in[3];
  const float* wg     = (const float*)d_in[4];
  const float* wu     = (const float*)d_in[5];
  const float* wd     = (const float*)d_in[6];

  float* out       = (float*)d_out;                // [N, D]
  float* score_out = out + (size_t)NTOK * DMODEL;  // [N, E]

  // Reordered ws layout (xb/wgu LAST so Tier C's Cp can alias them — both
  // are dead after ffn1):
  // gw | idx | pos | cnt | dummy | wdb | Hb(8x) | xb | wgu  [| Cp aliases xb..]
  const size_t CNT = (size_t)16777216;
  size_t off = 0;
  float* gw    = (float*)((char*)d_ws + off); off += (size_t)NTOK * NEXP * 4;
  int*   idx   = (int*)((char*)d_ws + off);   off += (size_t)NEXP * NTOK * 4;
  int*   pos   = (int*)((char*)d_ws + off);   off += (size_t)NEXP * NTOK * 4;
  int*   cnt   = (int*)((char*)d_ws + off);   off += 16 * 4;
  float* dummy = (float*)((char*)d_ws + off); off += (size_t)DMODEL * 4;
  short* wdb   = (short*)((char*)d_ws + off); off += CNT * 2;
  const size_t hb_off = off;
  short* Hb    = (short*)((char*)d_ws + off); off += (size_t)NEXP * NTOK * DFF * 2;
  const size_t xb_off = off;
  short* xb    = (short*)((char*)d_ws + off); off += CNT * 2;
  short* wgu   = (short*)((char*)d_ws + off); off += CNT * 4;
  const size_t needA = off;                                        // ~257 MB
  short* Cp    = (short*)((char*)d_ws + xb_off);
  const size_t needC = xb_off + (size_t)NEXP * NTOK * DMODEL * 2;  // ~417 MB

  const bool tierC = (ws_size >= needC);
  const bool tierA = (ws_size >= needA);

  // Tier B layout (shared Hb): xb/wgu right after a 1-expert Hb.
  short* HbB  = Hb;
  short* xbB  = (short*)((char*)d_ws + hb_off + (size_t)NTOK * DFF * 2);
  short* wguB = xbB + CNT;

  const int nIc4 = (int)((2 * NEXP * NTOK + 16) / 4);  // idx + pos + cnt
  prep_zero<<<2048, 256, 0, stream>>>((float4*)out, (int4*)idx, nIc4,
                                      tierC ? 0 : 1);

  short* xbT  = tierA ? xb : xbB;
  short* wguT = tierA ? wgu : wguB;
  cvt_kernel<<<2048, 256, 0, stream>>>(x,  xbT,  (int)(CNT / 8));
  cvt_kernel<<<2048, 256, 0, stream>>>(wd, wdb, (int)(CNT / 8));
  pack_gu<<<2048, 256, 0, stream>>>(wg, wu, wguT);
  gate_v3<<<NTOK / 32, 256, 0, stream>>>(x, W_A, gscale, gbias, gw,
                                         score_out, idx, pos, cnt);

  if (tierC) {
    ffn1_gemm256<<<dim3(2048 / 256, NTOK / 256, NEXP), 512, 0, stream>>>(
        xb, wgu, idx, cnt, gw, Hb, -1);
    ffn2z_gemm<<<dim3(DMODEL / 128, NTOK / 128, NEXP), 256, 0, stream>>>(
        Hb, wdb, cnt, Cp);
    reduce_out<<<NTOK, 256, 0, stream>>>(Cp, pos, out);
  } else if (tierA) {
    ffn1_gemm256<<<dim3(2048 / 256, NTOK / 256, NEXP), 512, 0, stream>>>(
        xb, wgu, idx, cnt, gw, Hb, -1);
    for (int e = 0; e < NEXP; ++e)
      ffn2_gemm_db<<<dim3(DMODEL / 128, NTOK / 128), 256, 0, stream>>>(
          Hb + (size_t)e * NTOK * DFF, wdb, idx, cnt, out, dummy, e);
  } else {
    for (int e = 0; e < NEXP; ++e) {
      ffn1_gemm256<<<dim3(2048 / 256, NTOK / 256), 512, 0, stream>>>(
          xbB, wguB, idx, cnt, gw, HbB, e);
      ffn2_gemm_db<<<dim3(DMODEL / 128, NTOK / 128), 256, 0, stream>>>(
          HbB, wdb, idx, cnt, out, dummy, e);
    }
  }
}

// Round 11
// 876.917 us; speedup vs baseline: 2.1786x; 1.1835x over previous
//
#include <hip/hip_runtime.h>
#include <hip/hip_bf16.h>
#include <math.h>

// Problem constants
#define NTOK   8192
#define DMODEL 2048
#define NEXP   8
#define RGATE  8
#define DFF    1024

#define NEG_SENTINEL (-3.0e38f)

using f32x4  = __attribute__((ext_vector_type(4))) float;
using short8 = __attribute__((ext_vector_type(8))) short;

// RNE float->bf16
static __device__ __forceinline__ short f2bf(float f) {
  union { float f; unsigned u; } v; v.f = f;
  unsigned r = v.u + 0x7fffu + ((v.u >> 16) & 1u);
  return (short)(r >> 16);
}
static __device__ __forceinline__ float bf2f(short s) {
  union { unsigned u; float f; } v; v.u = ((unsigned)(unsigned short)s) << 16;
  return v.f;
}
static __device__ __forceinline__ short8 cvt8(const float4 a, const float4 b) {
  short8 o;
  o[0] = f2bf(a.x); o[1] = f2bf(a.y); o[2] = f2bf(a.z); o[3] = f2bf(a.w);
  o[4] = f2bf(b.x); o[5] = f2bf(b.y); o[6] = f2bf(b.z); o[7] = f2bf(b.w);
  return o;
}

#define GLOAD_LDS(gp, lp)                                                  \
  __builtin_amdgcn_global_load_lds(                                        \
      (const __attribute__((address_space(1))) void*)(gp),                 \
      (__attribute__((address_space(3))) void*)(lp), 16, 0, 0)

// ---------------------------------------------------------------------------
// prep_zero: zero idx+pos+cnt; zero out only when an RMW path will run.
// ---------------------------------------------------------------------------
__global__ __launch_bounds__(256) void prep_zero(
    float4* __restrict__ out4, int4* __restrict__ ic4, int nIc4, int zero_out) {
  const int stride = gridDim.x * blockDim.x;
  const float4 z4 = make_float4(0.f, 0.f, 0.f, 0.f);
  for (int i = blockIdx.x * blockDim.x + threadIdx.x;
       i < NTOK * DMODEL / 4; i += stride) {
    if (zero_out) out4[i] = z4;
    if (i < nIc4) ic4[i] = make_int4(0, 0, 0, 0);
    if (!zero_out && i >= nIc4) break;
  }
}

// ---------------------------------------------------------------------------
// cvt: fp32 -> bf16
// ---------------------------------------------------------------------------
__global__ __launch_bounds__(256) void cvt_kernel(
    const float* __restrict__ in, short* __restrict__ out, int n8) {
  const int stride = gridDim.x * blockDim.x;
  for (int i = blockIdx.x * blockDim.x + threadIdx.x; i < n8; i += stride) {
    const float4 a = ((const float4*)in)[(size_t)i * 2];
    const float4 b = ((const float4*)in)[(size_t)i * 2 + 1];
    ((short8*)out)[i] = cvt8(a, b);
  }
}

// ---------------------------------------------------------------------------
// pack_gu: interleave wg/wu rows in 16-row groups.
// ---------------------------------------------------------------------------
__global__ __launch_bounds__(256) void pack_gu(
    const float* __restrict__ wg, const float* __restrict__ wu,
    short* __restrict__ wgu) {
  const int stride = gridDim.x * blockDim.x;
  const int total = NEXP * 2048 * (DMODEL / 8);
  for (int i = blockIdx.x * blockDim.x + threadIdx.x; i < total; i += stride) {
    const int c = i & 255;
    const int r = (i >> 8) & 2047;
    const int e = i >> 19;
    const int sel = (r >> 4) & 1;
    const int f = ((r >> 5) << 4) + (r & 15);
    const float* src = (sel ? wu : wg) + ((size_t)(e * DFF + f)) * DMODEL + c * 8;
    const float4 a = *(const float4*)src;
    const float4 b = *(const float4*)(src + 4);
    ((short8*)wgu)[i] = cvt8(a, b);
  }
}

// ---------------------------------------------------------------------------
// gate_v3: register outer-product gate + pos[e][n] inverse map (R10-proven).
// ---------------------------------------------------------------------------
__global__ __launch_bounds__(256) void gate_v3(
    const float* __restrict__ x, const float* __restrict__ W_A,
    const float* __restrict__ gscale, const float* __restrict__ gbias,
    float* __restrict__ gw, float* __restrict__ score_out,
    int* __restrict__ idx, int* __restrict__ pos, int* __restrict__ cnt) {
  __shared__ float ghs[32][65];
  const int tok0 = blockIdx.x * 32;
  const int t = threadIdx.x;
  const int ks = t & 3;
  const int posn = t >> 2;
  const int tg = posn & 7;
  const int rg = posn >> 3;
  const float* xp = x + (size_t)(tok0 + tg * 4) * DMODEL;
  const float* wp = W_A + (size_t)(rg * 8) * DMODEL;

  float acc[4][8];
#pragma unroll
  for (int i = 0; i < 4; ++i)
#pragma unroll
    for (int r = 0; r < 8; ++r) acc[i][r] = 0.f;

  float4 xa_[4], wa_[8], xb_[4], wb_[8];
  auto loadj = [&](int j, float4* xv, float4* wv) {
    const int k = ks * 4 + j * 16;
#pragma unroll
    for (int i = 0; i < 4; ++i) xv[i] = *(const float4*)(xp + (size_t)i * DMODEL + k);
#pragma unroll
    for (int r = 0; r < 8; ++r) wv[r] = *(const float4*)(wp + (size_t)r * DMODEL + k);
  };
  auto fmaj = [&](const float4* xv, const float4* wv) {
#pragma unroll
    for (int i = 0; i < 4; ++i)
#pragma unroll
      for (int r = 0; r < 8; ++r) {
        acc[i][r] = fmaf(xv[i].x, wv[r].x, acc[i][r]);
        acc[i][r] = fmaf(xv[i].y, wv[r].y, acc[i][r]);
        acc[i][r] = fmaf(xv[i].z, wv[r].z, acc[i][r]);
        acc[i][r] = fmaf(xv[i].w, wv[r].w, acc[i][r]);
      }
  };

  loadj(0, xa_, wa_);
#pragma unroll 1
  for (int j = 0; j < 128; j += 2) {
    loadj(j + 1, xb_, wb_);
    fmaj(xa_, wa_);
    if (j + 2 < 128) loadj(j + 2, xa_, wa_);
    fmaj(xb_, wb_);
  }

#pragma unroll
  for (int i = 0; i < 4; ++i)
#pragma unroll
    for (int r = 0; r < 8; ++r) {
      float v = acc[i][r];
      v += __shfl_xor(v, 1);
      v += __shfl_xor(v, 2);
      acc[i][r] = v;
    }
  if (ks == 0) {
#pragma unroll
    for (int i = 0; i < 4; ++i)
#pragma unroll
      for (int r = 0; r < 8; ++r) ghs[tg * 4 + i][rg * 8 + r] = acc[i][r];
  }
  __syncthreads();

  {
    const int tk = t >> 3, e = t & 7;
    const int n = tok0 + tk;
    float ss = 0.f;
#pragma unroll
    for (int r = 0; r < RGATE; ++r) { const float v = ghs[tk][e * 8 + r]; ss += v * v; }
    const float score = sqrtf(ss) * gscale[e] - gbias[e];
    const bool m = (score >= 0.0f);
    const float sig = 1.0f / (1.0f + expf(-score));
    gw[(size_t)n * NEXP + e] = m ? sig : 0.0f;
    score_out[(size_t)n * NEXP + e] = m ? score : NEG_SENTINEL;
    int slot = -1;
    if (m) {
      slot = atomicAdd(&cnt[e], 1);
      idx[(size_t)e * NTOK + slot] = n;
    }
    pos[(size_t)e * NTOK + n] = slot;
  }
}

// ===========================================================================
// ffn1_gemm256: UNCHANGED (R8-proven: ~366 µs, conflicts 0, MfmaUtil 29%).
// ===========================================================================
#define FFN1_STAGE(AS, BS, k0)                                                 \
  _Pragma("unroll") for (int i_ = 0; i_ < 4; ++i_) {                           \
    const int row_ = wid * 32 + i_ * 8;                                        \
    GLOAD_LDS(xb + (size_t)tokA[i_] * DMODEL + (k0) + lk,                      \
              (char*)(AS) + row_ * 128);                                       \
    GLOAD_LDS(Bb + (size_t)(row_ + lr) * DMODEL + (k0) + lk,                   \
              (char*)(BS) + row_ * 128);                                       \
  }

#define FFN1_COMPUTE(AS, BS)                                                   \
  _Pragma("unroll") for (int ks_ = 0; ks_ < 2; ++ks_) {                        \
    const int cswz_ = ((ks_ * 4 + (lane >> 4)) ^ (lane & 7)) << 4;             \
    short8 af_[8], bf_[4];                                                     \
    _Pragma("unroll") for (int q_ = 0; q_ < 8; ++q_)                           \
      af_[q_] = *(const short8*)((const char*)(AS) +                           \
                (arow + q_ * 16 + (lane & 15)) * 128 + cswz_);                 \
    _Pragma("unroll") for (int q_ = 0; q_ < 4; ++q_)                           \
      bf_[q_] = *(const short8*)((const char*)(BS) +                           \
                (brow + q_ * 16 + (lane & 15)) * 128 + cswz_);                 \
    _Pragma("unroll") for (int nf_ = 0; nf_ < 8; ++nf_)                        \
      _Pragma("unroll") for (int ff_ = 0; ff_ < 4; ++ff_)                      \
        acc[nf_][ff_] = __builtin_amdgcn_mfma_f32_16x16x32_bf16(               \
            af_[nf_], bf_[ff_], acc[nf_][ff_], 0, 0, 0);                       \
  }

__global__ __launch_bounds__(512, 2) void ffn1_gemm256(
    const short* __restrict__ xb, const short* __restrict__ wgu,
    const int* __restrict__ idx, const int* __restrict__ cnt,
    const float* __restrict__ gw, short* __restrict__ Hb, int e_arg) {
  const int e = (e_arg < 0) ? (int)blockIdx.z : e_arg;
  short* __restrict__ Hbe = Hb + ((e_arg < 0) ? (size_t)e * NTOK * DFF : (size_t)0);
  const int cnte = cnt[e];
  const int n0 = blockIdx.y * 256;
  if (n0 >= cnte) return;

  __shared__ __align__(16) short As0[256 * 64];
  __shared__ __align__(16) short Bs0[256 * 64];
  __shared__ __align__(16) short As1[256 * 64];
  __shared__ __align__(16) short Bs1[256 * 64];

  const int c0 = blockIdx.x * 256;
  const int t = threadIdx.x, lane = t & 63, wid = t >> 6;
  const int arow = (wid >> 2) * 128;
  const int brow = (wid & 3) * 64;
  const int* idxe = idx + (size_t)e * NTOK;
  const short* Bb = wgu + (size_t)e * 2048 * DMODEL + (size_t)c0 * DMODEL;
  const int lr = lane >> 3;
  const int lk = ((lane & 7) ^ lr) * 8;

  int tokA[4];
#pragma unroll
  for (int i = 0; i < 4; ++i) tokA[i] = idxe[n0 + wid * 32 + i * 8 + lr];

  f32x4 acc[8][4];
#pragma unroll
  for (int i = 0; i < 8; ++i)
#pragma unroll
    for (int j = 0; j < 4; ++j) acc[i][j] = (f32x4){0.f, 0.f, 0.f, 0.f};

  FFN1_STAGE(As0, Bs0, 0);
  __syncthreads();
#pragma unroll 1
  for (int kt = 0; kt < 32; kt += 2) {
    FFN1_STAGE(As1, Bs1, (kt + 1) * 64);
    FFN1_COMPUTE(As0, Bs0);
    __syncthreads();
    if (kt + 2 < 32) FFN1_STAGE(As0, Bs0, (kt + 2) * 64);
    FFN1_COMPUTE(As1, Bs1);
    __syncthreads();
  }

  const int fhalf = c0 >> 1;
#pragma unroll
  for (int nf = 0; nf < 8; ++nf) {
#pragma unroll
    for (int j = 0; j < 4; ++j) {
      const int n = n0 + arow + nf * 16 + (lane >> 4) * 4 + j;
      const bool valid = n < cnte;
      const int tok = valid ? idxe[n] : 0;
      const float gwv = gw[(size_t)tok * NEXP + e];
#pragma unroll
      for (int p = 0; p < 2; ++p) {
        const float gv = acc[nf][2 * p][j];
        const float uv = acc[nf][2 * p + 1][j];
        const float h = (gv / (1.f + expf(-gv))) * uv * gwv;
        const int f = fhalf + ((wid & 3) * 2 + p) * 16 + (lane & 15);
        Hbe[(size_t)n * DFF + f] = valid ? f2bf(h) : (short)0;
      }
    }
  }
}

// ===========================================================================
// ffn2 staging/compute macros
// ===========================================================================
#define FFN2_STAGE(AS, BS, k0)                                                 \
  _Pragma("unroll") for (int i_ = 0; i_ < 4; ++i_) {                           \
    const int row_ = wid * 32 + i_ * 8;                                        \
    GLOAD_LDS(Ab + (size_t)(row_ + lr) * DFF + (k0) + lk,                      \
              (char*)(AS) + row_ * 128);                                       \
    GLOAD_LDS(Bb + (size_t)(row_ + lr) * DFF + (k0) + lk,                      \
              (char*)(BS) + row_ * 128);                                       \
  }

#define FFN2_COMPUTE(AS, BS)                                                   \
  _Pragma("unroll") for (int ks_ = 0; ks_ < 2; ++ks_) {                        \
    const int cswz_ = ((ks_ * 4 + (lane >> 4)) ^ (lane & 7)) << 4;             \
    short8 af_[4], bf_[4];                                                     \
    _Pragma("unroll") for (int q_ = 0; q_ < 4; ++q_) {                         \
      af_[q_] = *(const short8*)((const char*)(AS) +                           \
                (wr * 64 + q_ * 16 + (lane & 15)) * 128 + cswz_);              \
      bf_[q_] = *(const short8*)((const char*)(BS) +                           \
                (wc * 64 + q_ * 16 + (lane & 15)) * 128 + cswz_);              \
    }                                                                          \
    _Pragma("unroll") for (int nf_ = 0; nf_ < 4; ++nf_)                        \
      _Pragma("unroll") for (int ff_ = 0; ff_ < 4; ++ff_)                      \
        acc[nf_][ff_] = __builtin_amdgcn_mfma_f32_16x16x32_bf16(               \
            af_[nf_], bf_[ff_], acc[nf_][ff_], 0, 0, 0);                       \
  }

// ---------------------------------------------------------------------------
// ffn2z_gemm: expert GROUP pass. e = e0 + blockIdx.z; bf16 compact partials
// into Cp slice z (no out RMW, tails overlap across the group).
// ---------------------------------------------------------------------------
__global__ __launch_bounds__(256, 2) void ffn2z_gemm(
    const short* __restrict__ Hb, const short* __restrict__ wdb,
    const int* __restrict__ cnt, short* __restrict__ Cp, int e0) {
  const int e = e0 + blockIdx.z;
  const int cnte = cnt[e];
  const int n0 = blockIdx.y * 128;
  if (n0 >= cnte) return;
  __shared__ __align__(16) short As0[128 * 64];
  __shared__ __align__(16) short Bs0[128 * 64];
  __shared__ __align__(16) short As1[128 * 64];
  __shared__ __align__(16) short Bs1[128 * 64];

  const int c0 = blockIdx.x * 128;
  const int t = threadIdx.x, lane = t & 63, wid = t >> 6;
  const int wr = wid >> 1, wc = wid & 1;
  const short* Ab = Hb + (size_t)e * NTOK * DFF + (size_t)n0 * DFF;
  const short* Bb = wdb + (size_t)e * DMODEL * DFF + (size_t)c0 * DFF;
  short* Cpe = Cp + (size_t)blockIdx.z * NTOK * DMODEL;
  const int lr = lane >> 3;
  const int lk = ((lane & 7) ^ lr) * 8;

  f32x4 acc[4][4];
#pragma unroll
  for (int i = 0; i < 4; ++i)
#pragma unroll
    for (int j = 0; j < 4; ++j) acc[i][j] = (f32x4){0.f, 0.f, 0.f, 0.f};

  FFN2_STAGE(As0, Bs0, 0);
  __syncthreads();
#pragma unroll 1
  for (int kt = 0; kt < 16; kt += 2) {
    FFN2_STAGE(As1, Bs1, (kt + 1) * 64);
    FFN2_COMPUTE(As0, Bs0);
    __syncthreads();
    if (kt + 2 < 16) FFN2_STAGE(As0, Bs0, (kt + 2) * 64);
    FFN2_COMPUTE(As1, Bs1);
    __syncthreads();
  }

#pragma unroll
  for (int nf = 0; nf < 4; ++nf) {
#pragma unroll
    for (int j = 0; j < 4; ++j) {
      const int n = n0 + wr * 64 + nf * 16 + (lane >> 4) * 4 + j;
      if (n < cnte) {
#pragma unroll
        for (int ff = 0; ff < 4; ++ff) {
          const int d = c0 + wc * 64 + ff * 16 + (lane & 15);
          Cpe[(size_t)n * DMODEL + d] = f2bf(acc[nf][ff][j]);
        }
      }
    }
  }
}

// ---------------------------------------------------------------------------
// reduce_out_g: out[n,:] (=|+=) sum_{e in group} Cp[z][pos[e][n],:].
// One block/token; coalesced 4KB row gathers; fixed e-order (deterministic).
// Pass 0 overwrites out (covers poison).
// ---------------------------------------------------------------------------
__global__ __launch_bounds__(256) void reduce_out_g(
    const short* __restrict__ Cp, const int* __restrict__ pos,
    float* __restrict__ out, int e0, int ge, int accum) {
  const int n = blockIdx.x;
  const int t = threadIdx.x;
  float* op = out + (size_t)n * DMODEL + t * 8;
  float acc[8];
  if (accum) {
    const float4 a = *(const float4*)op;
    const float4 b = *(const float4*)(op + 4);
    acc[0] = a.x; acc[1] = a.y; acc[2] = a.z; acc[3] = a.w;
    acc[4] = b.x; acc[5] = b.y; acc[6] = b.z; acc[7] = b.w;
  } else {
#pragma unroll
    for (int j = 0; j < 8; ++j) acc[j] = 0.f;
  }
  for (int el = 0; el < ge; ++el) {  // uniform bound, uniform branch
    const int p = pos[(size_t)(e0 + el) * NTOK + n];
    if (p >= 0) {
      const short8 v = *(const short8*)(Cp + (size_t)el * NTOK * DMODEL +
                                        (size_t)p * DMODEL + t * 8);
#pragma unroll
      for (int j = 0; j < 8; ++j) acc[j] += bf2f(v[j]);
    }
  }
  *(float4*)op = make_float4(acc[0], acc[1], acc[2], acc[3]);
  *(float4*)(op + 4) = make_float4(acc[4], acc[5], acc[6], acc[7]);
}

// ---------------------------------------------------------------------------
// ffn2_gemm_db (fallback Tier B): R9-proven out-RMW version.
// ---------------------------------------------------------------------------
__global__ __launch_bounds__(256, 2) void ffn2_gemm_db(
    const short* __restrict__ Hbe, const short* __restrict__ wdb,
    const int* __restrict__ idx, const int* __restrict__ cnt,
    float* __restrict__ out, float* __restrict__ dummy, int e) {
  const int cnte = cnt[e];
  const int n0 = blockIdx.y * 128;
  if (n0 >= cnte) return;
  __shared__ __align__(16) short As0[128 * 64];
  __shared__ __align__(16) short Bs0[128 * 64];
  __shared__ __align__(16) short As1[128 * 64];
  __shared__ __align__(16) short Bs1[128 * 64];

  const int c0 = blockIdx.x * 128;
  const int t = threadIdx.x, lane = t & 63, wid = t >> 6;
  const int wr = wid >> 1, wc = wid & 1;
  const int* idxe = idx + (size_t)e * NTOK;
  const short* Ab = Hbe + (size_t)n0 * DFF;
  const short* Bb = wdb + (size_t)e * DMODEL * DFF + (size_t)c0 * DFF;
  const int lr = lane >> 3;
  const int lk = ((lane & 7) ^ lr) * 8;

  f32x4 acc[4][4];
#pragma unroll
  for (int i = 0; i < 4; ++i)
#pragma unroll
    for (int j = 0; j < 4; ++j) acc[i][j] = (f32x4){0.f, 0.f, 0.f, 0.f};

  FFN2_STAGE(As0, Bs0, 0);
  __syncthreads();
#pragma unroll 1
  for (int kt = 0; kt < 16; kt += 2) {
    FFN2_STAGE(As1, Bs1, (kt + 1) * 64);
    FFN2_COMPUTE(As0, Bs0);
    __syncthreads();
    if (kt + 2 < 16) FFN2_STAGE(As0, Bs0, (kt + 2) * 64);
    FFN2_COMPUTE(As1, Bs1);
    __syncthreads();
  }

#pragma unroll
  for (int nf = 0; nf < 4; ++nf) {
#pragma unroll
    for (int j = 0; j < 4; ++j) {
      const int n = n0 + wr * 64 + nf * 16 + (lane >> 4) * 4 + j;
      const bool valid = n < cnte;
      const int tok = valid ? idxe[n] : 0;
      float* bp = valid ? (out + (size_t)tok * DMODEL) : dummy;
#pragma unroll
      for (int ff = 0; ff < 4; ++ff) {
        const int d = c0 + wc * 64 + ff * 16 + (lane & 15);
        bp[valid ? d : (d & 2047)] += acc[nf][ff][j];
      }
    }
  }
}

// ---------------------------------------------------------------------------
extern "C" void kernel_launch(void* const* d_in, const int* in_sizes, int n_in,
                              void* d_out, int out_size, void* d_ws, size_t ws_size,
                              hipStream_t stream) {
  const float* x      = (const float*)d_in[0];
  const float* W_A    = (const float*)d_in[1];
  const float* gscale = (const float*)d_in[2];
  const float* gbias  = (const float*)d_in[3];
  const float* wg     = (const float*)d_in[4];
  const float* wu     = (const float*)d_in[5];
  const float* wd     = (const float*)d_in[6];

  float* out       = (float*)d_out;                // [N, D]
  float* score_out = out + (size_t)NTOK * DMODEL;  // [N, E]

  // ws layout: gw | idx | pos | cnt | dummy | wdb | Hb(8x) | xb | wgu
  // Tier-C-grouped: Cp (G x 32MB slices) aliases xb+wgu (dead after ffn1).
  const size_t CNT = (size_t)16777216;
  const size_t CP_SLICE = (size_t)NTOK * DMODEL * 2;  // 32 MB
  size_t off = 0;
  float* gw    = (float*)((char*)d_ws + off); off += (size_t)NTOK * NEXP * 4;
  int*   idx   = (int*)((char*)d_ws + off);   off += (size_t)NEXP * NTOK * 4;
  int*   pos   = (int*)((char*)d_ws + off);   off += (size_t)NEXP * NTOK * 4;
  int*   cnt   = (int*)((char*)d_ws + off);   off += 16 * 4;
  float* dummy = (float*)((char*)d_ws + off); off += (size_t)DMODEL * 4;
  short* wdb   = (short*)((char*)d_ws + off); off += CNT * 2;
  const size_t hb_off = off;
  short* Hb    = (short*)((char*)d_ws + off); off += (size_t)NEXP * NTOK * DFF * 2;
  const size_t xb_off = off;
  short* xb    = (short*)((char*)d_ws + off); off += CNT * 2;
  short* wgu   = (short*)((char*)d_ws + off); off += CNT * 4;
  const size_t needA = off;
  short* Cp    = (short*)((char*)d_ws + xb_off);

  const bool tierA = (ws_size >= needA);
  int G = 0;
  if (tierA) {
    size_t avail = ws_size - xb_off;
    G = (int)(avail / CP_SLICE);
    if (G > NEXP) G = NEXP;
  }

  // Tier B layout (shared Hb)
  short* HbB  = Hb;
  short* xbB  = (short*)((char*)d_ws + hb_off + (size_t)NTOK * DFF * 2);
  short* wguB = xbB + CNT;

  const int nIc4 = (int)((2 * NEXP * NTOK + 16) / 4);  // idx + pos + cnt
  const int zero_out = (tierA && G >= 1) ? 0 : 1;
  prep_zero<<<2048, 256, 0, stream>>>((float4*)out, (int4*)idx, nIc4, zero_out);

  short* xbT  = tierA ? xb : xbB;
  short* wguT = tierA ? wgu : wguB;
  cvt_kernel<<<2048, 256, 0, stream>>>(x,  xbT,  (int)(CNT / 8));
  cvt_kernel<<<2048, 256, 0, stream>>>(wd, wdb, (int)(CNT / 8));
  pack_gu<<<2048, 256, 0, stream>>>(wg, wu, wguT);
  gate_v3<<<NTOK / 32, 256, 0, stream>>>(x, W_A, gscale, gbias, gw,
                                         score_out, idx, pos, cnt);

  if (tierA && G >= 1) {
    ffn1_gemm256<<<dim3(2048 / 256, NTOK / 256, NEXP), 512, 0, stream>>>(
        xb, wgu, idx, cnt, gw, Hb, -1);
    // Grouped expert passes: ffn2z (write partials) -> reduce (gather-sum).
    const int np = (NEXP + G - 1) / G;
    int e0 = 0;
    for (int p = 0; p < np; ++p) {
      const int rem_p = np - p;
      const int ge = (NEXP - e0 + rem_p - 1) / rem_p;  // balanced group size
      ffn2z_gemm<<<dim3(DMODEL / 128, NTOK / 128, ge), 256, 0, stream>>>(
          Hb, wdb, cnt, Cp, e0);
      reduce_out_g<<<NTOK, 256, 0, stream>>>(Cp, pos, out, e0, ge, p > 0);
      e0 += ge;
    }
  } else if (tierA) {
    ffn1_gemm256<<<dim3(2048 / 256, NTOK / 256, NEXP), 512, 0, stream>>>(
        xb, wgu, idx, cnt, gw, Hb, -1);
    for (int e = 0; e < NEXP; ++e)
      ffn2_gemm_db<<<dim3(DMODEL / 128, NTOK / 128), 256, 0, stream>>>(
          Hb + (size_t)e * NTOK * DFF, wdb, idx, cnt, out, dummy, e);
  } else {
    for (int e = 0; e < NEXP; ++e) {
      ffn1_gemm256<<<dim3(2048 / 256, NTOK / 256), 512, 0, stream>>>(
          xbB, wguB, idx, cnt, gw, HbB, e);
      ffn2_gemm_db<<<dim3(DMODEL / 128, NTOK / 128), 256, 0, stream>>>(
          HbB, wdb, idx, cnt, out, dummy, e);
    }
  }
}

// Round 12
// 826.733 us; speedup vs baseline: 2.3109x; 1.0607x over previous
//
#include <hip/hip_runtime.h>
#include <hip/hip_bf16.h>
#include <math.h>

// Problem constants
#define NTOK   8192
#define DMODEL 2048
#define NEXP   8
#define RGATE  8
#define DFF    1024

#define NEG_SENTINEL (-3.0e38f)

using f32x4  = __attribute__((ext_vector_type(4))) float;
using short8 = __attribute__((ext_vector_type(8))) short;

// RNE float->bf16
static __device__ __forceinline__ short f2bf(float f) {
  union { float f; unsigned u; } v; v.f = f;
  unsigned r = v.u + 0x7fffu + ((v.u >> 16) & 1u);
  return (short)(r >> 16);
}
static __device__ __forceinline__ float bf2f(short s) {
  union { unsigned u; float f; } v; v.u = ((unsigned)(unsigned short)s) << 16;
  return v.f;
}
static __device__ __forceinline__ short8 cvt8(const float4 a, const float4 b) {
  short8 o;
  o[0] = f2bf(a.x); o[1] = f2bf(a.y); o[2] = f2bf(a.z); o[3] = f2bf(a.w);
  o[4] = f2bf(b.x); o[5] = f2bf(b.y); o[6] = f2bf(b.z); o[7] = f2bf(b.w);
  return o;
}

#define GLOAD_LDS(gp, lp)                                                  \
  __builtin_amdgcn_global_load_lds(                                        \
      (const __attribute__((address_space(1))) void*)(gp),                 \
      (__attribute__((address_space(3))) void*)(lp), 16, 0, 0)

// ---------------------------------------------------------------------------
// prep_all: ONE kernel for {zero cnt, cvt x->xb, cvt wd->wdb, pack wg/wu->wgu,
// optional out zero}. Segmented grid-stride; saves 4 dispatch gaps. idx/pos
// need no zeroing (gate writes pos fully; idx reads are clamped below cnt).
// ---------------------------------------------------------------------------
#define SEG_CVT  2097152              // CNT/8 16B-chunk count
#define SEG_PACK 4194304              // NEXP*2048*(DMODEL/8)
__global__ __launch_bounds__(256) void prep_all(
    const float* __restrict__ x, const float* __restrict__ wd,
    const float* __restrict__ wg, const float* __restrict__ wu,
    short* __restrict__ xb, short* __restrict__ wdb, short* __restrict__ wgu,
    int* __restrict__ cnt, float4* __restrict__ out4, int zero_out) {
  if (blockIdx.x == 0 && threadIdx.x < 16) cnt[threadIdx.x] = 0;
  const int stride = gridDim.x * blockDim.x;
  const int total = SEG_CVT * 2 + SEG_PACK + (zero_out ? SEG_CVT : 0);
  for (int i = blockIdx.x * blockDim.x + threadIdx.x; i < total; i += stride) {
    if (i < SEG_CVT) {
      const float4 a = ((const float4*)x)[(size_t)i * 2];
      const float4 b = ((const float4*)x)[(size_t)i * 2 + 1];
      ((short8*)xb)[i] = cvt8(a, b);
    } else if (i < 2 * SEG_CVT) {
      const int j = i - SEG_CVT;
      const float4 a = ((const float4*)wd)[(size_t)j * 2];
      const float4 b = ((const float4*)wd)[(size_t)j * 2 + 1];
      ((short8*)wdb)[j] = cvt8(a, b);
    } else if (i < 2 * SEG_CVT + SEG_PACK) {
      const int j = i - 2 * SEG_CVT;
      const int c = j & 255;
      const int r = (j >> 8) & 2047;
      const int e = j >> 19;
      const int sel = (r >> 4) & 1;
      const int f = ((r >> 5) << 4) + (r & 15);
      const float* src = (sel ? wu : wg) + ((size_t)(e * DFF + f)) * DMODEL + c * 8;
      const float4 a = *(const float4*)src;
      const float4 b = *(const float4*)(src + 4);
      ((short8*)wgu)[j] = cvt8(a, b);
    } else {
      const int j = i - (2 * SEG_CVT + SEG_PACK);
      out4[(size_t)j * 2] = make_float4(0.f, 0.f, 0.f, 0.f);
      out4[(size_t)j * 2 + 1] = make_float4(0.f, 0.f, 0.f, 0.f);
    }
  }
}

// ---------------------------------------------------------------------------
// gate_v3: register outer-product gate + pos[e][n] inverse map (R10-proven).
// ---------------------------------------------------------------------------
__global__ __launch_bounds__(256) void gate_v3(
    const float* __restrict__ x, const float* __restrict__ W_A,
    const float* __restrict__ gscale, const float* __restrict__ gbias,
    float* __restrict__ gw, float* __restrict__ score_out,
    int* __restrict__ idx, int* __restrict__ pos, int* __restrict__ cnt) {
  __shared__ float ghs[32][65];
  const int tok0 = blockIdx.x * 32;
  const int t = threadIdx.x;
  const int ks = t & 3;
  const int posn = t >> 2;
  const int tg = posn & 7;
  const int rg = posn >> 3;
  const float* xp = x + (size_t)(tok0 + tg * 4) * DMODEL;
  const float* wp = W_A + (size_t)(rg * 8) * DMODEL;

  float acc[4][8];
#pragma unroll
  for (int i = 0; i < 4; ++i)
#pragma unroll
    for (int r = 0; r < 8; ++r) acc[i][r] = 0.f;

  float4 xa_[4], wa_[8], xb_[4], wb_[8];
  auto loadj = [&](int j, float4* xv, float4* wv) {
    const int k = ks * 4 + j * 16;
#pragma unroll
    for (int i = 0; i < 4; ++i) xv[i] = *(const float4*)(xp + (size_t)i * DMODEL + k);
#pragma unroll
    for (int r = 0; r < 8; ++r) wv[r] = *(const float4*)(wp + (size_t)r * DMODEL + k);
  };
  auto fmaj = [&](const float4* xv, const float4* wv) {
#pragma unroll
    for (int i = 0; i < 4; ++i)
#pragma unroll
      for (int r = 0; r < 8; ++r) {
        acc[i][r] = fmaf(xv[i].x, wv[r].x, acc[i][r]);
        acc[i][r] = fmaf(xv[i].y, wv[r].y, acc[i][r]);
        acc[i][r] = fmaf(xv[i].z, wv[r].z, acc[i][r]);
        acc[i][r] = fmaf(xv[i].w, wv[r].w, acc[i][r]);
      }
  };

  loadj(0, xa_, wa_);
#pragma unroll 1
  for (int j = 0; j < 128; j += 2) {
    loadj(j + 1, xb_, wb_);
    fmaj(xa_, wa_);
    if (j + 2 < 128) loadj(j + 2, xa_, wa_);
    fmaj(xb_, wb_);
  }

#pragma unroll
  for (int i = 0; i < 4; ++i)
#pragma unroll
    for (int r = 0; r < 8; ++r) {
      float v = acc[i][r];
      v += __shfl_xor(v, 1);
      v += __shfl_xor(v, 2);
      acc[i][r] = v;
    }
  if (ks == 0) {
#pragma unroll
    for (int i = 0; i < 4; ++i)
#pragma unroll
      for (int r = 0; r < 8; ++r) ghs[tg * 4 + i][rg * 8 + r] = acc[i][r];
  }
  __syncthreads();

  {
    const int tk = t >> 3, e = t & 7;
    const int n = tok0 + tk;
    float ss = 0.f;
#pragma unroll
    for (int r = 0; r < RGATE; ++r) { const float v = ghs[tk][e * 8 + r]; ss += v * v; }
    const float score = sqrtf(ss) * gscale[e] - gbias[e];
    const bool m = (score >= 0.0f);
    const float sig = 1.0f / (1.0f + expf(-score));
    gw[(size_t)n * NEXP + e] = m ? sig : 0.0f;
    score_out[(size_t)n * NEXP + e] = m ? score : NEG_SENTINEL;
    int slot = -1;
    if (m) {
      slot = atomicAdd(&cnt[e], 1);
      idx[(size_t)e * NTOK + slot] = n;
    }
    pos[(size_t)e * NTOK + n] = slot;
  }
}

// ===========================================================================
// ffn1_gemm256: R8 structure + R12 changes: (a) quadrant-phased compute
// (per-quadrant ds_reads feed 16-MFMA clusters — gives the scheduler
// read/MFMA role diversity across waves), (b) s_setprio(1/0) around MFMA
// clusters (T5; correctness-neutral hint), (c) idx reads clamped (idx no
// longer pre-zeroed).
// ===========================================================================
#define FFN1_STAGE(AS, BS, k0)                                                 \
  _Pragma("unroll") for (int i_ = 0; i_ < 4; ++i_) {                           \
    const int row_ = wid * 32 + i_ * 8;                                        \
    GLOAD_LDS(xb + (size_t)tokA[i_] * DMODEL + (k0) + lk,                      \
              (char*)(AS) + row_ * 128);                                       \
    GLOAD_LDS(Bb + (size_t)(row_ + lr) * DMODEL + (k0) + lk,                   \
              (char*)(BS) + row_ * 128);                                       \
  }

#define CSWZ(ks_) ((((ks_) * 4 + (lane >> 4)) ^ (lane & 7)) << 4)

#define FFN1_COMPUTE(AS, BS)                                                   \
  _Pragma("unroll") for (int ah_ = 0; ah_ < 2; ++ah_) {                        \
    short8 af_[4][2];                                                          \
    _Pragma("unroll") for (int q_ = 0; q_ < 4; ++q_)                           \
      _Pragma("unroll") for (int ks_ = 0; ks_ < 2; ++ks_)                      \
        af_[q_][ks_] = *(const short8*)((const char*)(AS) +                    \
            (arow + (ah_ * 4 + q_) * 16 + (lane & 15)) * 128 + CSWZ(ks_));     \
    _Pragma("unroll") for (int bh_ = 0; bh_ < 2; ++bh_) {                      \
      short8 bf_[2][2];                                                        \
      _Pragma("unroll") for (int q_ = 0; q_ < 2; ++q_)                         \
        _Pragma("unroll") for (int ks_ = 0; ks_ < 2; ++ks_)                    \
          bf_[q_][ks_] = *(const short8*)((const char*)(BS) +                  \
              (brow + (bh_ * 2 + q_) * 16 + (lane & 15)) * 128 + CSWZ(ks_));   \
      __builtin_amdgcn_s_setprio(1);                                           \
      _Pragma("unroll") for (int ks_ = 0; ks_ < 2; ++ks_)                      \
        _Pragma("unroll") for (int nf_ = 0; nf_ < 4; ++nf_)                    \
          _Pragma("unroll") for (int ff_ = 0; ff_ < 2; ++ff_)                  \
            acc[ah_ * 4 + nf_][bh_ * 2 + ff_] =                                \
                __builtin_amdgcn_mfma_f32_16x16x32_bf16(                       \
                    af_[nf_][ks_], bf_[ff_][ks_],                              \
                    acc[ah_ * 4 + nf_][bh_ * 2 + ff_], 0, 0, 0);               \
      __builtin_amdgcn_s_setprio(0);                                           \
    }                                                                          \
  }

__global__ __launch_bounds__(512, 2) void ffn1_gemm256(
    const short* __restrict__ xb, const short* __restrict__ wgu,
    const int* __restrict__ idx, const int* __restrict__ cnt,
    const float* __restrict__ gw, short* __restrict__ Hb, int e_arg) {
  const int e = (e_arg < 0) ? (int)blockIdx.z : e_arg;
  short* __restrict__ Hbe = Hb + ((e_arg < 0) ? (size_t)e * NTOK * DFF : (size_t)0);
  const int cnte = cnt[e];
  const int n0 = blockIdx.y * 256;
  if (n0 >= cnte) return;

  __shared__ __align__(16) short As0[256 * 64];
  __shared__ __align__(16) short Bs0[256 * 64];
  __shared__ __align__(16) short As1[256 * 64];
  __shared__ __align__(16) short Bs1[256 * 64];

  const int c0 = blockIdx.x * 256;
  const int t = threadIdx.x, lane = t & 63, wid = t >> 6;
  const int arow = (wid >> 2) * 128;
  const int brow = (wid & 3) * 64;
  const int* idxe = idx + (size_t)e * NTOK;
  const short* Bb = wgu + (size_t)e * 2048 * DMODEL + (size_t)c0 * DMODEL;
  const int lr = lane >> 3;
  const int lk = ((lane & 7) ^ lr) * 8;

  int tokA[4];
#pragma unroll
  for (int i = 0; i < 4; ++i) {
    int n = n0 + wid * 32 + i * 8 + lr;
    if (n >= cnte) n = cnte - 1;  // idx not pre-zeroed: clamp to valid slot
    tokA[i] = idxe[n];
  }

  f32x4 acc[8][4];
#pragma unroll
  for (int i = 0; i < 8; ++i)
#pragma unroll
    for (int j = 0; j < 4; ++j) acc[i][j] = (f32x4){0.f, 0.f, 0.f, 0.f};

  FFN1_STAGE(As0, Bs0, 0);
  __syncthreads();
#pragma unroll 1
  for (int kt = 0; kt < 32; kt += 2) {
    FFN1_STAGE(As1, Bs1, (kt + 1) * 64);
    FFN1_COMPUTE(As0, Bs0);
    __syncthreads();
    if (kt + 2 < 32) FFN1_STAGE(As0, Bs0, (kt + 2) * 64);
    FFN1_COMPUTE(As1, Bs1);
    __syncthreads();
  }

  const int fhalf = c0 >> 1;
#pragma unroll
  for (int nf = 0; nf < 8; ++nf) {
#pragma unroll
    for (int j = 0; j < 4; ++j) {
      const int n = n0 + arow + nf * 16 + (lane >> 4) * 4 + j;
      const bool valid = n < cnte;
      const int tok = valid ? idxe[n] : 0;
      const float gwv = gw[(size_t)tok * NEXP + e];
#pragma unroll
      for (int p = 0; p < 2; ++p) {
        const float gv = acc[nf][2 * p][j];
        const float uv = acc[nf][2 * p + 1][j];
        const float h = (gv / (1.f + expf(-gv))) * uv * gwv;
        const int f = fhalf + ((wid & 3) * 2 + p) * 16 + (lane & 15);
        Hbe[(size_t)n * DFF + f] = valid ? f2bf(h) : (short)0;
      }
    }
  }
}

// ===========================================================================
// ffn2 staging + phased compute (same T5 treatment)
// ===========================================================================
#define FFN2_STAGE(AS, BS, k0)                                                 \
  _Pragma("unroll") for (int i_ = 0; i_ < 4; ++i_) {                           \
    const int row_ = wid * 32 + i_ * 8;                                        \
    GLOAD_LDS(Ab + (size_t)(row_ + lr) * DFF + (k0) + lk,                      \
              (char*)(AS) + row_ * 128);                                       \
    GLOAD_LDS(Bb + (size_t)(row_ + lr) * DFF + (k0) + lk,                      \
              (char*)(BS) + row_ * 128);                                       \
  }

#define FFN2_COMPUTE(AS, BS)                                                   \
  {                                                                            \
    short8 af_[4][2];                                                          \
    _Pragma("unroll") for (int q_ = 0; q_ < 4; ++q_)                           \
      _Pragma("unroll") for (int ks_ = 0; ks_ < 2; ++ks_)                      \
        af_[q_][ks_] = *(const short8*)((const char*)(AS) +                    \
            (wr * 64 + q_ * 16 + (lane & 15)) * 128 + CSWZ(ks_));              \
    _Pragma("unroll") for (int bh_ = 0; bh_ < 2; ++bh_) {                      \
      short8 bf_[2][2];                                                        \
      _Pragma("unroll") for (int q_ = 0; q_ < 2; ++q_)                         \
        _Pragma("unroll") for (int ks_ = 0; ks_ < 2; ++ks_)                    \
          bf_[q_][ks_] = *(const short8*)((const char*)(BS) +                  \
              (wc * 64 + (bh_ * 2 + q_) * 16 + (lane & 15)) * 128 + CSWZ(ks_));\
      __builtin_amdgcn_s_setprio(1);                                           \
      _Pragma("unroll") for (int ks_ = 0; ks_ < 2; ++ks_)                      \
        _Pragma("unroll") for (int nf_ = 0; nf_ < 4; ++nf_)                    \
          _Pragma("unroll") for (int ff_ = 0; ff_ < 2; ++ff_)                  \
            acc[nf_][bh_ * 2 + ff_] =                                          \
                __builtin_amdgcn_mfma_f32_16x16x32_bf16(                       \
                    af_[nf_][ks_], bf_[ff_][ks_],                              \
                    acc[nf_][bh_ * 2 + ff_], 0, 0, 0);                         \
      __builtin_amdgcn_s_setprio(0);                                           \
    }                                                                          \
  }

// ---------------------------------------------------------------------------
// ffn2z_gemm: expert GROUP pass -> bf16 compact partials (R11-proven).
// ---------------------------------------------------------------------------
__global__ __launch_bounds__(256, 2) void ffn2z_gemm(
    const short* __restrict__ Hb, const short* __restrict__ wdb,
    const int* __restrict__ cnt, short* __restrict__ Cp, int e0) {
  const int e = e0 + blockIdx.z;
  const int cnte = cnt[e];
  const int n0 = blockIdx.y * 128;
  if (n0 >= cnte) return;
  __shared__ __align__(16) short As0[128 * 64];
  __shared__ __align__(16) short Bs0[128 * 64];
  __shared__ __align__(16) short As1[128 * 64];
  __shared__ __align__(16) short Bs1[128 * 64];

  const int c0 = blockIdx.x * 128;
  const int t = threadIdx.x, lane = t & 63, wid = t >> 6;
  const int wr = wid >> 1, wc = wid & 1;
  const short* Ab = Hb + (size_t)e * NTOK * DFF + (size_t)n0 * DFF;
  const short* Bb = wdb + (size_t)e * DMODEL * DFF + (size_t)c0 * DFF;
  short* Cpe = Cp + (size_t)blockIdx.z * NTOK * DMODEL;
  const int lr = lane >> 3;
  const int lk = ((lane & 7) ^ lr) * 8;

  f32x4 acc[4][4];
#pragma unroll
  for (int i = 0; i < 4; ++i)
#pragma unroll
    for (int j = 0; j < 4; ++j) acc[i][j] = (f32x4){0.f, 0.f, 0.f, 0.f};

  FFN2_STAGE(As0, Bs0, 0);
  __syncthreads();
#pragma unroll 1
  for (int kt = 0; kt < 16; kt += 2) {
    FFN2_STAGE(As1, Bs1, (kt + 1) * 64);
    FFN2_COMPUTE(As0, Bs0);
    __syncthreads();
    if (kt + 2 < 16) FFN2_STAGE(As0, Bs0, (kt + 2) * 64);
    FFN2_COMPUTE(As1, Bs1);
    __syncthreads();
  }

#pragma unroll
  for (int nf = 0; nf < 4; ++nf) {
#pragma unroll
    for (int j = 0; j < 4; ++j) {
      const int n = n0 + wr * 64 + nf * 16 + (lane >> 4) * 4 + j;
      if (n < cnte) {
#pragma unroll
        for (int ff = 0; ff < 4; ++ff) {
          const int d = c0 + wc * 64 + ff * 16 + (lane & 15);
          Cpe[(size_t)n * DMODEL + d] = f2bf(acc[nf][ff][j]);
        }
      }
    }
  }
}

// ---------------------------------------------------------------------------
// reduce_out_g: out[n,:] (=|+=) sum_{e in group} Cp[z][pos[e][n],:] (R11).
// ---------------------------------------------------------------------------
__global__ __launch_bounds__(256) void reduce_out_g(
    const short* __restrict__ Cp, const int* __restrict__ pos,
    float* __restrict__ out, int e0, int ge, int accum) {
  const int n = blockIdx.x;
  const int t = threadIdx.x;
  float* op = out + (size_t)n * DMODEL + t * 8;
  float acc[8];
  if (accum) {
    const float4 a = *(const float4*)op;
    const float4 b = *(const float4*)(op + 4);
    acc[0] = a.x; acc[1] = a.y; acc[2] = a.z; acc[3] = a.w;
    acc[4] = b.x; acc[5] = b.y; acc[6] = b.z; acc[7] = b.w;
  } else {
#pragma unroll
    for (int j = 0; j < 8; ++j) acc[j] = 0.f;
  }
  for (int el = 0; el < ge; ++el) {
    const int p = pos[(size_t)(e0 + el) * NTOK + n];
    if (p >= 0) {
      const short8 v = *(const short8*)(Cp + (size_t)el * NTOK * DMODEL +
                                        (size_t)p * DMODEL + t * 8);
#pragma unroll
      for (int j = 0; j < 8; ++j) acc[j] += bf2f(v[j]);
    }
  }
  *(float4*)op = make_float4(acc[0], acc[1], acc[2], acc[3]);
  *(float4*)(op + 4) = make_float4(acc[4], acc[5], acc[6], acc[7]);
}

// ---------------------------------------------------------------------------
// ffn2_gemm_db (fallback tiers): out-RMW version (R9-proven).
// ---------------------------------------------------------------------------
__global__ __launch_bounds__(256, 2) void ffn2_gemm_db(
    const short* __restrict__ Hbe, const short* __restrict__ wdb,
    const int* __restrict__ idx, const int* __restrict__ cnt,
    float* __restrict__ out, float* __restrict__ dummy, int e) {
  const int cnte = cnt[e];
  const int n0 = blockIdx.y * 128;
  if (n0 >= cnte) return;
  __shared__ __align__(16) short As0[128 * 64];
  __shared__ __align__(16) short Bs0[128 * 64];
  __shared__ __align__(16) short As1[128 * 64];
  __shared__ __align__(16) short Bs1[128 * 64];

  const int c0 = blockIdx.x * 128;
  const int t = threadIdx.x, lane = t & 63, wid = t >> 6;
  const int wr = wid >> 1, wc = wid & 1;
  const int* idxe = idx + (size_t)e * NTOK;
  const short* Ab = Hbe + (size_t)n0 * DFF;
  const short* Bb = wdb + (size_t)e * DMODEL * DFF + (size_t)c0 * DFF;
  const int lr = lane >> 3;
  const int lk = ((lane & 7) ^ lr) * 8;

  f32x4 acc[4][4];
#pragma unroll
  for (int i = 0; i < 4; ++i)
#pragma unroll
    for (int j = 0; j < 4; ++j) acc[i][j] = (f32x4){0.f, 0.f, 0.f, 0.f};

  FFN2_STAGE(As0, Bs0, 0);
  __syncthreads();
#pragma unroll 1
  for (int kt = 0; kt < 16; kt += 2) {
    FFN2_STAGE(As1, Bs1, (kt + 1) * 64);
    FFN2_COMPUTE(As0, Bs0);
    __syncthreads();
    if (kt + 2 < 16) FFN2_STAGE(As0, Bs0, (kt + 2) * 64);
    FFN2_COMPUTE(As1, Bs1);
    __syncthreads();
  }

#pragma unroll
  for (int nf = 0; nf < 4; ++nf) {
#pragma unroll
    for (int j = 0; j < 4; ++j) {
      const int n = n0 + wr * 64 + nf * 16 + (lane >> 4) * 4 + j;
      const bool valid = n < cnte;
      const int tok = valid ? idxe[n] : 0;
      float* bp = valid ? (out + (size_t)tok * DMODEL) : dummy;
#pragma unroll
      for (int ff = 0; ff < 4; ++ff) {
        const int d = c0 + wc * 64 + ff * 16 + (lane & 15);
        bp[valid ? d : (d & 2047)] += acc[nf][ff][j];
      }
    }
  }
}

// ---------------------------------------------------------------------------
extern "C" void kernel_launch(void* const* d_in, const int* in_sizes, int n_in,
                              void* d_out, int out_size, void* d_ws, size_t ws_size,
                              hipStream_t stream) {
  const float* x      = (const float*)d_in[0];
  const float* W_A    = (const float*)d_in[1];
  const float* gscale = (const float*)d_in[2];
  const float* gbias  = (const float*)d_in[3];
  const float* wg     = (const float*)d_in[4];
  const float* wu     = (const float*)d_in[5];
  const float* wd     = (const float*)d_in[6];

  float* out       = (float*)d_out;                // [N, D]
  float* score_out = out + (size_t)NTOK * DMODEL;  // [N, E]

  // ws layout: gw | idx | pos | cnt | dummy | wdb | Hb(8x) | xb | wgu
  // Tier-C-grouped: Cp (G x 32MB slices) aliases xb+wgu (dead after ffn1).
  const size_t CNT = (size_t)16777216;
  const size_t CP_SLICE = (size_t)NTOK * DMODEL * 2;  // 32 MB
  size_t off = 0;
  float* gw    = (float*)((char*)d_ws + off); off += (size_t)NTOK * NEXP * 4;
  int*   idx   = (int*)((char*)d_ws + off);   off += (size_t)NEXP * NTOK * 4;
  int*   pos   = (int*)((char*)d_ws + off);   off += (size_t)NEXP * NTOK * 4;
  int*   cnt   = (int*)((char*)d_ws + off);   off += 16 * 4;
  float* dummy = (float*)((char*)d_ws + off); off += (size_t)DMODEL * 4;
  short* wdb   = (short*)((char*)d_ws + off); off += CNT * 2;
  const size_t hb_off = off;
  short* Hb    = (short*)((char*)d_ws + off); off += (size_t)NEXP * NTOK * DFF * 2;
  const size_t xb_off = off;
  short* xb    = (short*)((char*)d_ws + off); off += CNT * 2;
  short* wgu   = (short*)((char*)d_ws + off); off += CNT * 4;
  const size_t needA = off;
  short* Cp    = (short*)((char*)d_ws + xb_off);

  const bool tierA = (ws_size >= needA);
  int G = 0;
  if (tierA) {
    size_t avail = ws_size - xb_off;
    G = (int)(avail / CP_SLICE);
    if (G > NEXP) G = NEXP;
  }

  // Tier B layout (shared Hb)
  short* HbB  = Hb;
  short* xbB  = (short*)((char*)d_ws + hb_off + (size_t)NTOK * DFF * 2);
  short* wguB = xbB + CNT;

  const int zero_out = (tierA && G >= 1) ? 0 : 1;
  short* xbT  = tierA ? xb : xbB;
  short* wguT = tierA ? wgu : wguB;

  prep_all<<<2048, 256, 0, stream>>>(x, wd, wg, wu, xbT, wdb, wguT, cnt,
                                     (float4*)out, zero_out);
  gate_v3<<<NTOK / 32, 256, 0, stream>>>(x, W_A, gscale, gbias, gw,
                                         score_out, idx, pos, cnt);

  if (tierA && G >= 1) {
    ffn1_gemm256<<<dim3(2048 / 256, NTOK / 256, NEXP), 512, 0, stream>>>(
        xb, wgu, idx, cnt, gw, Hb, -1);
    const int np = (NEXP + G - 1) / G;
    int e0 = 0;
    for (int p = 0; p < np; ++p) {
      const int rem_p = np - p;
      const int ge = (NEXP - e0 + rem_p - 1) / rem_p;
      ffn2z_gemm<<<dim3(DMODEL / 128, NTOK / 128, ge), 256, 0, stream>>>(
          Hb, wdb, cnt, Cp, e0);
      reduce_out_g<<<NTOK, 256, 0, stream>>>(Cp, pos, out, e0, ge, p > 0);
      e0 += ge;
    }
  } else if (tierA) {
    ffn1_gemm256<<<dim3(2048 / 256, NTOK / 256, NEXP), 512, 0, stream>>>(
        xb, wgu, idx, cnt, gw, Hb, -1);
    for (int e = 0; e < NEXP; ++e)
      ffn2_gemm_db<<<dim3(DMODEL / 128, NTOK / 128), 256, 0, stream>>>(
          Hb + (size_t)e * NTOK * DFF, wdb, idx, cnt, out, dummy, e);
  } else {
    for (int e = 0; e < NEXP; ++e) {
      ffn1_gemm256<<<dim3(2048 / 256, NTOK / 256), 512, 0, stream>>>(
          xbB, wguB, idx, cnt, gw, HbB, e);
      ffn2_gemm_db<<<dim3(DMODEL / 128, NTOK / 128), 256, 0, stream>>>(
          HbB, wdb, idx, cnt, out, dummy, e);
    }
  }
}